// Round 1
// baseline (1167.617 us; speedup 1.0000x reference)
//
#include <hip/hip_runtime.h>

#define B_ 8
#define N_ 307
#define T_ 48
#define D_ 64
#define H_ 4
#define HD_ 16
#define SK_ 20
#define DFF_ 256
#define EPS_ 1e-5f
#define SE 68  // row stride (floats) for t-indexed LDS tiles; 272B = 16B-aligned

// ---------------- kernel 1: pe[t] + time-feature embeddings → tcpe[B][T][64]
__global__ void tcpe_kernel(const int* __restrict__ tf,
                            const float* __restrict__ em,
                            const float* __restrict__ eh,
                            const float* __restrict__ ew,
                            const float* __restrict__ emo,
                            const float* __restrict__ ey,
                            float* __restrict__ tcpe) {
  int idx = blockIdx.x * 256 + threadIdx.x;  // B*T*64 = 24576
  if (idx >= B_ * T_ * D_) return;
  int d = idx & (D_ - 1);
  int bt = idx >> 6;
  int t = bt % T_;
  float freq = expf((float)((d >> 1) << 1) * (-logf(10000.0f) / (float)D_));
  float ang = (float)t * freq;
  float pe = (d & 1) ? cosf(ang) : sinf(ang);
  const int* f = tf + bt * 5;
  float v = pe + em[f[0] * D_ + d] + eh[f[1] * D_ + d] + ew[f[2] * D_ + d] +
            emo[f[3] * D_ + d] + ey[f[4] * D_ + d];
  tcpe[idx] = v;
}

__device__ inline float wave_sum(float v) {
#pragma unroll
  for (int off = 32; off >= 1; off >>= 1) v += __shfl_xor(v, off);
  return v;
}
__device__ inline float wave_max(float v) {
#pragma unroll
  for (int off = 32; off >= 1; off >>= 1) v = fmaxf(v, __shfl_xor(v, off));
  return v;
}

// 48x64 GEMM, K=64: wave g computes rows t=g*12..g*12+11, lane = output col.
template <int SS, int WSTRIDE, bool RELU>
__device__ inline void gemm_tile(const float* src, const float* __restrict__ W,
                                 int wcol, float bias, float* dst, int dstride,
                                 int lane, int g) {
  float w[64];
#pragma unroll
  for (int k = 0; k < 64; ++k) w[k] = W[k * WSTRIDE + wcol + lane];
  for (int tt = 0; tt < 12; ++tt) {
    int t = g * 12 + tt;
    float acc = bias;
#pragma unroll
    for (int k = 0; k < 64; k += 4) {
      float4 e = *(const float4*)&src[t * SS + k];
      acc = fmaf(e.x, w[k + 0], acc);
      acc = fmaf(e.y, w[k + 1], acc);
      acc = fmaf(e.z, w[k + 2], acc);
      acc = fmaf(e.w, w[k + 3], acc);
    }
    if (RELU) acc = fmaxf(acc, 0.0f);
    dst[t * dstride + lane] = acc;
  }
}

// ---------------- kernel 2: one block per (b,n); full fused layer
__global__ __launch_bounds__(256) void fused_kernel(
    const float* __restrict__ x, const int* __restrict__ idxs,
    const float* __restrict__ Wq, const float* __restrict__ Wk,
    const float* __restrict__ Wv, const float* __restrict__ Wo,
    const float* __restrict__ bo, const float* __restrict__ W1,
    const float* __restrict__ b1, const float* __restrict__ W2,
    const float* __restrict__ b2, const float* __restrict__ g1,
    const float* __restrict__ be1, const float* __restrict__ g2,
    const float* __restrict__ be2, const float* __restrict__ tcpe,
    float* __restrict__ out) {
  __shared__ float s_enc[T_ * SE];
  __shared__ float s_q[T_ * SE];
  __shared__ float s_k[T_ * SE];
  __shared__ float s_v[T_ * SE];
  __shared__ float s_ctx[T_ * D_];
  __shared__ float s_attn[H_ * SK_ * T_];
  __shared__ float s_M[H_ * T_];
  __shared__ float s_vmean[H_ * HD_];
  __shared__ int s_mtop[H_ * SK_];
#define s_h s_q    // reused after attention
#define s_ff1 s_k  // reused after attention

  const int tid = threadIdx.x;
  const int lane = tid & 63;
  const int g = tid >> 6;  // wave id == head id in attention
  const int bn = blockIdx.x;
  const int b = bn / N_;

  // P0: enc = x + (pe + tc)
  {
    const float4* x4 = (const float4*)(x + (size_t)bn * (T_ * D_));
    const float4* t4 = (const float4*)(tcpe + (size_t)b * (T_ * D_));
#pragma unroll
    for (int r = 0; r < 3; ++r) {
      int i = tid + 256 * r;  // 768 float4s
      float4 xv = x4[i];
      float4 tv = t4[i];
      int t = i >> 4;
      int d = (i & 15) << 2;
      *(float4*)&s_enc[t * SE + d] =
          make_float4(xv.x + tv.x, xv.y + tv.y, xv.z + tv.z, xv.w + tv.w);
    }
  }
  __syncthreads();

  // P1: Q,K,V = enc @ W{q,k,v}
  gemm_tile<SE, D_, false>(s_enc, Wq, 0, 0.0f, s_q, SE, lane, g);
  gemm_tile<SE, D_, false>(s_enc, Wk, 0, 0.0f, s_k, SE, lane, g);
  gemm_tile<SE, D_, false>(s_enc, Wv, 0, 0.0f, s_v, SE, lane, g);
  __syncthreads();

  // P2: ProbSparse attention, wave g handles head g
  // (a) sparse measurement M[t] = max_s q·k_samp − mean_s q·k_samp
  if (lane < T_) {
    float q[16];
#pragma unroll
    for (int j = 0; j < 16; j += 4) {
      float4 v4 = *(const float4*)&s_q[lane * SE + g * HD_ + j];
      q[j] = v4.x; q[j + 1] = v4.y; q[j + 2] = v4.z; q[j + 3] = v4.w;
    }
    float mx = -1e30f, sm = 0.0f;
    for (int s = 0; s < SK_; ++s) {
      int kt = idxs[lane * SK_ + s];
      float acc = 0.0f;
#pragma unroll
      for (int j = 0; j < 16; j += 4) {
        float4 kv = *(const float4*)&s_k[kt * SE + g * HD_ + j];
        acc = fmaf(kv.x, q[j], acc);
        acc = fmaf(kv.y, q[j + 1], acc);
        acc = fmaf(kv.z, q[j + 2], acc);
        acc = fmaf(kv.w, q[j + 3], acc);
      }
      mx = fmaxf(mx, acc);
      sm += acc;
    }
    s_M[g * T_ + lane] = mx - sm * (1.0f / (float)SK_);
  }
  __syncthreads();
  // (b) top-20 by rank; matches jax.lax.top_k tie-breaking (lower index first)
  if (lane < T_) {
    float mv = s_M[g * T_ + lane];
    int rank = 0;
    for (int t2 = 0; t2 < T_; ++t2) {
      float o = s_M[g * T_ + t2];
      rank += (o > mv || (o == mv && t2 < lane)) ? 1 : 0;
    }
    if (rank < SK_) s_mtop[g * SK_ + rank] = lane;
  }
  __syncthreads();
  // (c) scores + softmax; lane = key position t'
  {
    float kr[16];
    if (lane < T_) {
#pragma unroll
      for (int j = 0; j < 16; j += 4) {
        float4 v4 = *(const float4*)&s_k[lane * SE + g * HD_ + j];
        kr[j] = v4.x; kr[j + 1] = v4.y; kr[j + 2] = v4.z; kr[j + 3] = v4.w;
      }
    } else {
#pragma unroll
      for (int j = 0; j < 16; ++j) kr[j] = 0.0f;
    }
    for (int u = 0; u < SK_; ++u) {
      int qt = s_mtop[g * SK_ + u];
      float acc = 0.0f;
#pragma unroll
      for (int j = 0; j < 16; j += 4) {
        float4 qv = *(const float4*)&s_q[qt * SE + g * HD_ + j];  // broadcast
        acc = fmaf(qv.x, kr[j], acc);
        acc = fmaf(qv.y, kr[j + 1], acc);
        acc = fmaf(qv.z, kr[j + 2], acc);
        acc = fmaf(qv.w, kr[j + 3], acc);
      }
      float sc = (lane < T_) ? acc * 0.25f : -1e30f;  // 1/sqrt(16)
      float mx = wave_max(sc);
      float e = (lane < T_) ? __expf(sc - mx) : 0.0f;
      float es = wave_sum(e);
      if (lane < T_) s_attn[(g * SK_ + u) * T_ + lane] = e / es;
    }
  }
  __syncthreads();
  // (d) upd = attn @ V ; ctx = broadcast(mean V) with rows m_top ← upd
  float upd[5];
#pragma unroll
  for (int r = 0; r < 5; ++r) {
    int i = lane + 64 * r;  // 320 = 20x16
    int u = i >> 4, j = i & 15;
    float acc = 0.0f;
#pragma unroll 4
    for (int t = 0; t < T_; ++t)
      acc = fmaf(s_attn[(g * SK_ + u) * T_ + t], s_v[t * SE + g * HD_ + j], acc);
    upd[r] = acc;
  }
  if (lane < HD_) {
    float acc = 0.0f;
    for (int t = 0; t < T_; ++t) acc += s_v[t * SE + g * HD_ + lane];
    s_vmean[g * HD_ + lane] = acc * (1.0f / (float)T_);
  }
  __syncthreads();
#pragma unroll
  for (int r = 0; r < 12; ++r) {
    int i = lane + 64 * r;  // 768 = 48x16
    int t = i >> 4, j = i & 15;
    s_ctx[t * D_ + g * HD_ + j] = s_vmean[g * HD_ + j];
  }
  __syncthreads();
#pragma unroll
  for (int r = 0; r < 5; ++r) {
    int i = lane + 64 * r;
    int u = i >> 4, j = i & 15;
    s_ctx[s_mtop[g * SK_ + u] * D_ + g * HD_ + j] = upd[r];
  }
  __syncthreads();

  // P3: att_out = ctx@Wo + bo ; h = LN1(att_out + enc)
  {
    float w[64];
#pragma unroll
    for (int k = 0; k < 64; ++k) w[k] = Wo[k * D_ + lane];
    float bov = bo[lane];
    float g1v = g1[lane], be1v = be1[lane];
    for (int tt = 0; tt < 12; ++tt) {
      int t = g * 12 + tt;
      float acc = bov;
#pragma unroll
      for (int k = 0; k < 64; k += 4) {
        float4 e = *(const float4*)&s_ctx[t * D_ + k];
        acc = fmaf(e.x, w[k], acc);
        acc = fmaf(e.y, w[k + 1], acc);
        acc = fmaf(e.z, w[k + 2], acc);
        acc = fmaf(e.w, w[k + 3], acc);
      }
      float val = acc + s_enc[t * SE + lane];
      float m = wave_sum(val) * (1.0f / 64.0f);
      float dv = val - m;
      float var = wave_sum(dv * dv) * (1.0f / 64.0f);
      s_h[t * SE + lane] = dv * (1.0f / sqrtf(var + EPS_)) * g1v + be1v;
    }
  }
  __syncthreads();

  // P4: FFN in 4 chunks of 64; ff accumulated in registers
  float ffacc[12];
#pragma unroll
  for (int i = 0; i < 12; ++i) ffacc[i] = 0.0f;
  for (int jc = 0; jc < 4; ++jc) {
    {
      float w[64];
#pragma unroll
      for (int k = 0; k < 64; ++k) w[k] = W1[k * DFF_ + jc * 64 + lane];
      float bb = b1[jc * 64 + lane];
      for (int tt = 0; tt < 12; ++tt) {
        int t = g * 12 + tt;
        float acc = bb;
#pragma unroll
        for (int k = 0; k < 64; k += 4) {
          float4 e = *(const float4*)&s_h[t * SE + k];
          acc = fmaf(e.x, w[k], acc);
          acc = fmaf(e.y, w[k + 1], acc);
          acc = fmaf(e.z, w[k + 2], acc);
          acc = fmaf(e.w, w[k + 3], acc);
        }
        s_ff1[t * SE + lane] = fmaxf(acc, 0.0f);
      }
    }
    __syncthreads();
    {
      float w[64];
#pragma unroll
      for (int k = 0; k < 64; ++k) w[k] = W2[(jc * 64 + k) * D_ + lane];
      for (int tt = 0; tt < 12; ++tt) {
        int t = g * 12 + tt;
        float acc = ffacc[tt];
#pragma unroll
        for (int k = 0; k < 64; k += 4) {
          float4 e = *(const float4*)&s_ff1[t * SE + k];
          acc = fmaf(e.x, w[k], acc);
          acc = fmaf(e.y, w[k + 1], acc);
          acc = fmaf(e.z, w[k + 2], acc);
          acc = fmaf(e.w, w[k + 3], acc);
        }
        ffacc[tt] = acc;
      }
    }
    __syncthreads();
  }

  // P5: out = LN2(ff + b2 + h)
  {
    float g2v = g2[lane], be2v = be2[lane], b2v = b2[lane];
    float* op = out + (size_t)bn * (T_ * D_);
    for (int tt = 0; tt < 12; ++tt) {
      int t = g * 12 + tt;
      float val = ffacc[tt] + b2v + s_h[t * SE + lane];
      float m = wave_sum(val) * (1.0f / 64.0f);
      float dv = val - m;
      float var = wave_sum(dv * dv) * (1.0f / 64.0f);
      op[t * D_ + lane] = dv * (1.0f / sqrtf(var + EPS_)) * g2v + be2v;
    }
  }
#undef s_h
#undef s_ff1
}

extern "C" void kernel_launch(void* const* d_in, const int* in_sizes, int n_in,
                              void* d_out, int out_size, void* d_ws,
                              size_t ws_size, hipStream_t stream) {
  const float* x = (const float*)d_in[0];
  const int* tf = (const int*)d_in[1];
  const int* idxs = (const int*)d_in[2];
  const float* Wq = (const float*)d_in[3];
  const float* Wk = (const float*)d_in[4];
  const float* Wv = (const float*)d_in[5];
  const float* Wo = (const float*)d_in[6];
  const float* bo = (const float*)d_in[7];
  const float* W1 = (const float*)d_in[8];
  const float* b1 = (const float*)d_in[9];
  const float* W2 = (const float*)d_in[10];
  const float* b2 = (const float*)d_in[11];
  const float* g1 = (const float*)d_in[12];
  const float* be1 = (const float*)d_in[13];
  const float* g2 = (const float*)d_in[14];
  const float* be2 = (const float*)d_in[15];
  const float* em = (const float*)d_in[16];
  const float* eh = (const float*)d_in[17];
  const float* ew = (const float*)d_in[18];
  const float* emo = (const float*)d_in[19];
  const float* ey = (const float*)d_in[20];
  float* tcpe = (float*)d_ws;  // B*T*64 floats = 96 KiB
  float* out = (float*)d_out;

  hipLaunchKernelGGL(tcpe_kernel, dim3((B_ * T_ * D_ + 255) / 256), dim3(256),
                     0, stream, tf, em, eh, ew, emo, ey, tcpe);
  hipLaunchKernelGGL(fused_kernel, dim3(B_ * N_), dim3(256), 0, stream, x,
                     idxs, Wq, Wk, Wv, Wo, bo, W1, b1, W2, b2, g1, be1, g2,
                     be2, tcpe, out);
}

// Round 2
// 1079.787 us; speedup vs baseline: 1.0813x; 1.0813x over previous
//
#include <hip/hip_runtime.h>

#define B_ 8
#define N_ 307
#define T_ 48
#define D_ 64
#define H_ 4
#define HD_ 16
#define SK_ 20
#define DFF_ 256
#define EPS_ 1e-5f
#define SE 68  // row stride (floats) for t-indexed LDS tiles; 272B = 16B-aligned
#define SH 20  // row stride for per-head [T][16] tiles; 80B = 16B-aligned
#define BNTD (B_ * N_ * T_ * D_)

// ---------------- kernel 1: pe[t] + time-feature embeddings → tcpe[B][T][64]
__global__ void tcpe_kernel(const int* __restrict__ tf,
                            const float* __restrict__ em,
                            const float* __restrict__ eh,
                            const float* __restrict__ ew,
                            const float* __restrict__ emo,
                            const float* __restrict__ ey,
                            float* __restrict__ tcpe) {
  int idx = blockIdx.x * 256 + threadIdx.x;  // B*T*64 = 24576
  if (idx >= B_ * T_ * D_) return;
  int d = idx & (D_ - 1);
  int bt = idx >> 6;
  int t = bt % T_;
  float freq = expf((float)((d >> 1) << 1) * (-logf(10000.0f) / (float)D_));
  float ang = (float)t * freq;
  float pe = (d & 1) ? cosf(ang) : sinf(ang);
  const int* f = tf + bt * 5;
  float v = pe + em[f[0] * D_ + d] + eh[f[1] * D_ + d] + ew[f[2] * D_ + d] +
            emo[f[3] * D_ + d] + ey[f[4] * D_ + d];
  tcpe[idx] = v;
}

__device__ inline float wave_sum(float v) {
#pragma unroll
  for (int off = 32; off >= 1; off >>= 1) v += __shfl_xor(v, off);
  return v;
}
__device__ inline float wave_max(float v) {
#pragma unroll
  for (int off = 32; off >= 1; off >>= 1) v = fmaxf(v, __shfl_xor(v, off));
  return v;
}

// 48x64 GEMM, K=64: wave g computes rows t=g*12..g*12+11, lane = output col.
template <int SS, int WSTRIDE, bool RELU>
__device__ inline void gemm_tile(const float* src, const float* __restrict__ W,
                                 int wcol, float bias, float* dst, int dstride,
                                 int lane, int g) {
  float w[64];
#pragma unroll
  for (int k = 0; k < 64; ++k) w[k] = W[k * WSTRIDE + wcol + lane];
  for (int tt = 0; tt < 12; ++tt) {
    int t = g * 12 + tt;
    float acc = bias;
#pragma unroll
    for (int k = 0; k < 64; k += 4) {
      float4 e = *(const float4*)&src[t * SS + k];
      acc = fmaf(e.x, w[k + 0], acc);
      acc = fmaf(e.y, w[k + 1], acc);
      acc = fmaf(e.z, w[k + 2], acc);
      acc = fmaf(e.w, w[k + 3], acc);
    }
    if (RELU) acc = fmaxf(acc, 0.0f);
    dst[t * dstride + lane] = acc;
  }
}

// ================= SPLIT PATH =================
// ---------------- kernel 2: enc = x+tcpe (LDS only); Q,K,V → global
__global__ __launch_bounds__(256) void qkv_kernel(
    const float* __restrict__ x, const float* __restrict__ tcpe,
    const float* __restrict__ Wq, const float* __restrict__ Wk,
    const float* __restrict__ Wv, float* __restrict__ Qg,
    float* __restrict__ Kg, float* __restrict__ Vg) {
  __shared__ float s_enc[T_ * SE];
  const int tid = threadIdx.x;
  const int lane = tid & 63;
  const int g = tid >> 6;
  const int bn = blockIdx.x;
  const int b = bn / N_;
  {
    const float4* x4 = (const float4*)(x + (size_t)bn * (T_ * D_));
    const float4* t4 = (const float4*)(tcpe + (size_t)b * (T_ * D_));
#pragma unroll
    for (int r = 0; r < 3; ++r) {
      int i = tid + 256 * r;
      float4 xv = x4[i];
      float4 tv = t4[i];
      int t = i >> 4;
      int d = (i & 15) << 2;
      *(float4*)&s_enc[t * SE + d] =
          make_float4(xv.x + tv.x, xv.y + tv.y, xv.z + tv.z, xv.w + tv.w);
    }
  }
  __syncthreads();
  const float* Ws[3] = {Wq, Wk, Wv};
  float* Gs[3] = {Qg, Kg, Vg};
#pragma unroll 1
  for (int m = 0; m < 3; ++m) {
    float w[64];
#pragma unroll
    for (int k = 0; k < 64; ++k) w[k] = Ws[m][k * D_ + lane];
    float* gp = Gs[m] + (size_t)bn * (T_ * D_);
    for (int tt = 0; tt < 12; ++tt) {
      int t = g * 12 + tt;
      float acc = 0.0f;
#pragma unroll
      for (int k = 0; k < 64; k += 4) {
        float4 e = *(const float4*)&s_enc[t * SE + k];
        acc = fmaf(e.x, w[k + 0], acc);
        acc = fmaf(e.y, w[k + 1], acc);
        acc = fmaf(e.z, w[k + 2], acc);
        acc = fmaf(e.w, w[k + 3], acc);
      }
      gp[t * D_ + lane] = acc;
    }
  }
}

// ---------------- kernel 3: per-(b,n,h) ProbSparse attention; ctx → V in place
__global__ __launch_bounds__(64) void attn_kernel(const float* __restrict__ Qg,
                                                  const float* __restrict__ Kg,
                                                  float* __restrict__ Vg,
                                                  const int* __restrict__ idxs) {
  __shared__ float s_q[T_ * SH];
  __shared__ float s_k[T_ * SH];
  __shared__ float s_v[T_ * SH];
  __shared__ float s_attn[SK_ * T_];
  __shared__ float s_M[T_];
  __shared__ float s_vmean[HD_];
  __shared__ int s_mtop[SK_];
  const int lane = threadIdx.x;
  const int bn = blockIdx.x;
  const int h = blockIdx.y;
  const size_t base = (size_t)bn * (T_ * D_) + h * HD_;
  // load head slices (48 rows x 16 floats each)
  for (int i = lane; i < 192; i += 64) {
    int t = i >> 2, j = (i & 3) << 2;
    *(float4*)&s_q[t * SH + j] = *(const float4*)&Qg[base + t * D_ + j];
    *(float4*)&s_k[t * SH + j] = *(const float4*)&Kg[base + t * D_ + j];
    *(float4*)&s_v[t * SH + j] = *(const float4*)&Vg[base + t * D_ + j];
  }
  __syncthreads();
  // (a) M[t] = max_s q·k_samp − mean_s
  if (lane < T_) {
    float q[16];
#pragma unroll
    for (int j = 0; j < 16; j += 4) {
      float4 v4 = *(const float4*)&s_q[lane * SH + j];
      q[j] = v4.x; q[j + 1] = v4.y; q[j + 2] = v4.z; q[j + 3] = v4.w;
    }
    float mx = -1e30f, sm = 0.0f;
    for (int s = 0; s < SK_; ++s) {
      int kt = idxs[lane * SK_ + s];
      float acc = 0.0f;
#pragma unroll
      for (int j = 0; j < 16; j += 4) {
        float4 kv = *(const float4*)&s_k[kt * SH + j];
        acc = fmaf(kv.x, q[j], acc);
        acc = fmaf(kv.y, q[j + 1], acc);
        acc = fmaf(kv.z, q[j + 2], acc);
        acc = fmaf(kv.w, q[j + 3], acc);
      }
      mx = fmaxf(mx, acc);
      sm += acc;
    }
    s_M[lane] = mx - sm * (1.0f / (float)SK_);
  }
  __syncthreads();
  // (b) top-20 by rank (jax.lax.top_k tie-break: lower index first)
  if (lane < T_) {
    float mv = s_M[lane];
    int rank = 0;
    for (int t2 = 0; t2 < T_; ++t2) {
      float o = s_M[t2];
      rank += (o > mv || (o == mv && t2 < lane)) ? 1 : 0;
    }
    if (rank < SK_) s_mtop[rank] = lane;
  }
  __syncthreads();
  // (c) scores + softmax; lane = key position t'
  {
    float kr[16];
    if (lane < T_) {
#pragma unroll
      for (int j = 0; j < 16; j += 4) {
        float4 v4 = *(const float4*)&s_k[lane * SH + j];
        kr[j] = v4.x; kr[j + 1] = v4.y; kr[j + 2] = v4.z; kr[j + 3] = v4.w;
      }
    } else {
#pragma unroll
      for (int j = 0; j < 16; ++j) kr[j] = 0.0f;
    }
    for (int u = 0; u < SK_; ++u) {
      int qt = s_mtop[u];
      float acc = 0.0f;
#pragma unroll
      for (int j = 0; j < 16; j += 4) {
        float4 qv = *(const float4*)&s_q[qt * SH + j];  // broadcast
        acc = fmaf(qv.x, kr[j], acc);
        acc = fmaf(qv.y, kr[j + 1], acc);
        acc = fmaf(qv.z, kr[j + 2], acc);
        acc = fmaf(qv.w, kr[j + 3], acc);
      }
      float sc = (lane < T_) ? acc * 0.25f : -1e30f;
      float mx = wave_max(sc);
      float e = (lane < T_) ? __expf(sc - mx) : 0.0f;
      float es = wave_sum(e);
      if (lane < T_) s_attn[u * T_ + lane] = e / es;
    }
  }
  __syncthreads();
  // (d) upd = attn @ V ; vmean
  float upd[5];
#pragma unroll
  for (int r = 0; r < 5; ++r) {
    int i = lane + 64 * r;  // 320 = 20x16
    int u = i >> 4, j = i & 15;
    float acc = 0.0f;
#pragma unroll 4
    for (int t = 0; t < T_; ++t)
      acc = fmaf(s_attn[u * T_ + t], s_v[t * SH + j], acc);
    upd[r] = acc;
  }
  if (lane < HD_) {
    float acc = 0.0f;
    for (int t = 0; t < T_; ++t) acc += s_v[t * SH + lane];
    s_vmean[lane] = acc * (1.0f / (float)T_);
  }
  __syncthreads();
  // overwrite s_v with ctx = broadcast vmean, rows m_top ← upd
#pragma unroll
  for (int r = 0; r < 12; ++r) {
    int i = lane + 64 * r;  // 768 = 48x16
    int t = i >> 4, j = i & 15;
    s_v[t * SH + j] = s_vmean[j];
  }
  __syncthreads();
#pragma unroll
  for (int r = 0; r < 5; ++r) {
    int i = lane + 64 * r;
    int u = i >> 4, j = i & 15;
    s_v[s_mtop[u] * SH + j] = upd[r];
  }
  __syncthreads();
  // ctx → global (in place over V)
  for (int i = lane; i < 192; i += 64) {
    int t = i >> 2, j = (i & 3) << 2;
    *(float4*)&Vg[base + t * D_ + j] = *(const float4*)&s_v[t * SH + j];
  }
}

// ---------------- kernel 4: Wo+LN1+FFN+LN2
__global__ __launch_bounds__(256) void tail_kernel(
    const float* __restrict__ x, const float* __restrict__ tcpe,
    const float* __restrict__ ctxG, const float* __restrict__ Wo,
    const float* __restrict__ bo, const float* __restrict__ W1,
    const float* __restrict__ b1, const float* __restrict__ W2,
    const float* __restrict__ b2, const float* __restrict__ g1,
    const float* __restrict__ be1, const float* __restrict__ g2,
    const float* __restrict__ be2, float* __restrict__ out) {
  __shared__ float s_ctx[T_ * SE];
  __shared__ float s_h[T_ * SE];
  __shared__ float s_ff1[T_ * SE];
  const int tid = threadIdx.x;
  const int lane = tid & 63;
  const int g = tid >> 6;
  const int bn = blockIdx.x;
  const int b = bn / N_;
  {
    const float4* c4 = (const float4*)(ctxG + (size_t)bn * (T_ * D_));
#pragma unroll
    for (int r = 0; r < 3; ++r) {
      int i = tid + 256 * r;
      int t = i >> 4;
      int d = (i & 15) << 2;
      *(float4*)&s_ctx[t * SE + d] = c4[i];
    }
  }
  __syncthreads();
  // Wo + residual(enc recomputed) + LN1 → s_h
  {
    float w[64];
#pragma unroll
    for (int k = 0; k < 64; ++k) w[k] = Wo[k * D_ + lane];
    float bov = bo[lane];
    float g1v = g1[lane], be1v = be1[lane];
    const float* xp = x + (size_t)bn * (T_ * D_);
    const float* tp = tcpe + (size_t)b * (T_ * D_);
    for (int tt = 0; tt < 12; ++tt) {
      int t = g * 12 + tt;
      float acc = bov;
#pragma unroll
      for (int k = 0; k < 64; k += 4) {
        float4 e = *(const float4*)&s_ctx[t * SE + k];
        acc = fmaf(e.x, w[k], acc);
        acc = fmaf(e.y, w[k + 1], acc);
        acc = fmaf(e.z, w[k + 2], acc);
        acc = fmaf(e.w, w[k + 3], acc);
      }
      float val = acc + xp[t * D_ + lane] + tp[t * D_ + lane];
      float m = wave_sum(val) * (1.0f / 64.0f);
      float dv = val - m;
      float var = wave_sum(dv * dv) * (1.0f / 64.0f);
      s_h[t * SE + lane] = dv * (1.0f / sqrtf(var + EPS_)) * g1v + be1v;
    }
  }
  __syncthreads();
  // FFN in 4 chunks of 64
  float ffacc[12];
#pragma unroll
  for (int i = 0; i < 12; ++i) ffacc[i] = 0.0f;
  for (int jc = 0; jc < 4; ++jc) {
    {
      float w[64];
#pragma unroll
      for (int k = 0; k < 64; ++k) w[k] = W1[k * DFF_ + jc * 64 + lane];
      float bb = b1[jc * 64 + lane];
      for (int tt = 0; tt < 12; ++tt) {
        int t = g * 12 + tt;
        float acc = bb;
#pragma unroll
        for (int k = 0; k < 64; k += 4) {
          float4 e = *(const float4*)&s_h[t * SE + k];
          acc = fmaf(e.x, w[k], acc);
          acc = fmaf(e.y, w[k + 1], acc);
          acc = fmaf(e.z, w[k + 2], acc);
          acc = fmaf(e.w, w[k + 3], acc);
        }
        s_ff1[t * SE + lane] = fmaxf(acc, 0.0f);
      }
    }
    __syncthreads();
    {
      float w[64];
#pragma unroll
      for (int k = 0; k < 64; ++k) w[k] = W2[(jc * 64 + k) * D_ + lane];
      for (int tt = 0; tt < 12; ++tt) {
        int t = g * 12 + tt;
        float acc = ffacc[tt];
#pragma unroll
        for (int k = 0; k < 64; k += 4) {
          float4 e = *(const float4*)&s_ff1[t * SE + k];
          acc = fmaf(e.x, w[k], acc);
          acc = fmaf(e.y, w[k + 1], acc);
          acc = fmaf(e.z, w[k + 2], acc);
          acc = fmaf(e.w, w[k + 3], acc);
        }
        ffacc[tt] = acc;
      }
    }
    __syncthreads();
  }
  // out = LN2(ff + b2 + h)
  {
    float g2v = g2[lane], be2v = be2[lane], b2v = b2[lane];
    float* op = out + (size_t)bn * (T_ * D_);
    for (int tt = 0; tt < 12; ++tt) {
      int t = g * 12 + tt;
      float val = ffacc[tt] + b2v + s_h[t * SE + lane];
      float m = wave_sum(val) * (1.0f / 64.0f);
      float dv = val - m;
      float var = wave_sum(dv * dv) * (1.0f / 64.0f);
      op[t * D_ + lane] = dv * (1.0f / sqrtf(var + EPS_)) * g2v + be2v;
    }
  }
}

// ================= FALLBACK: round-1 monolithic fused kernel =================
__global__ __launch_bounds__(256) void fused_kernel(
    const float* __restrict__ x, const int* __restrict__ idxs,
    const float* __restrict__ Wq, const float* __restrict__ Wk,
    const float* __restrict__ Wv, const float* __restrict__ Wo,
    const float* __restrict__ bo, const float* __restrict__ W1,
    const float* __restrict__ b1, const float* __restrict__ W2,
    const float* __restrict__ b2, const float* __restrict__ g1,
    const float* __restrict__ be1, const float* __restrict__ g2,
    const float* __restrict__ be2, const float* __restrict__ tcpe,
    float* __restrict__ out) {
  __shared__ float s_enc[T_ * SE];
  __shared__ float s_q[T_ * SE];
  __shared__ float s_k[T_ * SE];
  __shared__ float s_v[T_ * SE];
  __shared__ float s_ctx[T_ * D_];
  __shared__ float s_attn[H_ * SK_ * T_];
  __shared__ float s_M[H_ * T_];
  __shared__ float s_vmean[H_ * HD_];
  __shared__ int s_mtop[H_ * SK_];
#define s_hh s_q
#define s_ff1b s_k
  const int tid = threadIdx.x;
  const int lane = tid & 63;
  const int g = tid >> 6;
  const int bn = blockIdx.x;
  const int b = bn / N_;
  {
    const float4* x4 = (const float4*)(x + (size_t)bn * (T_ * D_));
    const float4* t4 = (const float4*)(tcpe + (size_t)b * (T_ * D_));
#pragma unroll
    for (int r = 0; r < 3; ++r) {
      int i = tid + 256 * r;
      float4 xv = x4[i];
      float4 tv = t4[i];
      int t = i >> 4;
      int d = (i & 15) << 2;
      *(float4*)&s_enc[t * SE + d] =
          make_float4(xv.x + tv.x, xv.y + tv.y, xv.z + tv.z, xv.w + tv.w);
    }
  }
  __syncthreads();
  gemm_tile<SE, D_, false>(s_enc, Wq, 0, 0.0f, s_q, SE, lane, g);
  gemm_tile<SE, D_, false>(s_enc, Wk, 0, 0.0f, s_k, SE, lane, g);
  gemm_tile<SE, D_, false>(s_enc, Wv, 0, 0.0f, s_v, SE, lane, g);
  __syncthreads();
  if (lane < T_) {
    float q[16];
#pragma unroll
    for (int j = 0; j < 16; j += 4) {
      float4 v4 = *(const float4*)&s_q[lane * SE + g * HD_ + j];
      q[j] = v4.x; q[j + 1] = v4.y; q[j + 2] = v4.z; q[j + 3] = v4.w;
    }
    float mx = -1e30f, sm = 0.0f;
    for (int s = 0; s < SK_; ++s) {
      int kt = idxs[lane * SK_ + s];
      float acc = 0.0f;
#pragma unroll
      for (int j = 0; j < 16; j += 4) {
        float4 kv = *(const float4*)&s_k[kt * SE + g * HD_ + j];
        acc = fmaf(kv.x, q[j], acc);
        acc = fmaf(kv.y, q[j + 1], acc);
        acc = fmaf(kv.z, q[j + 2], acc);
        acc = fmaf(kv.w, q[j + 3], acc);
      }
      mx = fmaxf(mx, acc);
      sm += acc;
    }
    s_M[g * T_ + lane] = mx - sm * (1.0f / (float)SK_);
  }
  __syncthreads();
  if (lane < T_) {
    float mv = s_M[g * T_ + lane];
    int rank = 0;
    for (int t2 = 0; t2 < T_; ++t2) {
      float o = s_M[g * T_ + t2];
      rank += (o > mv || (o == mv && t2 < lane)) ? 1 : 0;
    }
    if (rank < SK_) s_mtop[g * SK_ + rank] = lane;
  }
  __syncthreads();
  {
    float kr[16];
    if (lane < T_) {
#pragma unroll
      for (int j = 0; j < 16; j += 4) {
        float4 v4 = *(const float4*)&s_k[lane * SE + g * HD_ + j];
        kr[j] = v4.x; kr[j + 1] = v4.y; kr[j + 2] = v4.z; kr[j + 3] = v4.w;
      }
    } else {
#pragma unroll
      for (int j = 0; j < 16; ++j) kr[j] = 0.0f;
    }
    for (int u = 0; u < SK_; ++u) {
      int qt = s_mtop[g * SK_ + u];
      float acc = 0.0f;
#pragma unroll
      for (int j = 0; j < 16; j += 4) {
        float4 qv = *(const float4*)&s_q[qt * SE + g * HD_ + j];
        acc = fmaf(qv.x, kr[j], acc);
        acc = fmaf(qv.y, kr[j + 1], acc);
        acc = fmaf(qv.z, kr[j + 2], acc);
        acc = fmaf(qv.w, kr[j + 3], acc);
      }
      float sc = (lane < T_) ? acc * 0.25f : -1e30f;
      float mx = wave_max(sc);
      float e = (lane < T_) ? __expf(sc - mx) : 0.0f;
      float es = wave_sum(e);
      if (lane < T_) s_attn[(g * SK_ + u) * T_ + lane] = e / es;
    }
  }
  __syncthreads();
  float upd[5];
#pragma unroll
  for (int r = 0; r < 5; ++r) {
    int i = lane + 64 * r;
    int u = i >> 4, j = i & 15;
    float acc = 0.0f;
#pragma unroll 4
    for (int t = 0; t < T_; ++t)
      acc = fmaf(s_attn[(g * SK_ + u) * T_ + t], s_v[t * SE + g * HD_ + j], acc);
    upd[r] = acc;
  }
  if (lane < HD_) {
    float acc = 0.0f;
    for (int t = 0; t < T_; ++t) acc += s_v[t * SE + g * HD_ + lane];
    s_vmean[g * HD_ + lane] = acc * (1.0f / (float)T_);
  }
  __syncthreads();
#pragma unroll
  for (int r = 0; r < 12; ++r) {
    int i = lane + 64 * r;
    int t = i >> 4, j = i & 15;
    s_ctx[t * D_ + g * HD_ + j] = s_vmean[g * HD_ + j];
  }
  __syncthreads();
#pragma unroll
  for (int r = 0; r < 5; ++r) {
    int i = lane + 64 * r;
    int u = i >> 4, j = i & 15;
    s_ctx[s_mtop[g * SK_ + u] * D_ + g * HD_ + j] = upd[r];
  }
  __syncthreads();
  {
    float w[64];
#pragma unroll
    for (int k = 0; k < 64; ++k) w[k] = Wo[k * D_ + lane];
    float bov = bo[lane];
    float g1v = g1[lane], be1v = be1[lane];
    for (int tt = 0; tt < 12; ++tt) {
      int t = g * 12 + tt;
      float acc = bov;
#pragma unroll
      for (int k = 0; k < 64; k += 4) {
        float4 e = *(const float4*)&s_ctx[t * D_ + k];
        acc = fmaf(e.x, w[k], acc);
        acc = fmaf(e.y, w[k + 1], acc);
        acc = fmaf(e.z, w[k + 2], acc);
        acc = fmaf(e.w, w[k + 3], acc);
      }
      float val = acc + s_enc[t * SE + lane];
      float m = wave_sum(val) * (1.0f / 64.0f);
      float dv = val - m;
      float var = wave_sum(dv * dv) * (1.0f / 64.0f);
      s_hh[t * SE + lane] = dv * (1.0f / sqrtf(var + EPS_)) * g1v + be1v;
    }
  }
  __syncthreads();
  float ffacc[12];
#pragma unroll
  for (int i = 0; i < 12; ++i) ffacc[i] = 0.0f;
  for (int jc = 0; jc < 4; ++jc) {
    {
      float w[64];
#pragma unroll
      for (int k = 0; k < 64; ++k) w[k] = W1[k * DFF_ + jc * 64 + lane];
      float bb = b1[jc * 64 + lane];
      for (int tt = 0; tt < 12; ++tt) {
        int t = g * 12 + tt;
        float acc = bb;
#pragma unroll
        for (int k = 0; k < 64; k += 4) {
          float4 e = *(const float4*)&s_hh[t * SE + k];
          acc = fmaf(e.x, w[k], acc);
          acc = fmaf(e.y, w[k + 1], acc);
          acc = fmaf(e.z, w[k + 2], acc);
          acc = fmaf(e.w, w[k + 3], acc);
        }
        s_ff1b[t * SE + lane] = fmaxf(acc, 0.0f);
      }
    }
    __syncthreads();
    {
      float w[64];
#pragma unroll
      for (int k = 0; k < 64; ++k) w[k] = W2[(jc * 64 + k) * D_ + lane];
      for (int tt = 0; tt < 12; ++tt) {
        int t = g * 12 + tt;
        float acc = ffacc[tt];
#pragma unroll
        for (int k = 0; k < 64; k += 4) {
          float4 e = *(const float4*)&s_ff1b[t * SE + k];
          acc = fmaf(e.x, w[k], acc);
          acc = fmaf(e.y, w[k + 1], acc);
          acc = fmaf(e.z, w[k + 2], acc);
          acc = fmaf(e.w, w[k + 3], acc);
        }
        ffacc[tt] = acc;
      }
    }
    __syncthreads();
  }
  {
    float g2v = g2[lane], be2v = be2[lane], b2v = b2[lane];
    float* op = out + (size_t)bn * (T_ * D_);
    for (int tt = 0; tt < 12; ++tt) {
      int t = g * 12 + tt;
      float val = ffacc[tt] + b2v + s_hh[t * SE + lane];
      float m = wave_sum(val) * (1.0f / 64.0f);
      float dv = val - m;
      float var = wave_sum(dv * dv) * (1.0f / 64.0f);
      op[t * D_ + lane] = dv * (1.0f / sqrtf(var + EPS_)) * g2v + be2v;
    }
  }
#undef s_hh
#undef s_ff1b
}

extern "C" void kernel_launch(void* const* d_in, const int* in_sizes, int n_in,
                              void* d_out, int out_size, void* d_ws,
                              size_t ws_size, hipStream_t stream) {
  const float* x = (const float*)d_in[0];
  const int* tf = (const int*)d_in[1];
  const int* idxs = (const int*)d_in[2];
  const float* Wq = (const float*)d_in[3];
  const float* Wk = (const float*)d_in[4];
  const float* Wv = (const float*)d_in[5];
  const float* Wo = (const float*)d_in[6];
  const float* bo = (const float*)d_in[7];
  const float* W1 = (const float*)d_in[8];
  const float* b1 = (const float*)d_in[9];
  const float* W2 = (const float*)d_in[10];
  const float* b2 = (const float*)d_in[11];
  const float* g1 = (const float*)d_in[12];
  const float* be1 = (const float*)d_in[13];
  const float* g2 = (const float*)d_in[14];
  const float* be2 = (const float*)d_in[15];
  const float* em = (const float*)d_in[16];
  const float* eh = (const float*)d_in[17];
  const float* ew = (const float*)d_in[18];
  const float* emo = (const float*)d_in[19];
  const float* ey = (const float*)d_in[20];
  float* out = (float*)d_out;

  float* tcpe = (float*)d_ws;  // 24576 floats
  size_t need = (size_t)(24576 + 3 * (size_t)BNTD) * sizeof(float);

  hipLaunchKernelGGL(tcpe_kernel, dim3((B_ * T_ * D_ + 255) / 256), dim3(256),
                     0, stream, tf, em, eh, ew, emo, ey, tcpe);

  if (ws_size >= need) {
    float* Qg = tcpe + 24576;
    float* Kg = Qg + BNTD;
    float* Vg = Kg + BNTD;
    hipLaunchKernelGGL(qkv_kernel, dim3(B_ * N_), dim3(256), 0, stream, x,
                       tcpe, Wq, Wk, Wv, Qg, Kg, Vg);
    hipLaunchKernelGGL(attn_kernel, dim3(B_ * N_, H_), dim3(64), 0, stream, Qg,
                       Kg, Vg, idxs);
    hipLaunchKernelGGL(tail_kernel, dim3(B_ * N_), dim3(256), 0, stream, x,
                       tcpe, Vg, Wo, bo, W1, b1, W2, b2, g1, be1, g2, be2,
                       out);
  } else {
    hipLaunchKernelGGL(fused_kernel, dim3(B_ * N_), dim3(256), 0, stream, x,
                       idxs, Wq, Wk, Wv, Wo, bo, W1, b1, W2, b2, g1, be1, g2,
                       be2, tcpe, out);
  }
}

// Round 3
// 275.403 us; speedup vs baseline: 4.2397x; 3.9208x over previous
//
#include <hip/hip_runtime.h>

#define B_ 8
#define N_ 307
#define T_ 48
#define D_ 64
#define H_ 4
#define HD_ 16
#define SK_ 20
#define DFF_ 256
#define EPS_ 1e-5f
#define SE 68  // row stride (floats) for t-indexed LDS tiles; 272B = 16B-aligned
#define SH 20  // row stride for per-head [T][16] tiles; 80B = 16B-aligned
#define BNTD (B_ * N_ * T_ * D_)
#define ROWS (B_ * N_ * T_)
#define STH 72   // bf16 row stride for h tile (144B, 16B-aligned)
#define STF 264  // bf16 row stride for f1 tile (528B, 16B-aligned)

typedef __attribute__((ext_vector_type(8))) short bf16x8;
typedef __attribute__((ext_vector_type(4))) float f32x4;

__device__ inline ushort f2bf(float f) {
  union { float f; uint u; } x;
  x.f = f;
  uint u = x.u;
  return (ushort)((u + 0x7fffu + ((u >> 16) & 1u)) >> 16);  // RNE
}

// ---------------- kernel 1: pe[t] + time-feature embeddings → tcpe[B][T][64]
__global__ void tcpe_kernel(const int* __restrict__ tf,
                            const float* __restrict__ em,
                            const float* __restrict__ eh,
                            const float* __restrict__ ew,
                            const float* __restrict__ emo,
                            const float* __restrict__ ey,
                            float* __restrict__ tcpe) {
  int idx = blockIdx.x * 256 + threadIdx.x;  // B*T*64 = 24576
  if (idx >= B_ * T_ * D_) return;
  int d = idx & (D_ - 1);
  int bt = idx >> 6;
  int t = bt % T_;
  float freq = expf((float)((d >> 1) << 1) * (-logf(10000.0f) / (float)D_));
  float ang = (float)t * freq;
  float pe = (d & 1) ? cosf(ang) : sinf(ang);
  const int* f = tf + bt * 5;
  float v = pe + em[f[0] * D_ + d] + eh[f[1] * D_ + d] + ew[f[2] * D_ + d] +
            emo[f[3] * D_ + d] + ey[f[4] * D_ + d];
  tcpe[idx] = v;
}

__device__ inline float wave_sum(float v) {
#pragma unroll
  for (int off = 32; off >= 1; off >>= 1) v += __shfl_xor(v, off);
  return v;
}
__device__ inline float wave_max(float v) {
#pragma unroll
  for (int off = 32; off >= 1; off >>= 1) v = fmaxf(v, __shfl_xor(v, off));
  return v;
}

// ---------------- kernel 2: enc = x+tcpe (LDS only); Q,K,V → global (fp32)
__global__ __launch_bounds__(256) void qkv_kernel(
    const float* __restrict__ x, const float* __restrict__ tcpe,
    const float* __restrict__ Wq, const float* __restrict__ Wk,
    const float* __restrict__ Wv, float* __restrict__ Qg,
    float* __restrict__ Kg, float* __restrict__ Vg) {
  __shared__ float s_enc[T_ * SE];
  const int tid = threadIdx.x;
  const int lane = tid & 63;
  const int g = tid >> 6;
  const int bn = blockIdx.x;
  const int b = bn / N_;
  {
    const float4* x4 = (const float4*)(x + (size_t)bn * (T_ * D_));
    const float4* t4 = (const float4*)(tcpe + (size_t)b * (T_ * D_));
#pragma unroll
    for (int r = 0; r < 3; ++r) {
      int i = tid + 256 * r;
      float4 xv = x4[i];
      float4 tv = t4[i];
      int t = i >> 4;
      int d = (i & 15) << 2;
      *(float4*)&s_enc[t * SE + d] =
          make_float4(xv.x + tv.x, xv.y + tv.y, xv.z + tv.z, xv.w + tv.w);
    }
  }
  __syncthreads();
  const float* Ws[3] = {Wq, Wk, Wv};
  float* Gs[3] = {Qg, Kg, Vg};
#pragma unroll 1
  for (int m = 0; m < 3; ++m) {
    float w[64];
#pragma unroll
    for (int k = 0; k < 64; ++k) w[k] = Ws[m][k * D_ + lane];
    float* gp = Gs[m] + (size_t)bn * (T_ * D_);
    for (int tt = 0; tt < 12; ++tt) {
      int t = g * 12 + tt;
      float acc = 0.0f;
#pragma unroll
      for (int k = 0; k < 64; k += 4) {
        float4 e = *(const float4*)&s_enc[t * SE + k];
        acc = fmaf(e.x, w[k + 0], acc);
        acc = fmaf(e.y, w[k + 1], acc);
        acc = fmaf(e.z, w[k + 2], acc);
        acc = fmaf(e.w, w[k + 3], acc);
      }
      gp[t * D_ + lane] = acc;
    }
  }
}

// ---------------- kernel 3: per-(b,n,h) ProbSparse attention; ctx → V in place
__global__ __launch_bounds__(64) void attn_kernel(const float* __restrict__ Qg,
                                                  const float* __restrict__ Kg,
                                                  float* __restrict__ Vg,
                                                  const int* __restrict__ idxs) {
  __shared__ float s_q[T_ * SH];
  __shared__ float s_k[T_ * SH];
  __shared__ float s_v[T_ * SH];
  __shared__ float s_attn[SK_ * T_];
  __shared__ float s_M[T_];
  __shared__ float s_vmean[HD_];
  __shared__ int s_mtop[SK_];
  const int lane = threadIdx.x;
  const int bn = blockIdx.x;
  const int h = blockIdx.y;
  const size_t base = (size_t)bn * (T_ * D_) + h * HD_;
  for (int i = lane; i < 192; i += 64) {
    int t = i >> 2, j = (i & 3) << 2;
    *(float4*)&s_q[t * SH + j] = *(const float4*)&Qg[base + t * D_ + j];
    *(float4*)&s_k[t * SH + j] = *(const float4*)&Kg[base + t * D_ + j];
    *(float4*)&s_v[t * SH + j] = *(const float4*)&Vg[base + t * D_ + j];
  }
  __syncthreads();
  if (lane < T_) {
    float q[16];
#pragma unroll
    for (int j = 0; j < 16; j += 4) {
      float4 v4 = *(const float4*)&s_q[lane * SH + j];
      q[j] = v4.x; q[j + 1] = v4.y; q[j + 2] = v4.z; q[j + 3] = v4.w;
    }
    float mx = -1e30f, sm = 0.0f;
    for (int s = 0; s < SK_; ++s) {
      int kt = idxs[lane * SK_ + s];
      float acc = 0.0f;
#pragma unroll
      for (int j = 0; j < 16; j += 4) {
        float4 kv = *(const float4*)&s_k[kt * SH + j];
        acc = fmaf(kv.x, q[j], acc);
        acc = fmaf(kv.y, q[j + 1], acc);
        acc = fmaf(kv.z, q[j + 2], acc);
        acc = fmaf(kv.w, q[j + 3], acc);
      }
      mx = fmaxf(mx, acc);
      sm += acc;
    }
    s_M[lane] = mx - sm * (1.0f / (float)SK_);
  }
  __syncthreads();
  if (lane < T_) {
    float mv = s_M[lane];
    int rank = 0;
    for (int t2 = 0; t2 < T_; ++t2) {
      float o = s_M[t2];
      rank += (o > mv || (o == mv && t2 < lane)) ? 1 : 0;
    }
    if (rank < SK_) s_mtop[rank] = lane;
  }
  __syncthreads();
  {
    float kr[16];
    if (lane < T_) {
#pragma unroll
      for (int j = 0; j < 16; j += 4) {
        float4 v4 = *(const float4*)&s_k[lane * SH + j];
        kr[j] = v4.x; kr[j + 1] = v4.y; kr[j + 2] = v4.z; kr[j + 3] = v4.w;
      }
    } else {
#pragma unroll
      for (int j = 0; j < 16; ++j) kr[j] = 0.0f;
    }
    for (int u = 0; u < SK_; ++u) {
      int qt = s_mtop[u];
      float acc = 0.0f;
#pragma unroll
      for (int j = 0; j < 16; j += 4) {
        float4 qv = *(const float4*)&s_q[qt * SH + j];
        acc = fmaf(qv.x, kr[j], acc);
        acc = fmaf(qv.y, kr[j + 1], acc);
        acc = fmaf(qv.z, kr[j + 2], acc);
        acc = fmaf(qv.w, kr[j + 3], acc);
      }
      float sc = (lane < T_) ? acc * 0.25f : -1e30f;
      float mx = wave_max(sc);
      float e = (lane < T_) ? __expf(sc - mx) : 0.0f;
      float es = wave_sum(e);
      if (lane < T_) s_attn[u * T_ + lane] = e / es;
    }
  }
  __syncthreads();
  float upd[5];
#pragma unroll
  for (int r = 0; r < 5; ++r) {
    int i = lane + 64 * r;
    int u = i >> 4, j = i & 15;
    float acc = 0.0f;
#pragma unroll 4
    for (int t = 0; t < T_; ++t)
      acc = fmaf(s_attn[u * T_ + t], s_v[t * SH + j], acc);
    upd[r] = acc;
  }
  if (lane < HD_) {
    float acc = 0.0f;
    for (int t = 0; t < T_; ++t) acc += s_v[t * SH + lane];
    s_vmean[lane] = acc * (1.0f / (float)T_);
  }
  __syncthreads();
#pragma unroll
  for (int r = 0; r < 12; ++r) {
    int i = lane + 64 * r;
    int t = i >> 4, j = i & 15;
    s_v[t * SH + j] = s_vmean[j];
  }
  __syncthreads();
#pragma unroll
  for (int r = 0; r < 5; ++r) {
    int i = lane + 64 * r;
    int u = i >> 4, j = i & 15;
    s_v[s_mtop[u] * SH + j] = upd[r];
  }
  __syncthreads();
  for (int i = lane; i < 192; i += 64) {
    int t = i >> 2, j = (i & 3) << 2;
    *(float4*)&Vg[base + t * D_ + j] = *(const float4*)&s_v[t * SH + j];
  }
}

// ---------------- kernel 4a: pre-swizzle Wo/W1/W2 into bf16 MFMA B-frag order
// layout: frag f=(ko*NT+no); flat idx = (f*64 + lane)*8 + e;
// element = W[ko*32 + (lane>>4)*8 + e][no*16 + (lane&15)]
__global__ void wswz_kernel(const float* __restrict__ Wo,
                            const float* __restrict__ W1,
                            const float* __restrict__ W2,
                            ushort* __restrict__ WoB, ushort* __restrict__ W1B,
                            ushort* __restrict__ W2B) {
  int idx = blockIdx.x * 256 + threadIdx.x;
  if (idx >= 4096 + 16384 + 16384) return;
  const float* W;
  ushort* O;
  int NT, N;
  if (idx < 4096) {
    W = Wo; O = WoB; NT = 4; N = 64;
  } else if (idx < 4096 + 16384) {
    idx -= 4096; W = W1; O = W1B; NT = 16; N = 256;
  } else {
    idx -= 20480; W = W2; O = W2B; NT = 4; N = 64;
  }
  int e = idx & 7;
  int l = (idx >> 3) & 63;
  int f = idx >> 9;
  int no = f % NT, ko = f / NT;
  int k = ko * 32 + (l >> 4) * 8 + e;
  int n = no * 16 + (l & 15);
  O[idx] = f2bf(W[k * N + n]);
}

// ---------------- kernel 4b: MFMA tail — Wo+LN1+FFN+LN2 over 64-row blocks
__global__ __launch_bounds__(256) void tail_mfma_kernel(
    const float* __restrict__ x, const float* __restrict__ tcpe,
    const float* __restrict__ ctxG, const ushort* __restrict__ WoB,
    const ushort* __restrict__ W1B, const ushort* __restrict__ W2B,
    const float* __restrict__ bo, const float* __restrict__ b1,
    const float* __restrict__ b2, const float* __restrict__ g1,
    const float* __restrict__ be1, const float* __restrict__ g2,
    const float* __restrict__ be2, float* __restrict__ out) {
  __shared__ ushort s_ht[4][16 * STH];
  __shared__ ushort s_ft[4][16 * STF];
  const int tid = threadIdx.x;
  const int w = tid >> 6;
  const int l = tid & 63;
  const int g = l >> 4;   // quarter-wave (k-group / C row-group)
  const int c = l & 15;   // column within tile / A row
  const int R0 = blockIdx.x * 64 + w * 16;
  ushort* ht = s_ht[w];
  ushort* ft = s_ft[w];
  const f32x4 z = {0.f, 0.f, 0.f, 0.f};

  // row descriptors for my 4 C-rows (row = g*4+reg within stripe)
  int rbase[4], tbase[4];
#pragma unroll
  for (int reg = 0; reg < 4; ++reg) {
    int r = R0 + g * 4 + reg;
    int bn = r / T_;
    int t = r - bn * T_;
    int b = bn / N_;
    rbase[reg] = r * D_;
    tbase[reg] = (b * T_ + t) * D_;
  }

  // stage ctx stripe → bf16 LDS tile (per-wave private; no __syncthreads)
  {
    int i = l >> 2;            // row 0..15
    int cb = l & 3;            // 16-float col block
    const float* src = ctxG + (size_t)(R0 + i) * D_ + cb * 16;
    float4 v0 = *(const float4*)(src);
    float4 v1 = *(const float4*)(src + 4);
    float4 v2 = *(const float4*)(src + 8);
    float4 v3 = *(const float4*)(src + 12);
    ushort* dst = ht + i * STH + cb * 16;
    uint4 p0, p1;
    p0.x = (uint)f2bf(v0.x) | ((uint)f2bf(v0.y) << 16);
    p0.y = (uint)f2bf(v0.z) | ((uint)f2bf(v0.w) << 16);
    p0.z = (uint)f2bf(v1.x) | ((uint)f2bf(v1.y) << 16);
    p0.w = (uint)f2bf(v1.z) | ((uint)f2bf(v1.w) << 16);
    p1.x = (uint)f2bf(v2.x) | ((uint)f2bf(v2.y) << 16);
    p1.y = (uint)f2bf(v2.z) | ((uint)f2bf(v2.w) << 16);
    p1.z = (uint)f2bf(v3.x) | ((uint)f2bf(v3.y) << 16);
    p1.w = (uint)f2bf(v3.z) | ((uint)f2bf(v3.w) << 16);
    *(uint4*)(dst) = p0;
    *(uint4*)(dst + 8) = p1;
  }

  f32x4 acc[16];
  // Wo GEMM: C[16x64] = ctx[16x64] @ Wo
  {
    bf16x8 a0 = *(const bf16x8*)(const void*)(ht + c * STH + g * 8);
    bf16x8 a1 = *(const bf16x8*)(const void*)(ht + c * STH + 32 + g * 8);
#pragma unroll
    for (int no = 0; no < 4; ++no) {
      bf16x8 b0 = *(const bf16x8*)(const void*)(WoB + (no * 64 + l) * 8);
      bf16x8 b1f = *(const bf16x8*)(const void*)(WoB + ((4 + no) * 64 + l) * 8);
      f32x4 t0 = __builtin_amdgcn_mfma_f32_16x16x32_bf16(a0, b0, z, 0, 0, 0);
      acc[no] = __builtin_amdgcn_mfma_f32_16x16x32_bf16(a1, b1f, t0, 0, 0, 0);
    }
  }

  // + bo + enc(residual), LN1 → h (kept fp32 in regs; bf16 copy → LDS)
  float h[16];
#pragma unroll
  for (int no = 0; no < 4; ++no) {
    int col = no * 16 + c;
    float bov = bo[col];
#pragma unroll
    for (int reg = 0; reg < 4; ++reg)
      h[no * 4 + reg] = acc[no][reg] + bov + x[rbase[reg] + col] +
                        tcpe[tbase[reg] + col];
  }
#pragma unroll
  for (int reg = 0; reg < 4; ++reg) {
    float s = h[reg] + h[4 + reg] + h[8 + reg] + h[12 + reg];
    s += __shfl_xor(s, 1); s += __shfl_xor(s, 2);
    s += __shfl_xor(s, 4); s += __shfl_xor(s, 8);
    float mean = s * (1.0f / 64.0f);
    float d0 = h[reg] - mean, d1 = h[4 + reg] - mean;
    float d2 = h[8 + reg] - mean, d3 = h[12 + reg] - mean;
    float q = d0 * d0 + d1 * d1 + d2 * d2 + d3 * d3;
    q += __shfl_xor(q, 1); q += __shfl_xor(q, 2);
    q += __shfl_xor(q, 4); q += __shfl_xor(q, 8);
    float rstd = 1.0f / sqrtf(q * (1.0f / 64.0f) + EPS_);
#pragma unroll
    for (int no = 0; no < 4; ++no) {
      int col = no * 16 + c;
      h[no * 4 + reg] = (h[no * 4 + reg] - mean) * rstd * g1[col] + be1[col];
    }
  }
#pragma unroll
  for (int no = 0; no < 4; ++no)
#pragma unroll
    for (int reg = 0; reg < 4; ++reg)
      ht[(g * 4 + reg) * STH + no * 16 + c] = f2bf(h[no * 4 + reg]);

  // W1 GEMM: f1[16x256] = h[16x64] @ W1
  {
    bf16x8 a0 = *(const bf16x8*)(const void*)(ht + c * STH + g * 8);
    bf16x8 a1 = *(const bf16x8*)(const void*)(ht + c * STH + 32 + g * 8);
#pragma unroll
    for (int no = 0; no < 16; ++no) {
      bf16x8 b0 = *(const bf16x8*)(const void*)(W1B + (no * 64 + l) * 8);
      bf16x8 b1f =
          *(const bf16x8*)(const void*)(W1B + ((16 + no) * 64 + l) * 8);
      f32x4 t0 = __builtin_amdgcn_mfma_f32_16x16x32_bf16(a0, b0, z, 0, 0, 0);
      acc[no] = __builtin_amdgcn_mfma_f32_16x16x32_bf16(a1, b1f, t0, 0, 0, 0);
    }
  }
  // bias + relu → bf16 f1 tile
#pragma unroll
  for (int no = 0; no < 16; ++no) {
    float bb = b1[no * 16 + c];
#pragma unroll
    for (int reg = 0; reg < 4; ++reg) {
      float vv = fmaxf(acc[no][reg] + bb, 0.0f);
      ft[(g * 4 + reg) * STF + no * 16 + c] = f2bf(vv);
    }
  }

  // W2 GEMM: o[16x64] = f1[16x256] @ W2
  f32x4 o[4] = {z, z, z, z};
#pragma unroll
  for (int ko = 0; ko < 8; ++ko) {
    bf16x8 fa = *(const bf16x8*)(const void*)(ft + c * STF + ko * 32 + g * 8);
#pragma unroll
    for (int no = 0; no < 4; ++no) {
      bf16x8 bf_ =
          *(const bf16x8*)(const void*)(W2B + ((ko * 4 + no) * 64 + l) * 8);
      o[no] = __builtin_amdgcn_mfma_f32_16x16x32_bf16(fa, bf_, o[no], 0, 0, 0);
    }
  }

  // + b2 + h, LN2 → out
  float v[16];
#pragma unroll
  for (int no = 0; no < 4; ++no) {
    float b2v = b2[no * 16 + c];
#pragma unroll
    for (int reg = 0; reg < 4; ++reg)
      v[no * 4 + reg] = o[no][reg] + b2v + h[no * 4 + reg];
  }
#pragma unroll
  for (int reg = 0; reg < 4; ++reg) {
    float s = v[reg] + v[4 + reg] + v[8 + reg] + v[12 + reg];
    s += __shfl_xor(s, 1); s += __shfl_xor(s, 2);
    s += __shfl_xor(s, 4); s += __shfl_xor(s, 8);
    float mean = s * (1.0f / 64.0f);
    float d0 = v[reg] - mean, d1 = v[4 + reg] - mean;
    float d2 = v[8 + reg] - mean, d3 = v[12 + reg] - mean;
    float q = d0 * d0 + d1 * d1 + d2 * d2 + d3 * d3;
    q += __shfl_xor(q, 1); q += __shfl_xor(q, 2);
    q += __shfl_xor(q, 4); q += __shfl_xor(q, 8);
    float rstd = 1.0f / sqrtf(q * (1.0f / 64.0f) + EPS_);
#pragma unroll
    for (int no = 0; no < 4; ++no) {
      int col = no * 16 + c;
      out[rbase[reg] + col] =
          (v[no * 4 + reg] - mean) * rstd * g2[col] + be2[col];
    }
  }
}

// ---------------- fallback tail (fp32, round-2 version)
__global__ __launch_bounds__(256) void tail_kernel(
    const float* __restrict__ x, const float* __restrict__ tcpe,
    const float* __restrict__ ctxG, const float* __restrict__ Wo,
    const float* __restrict__ bo, const float* __restrict__ W1,
    const float* __restrict__ b1, const float* __restrict__ W2,
    const float* __restrict__ b2, const float* __restrict__ g1,
    const float* __restrict__ be1, const float* __restrict__ g2,
    const float* __restrict__ be2, float* __restrict__ out) {
  __shared__ float s_ctx[T_ * SE];
  __shared__ float s_h[T_ * SE];
  __shared__ float s_ff1[T_ * SE];
  const int tid = threadIdx.x;
  const int lane = tid & 63;
  const int g = tid >> 6;
  const int bn = blockIdx.x;
  const int b = bn / N_;
  {
    const float4* c4 = (const float4*)(ctxG + (size_t)bn * (T_ * D_));
#pragma unroll
    for (int r = 0; r < 3; ++r) {
      int i = tid + 256 * r;
      int t = i >> 4;
      int d = (i & 15) << 2;
      *(float4*)&s_ctx[t * SE + d] = c4[i];
    }
  }
  __syncthreads();
  {
    float w[64];
#pragma unroll
    for (int k = 0; k < 64; ++k) w[k] = Wo[k * D_ + lane];
    float bov = bo[lane];
    float g1v = g1[lane], be1v = be1[lane];
    const float* xp = x + (size_t)bn * (T_ * D_);
    const float* tp = tcpe + (size_t)b * (T_ * D_);
    for (int tt = 0; tt < 12; ++tt) {
      int t = g * 12 + tt;
      float acc = bov;
#pragma unroll
      for (int k = 0; k < 64; k += 4) {
        float4 e = *(const float4*)&s_ctx[t * SE + k];
        acc = fmaf(e.x, w[k], acc);
        acc = fmaf(e.y, w[k + 1], acc);
        acc = fmaf(e.z, w[k + 2], acc);
        acc = fmaf(e.w, w[k + 3], acc);
      }
      float val = acc + xp[t * D_ + lane] + tp[t * D_ + lane];
      float m = wave_sum(val) * (1.0f / 64.0f);
      float dv = val - m;
      float var = wave_sum(dv * dv) * (1.0f / 64.0f);
      s_h[t * SE + lane] = dv * (1.0f / sqrtf(var + EPS_)) * g1v + be1v;
    }
  }
  __syncthreads();
  float ffacc[12];
#pragma unroll
  for (int i = 0; i < 12; ++i) ffacc[i] = 0.0f;
  for (int jc = 0; jc < 4; ++jc) {
    {
      float w[64];
#pragma unroll
      for (int k = 0; k < 64; ++k) w[k] = W1[k * DFF_ + jc * 64 + lane];
      float bb = b1[jc * 64 + lane];
      for (int tt = 0; tt < 12; ++tt) {
        int t = g * 12 + tt;
        float acc = bb;
#pragma unroll
        for (int k = 0; k < 64; k += 4) {
          float4 e = *(const float4*)&s_h[t * SE + k];
          acc = fmaf(e.x, w[k], acc);
          acc = fmaf(e.y, w[k + 1], acc);
          acc = fmaf(e.z, w[k + 2], acc);
          acc = fmaf(e.w, w[k + 3], acc);
        }
        s_ff1[t * SE + lane] = fmaxf(acc, 0.0f);
      }
    }
    __syncthreads();
    {
      float w[64];
#pragma unroll
      for (int k = 0; k < 64; ++k) w[k] = W2[(jc * 64 + k) * D_ + lane];
      for (int tt = 0; tt < 12; ++tt) {
        int t = g * 12 + tt;
        float acc = ffacc[tt];
#pragma unroll
        for (int k = 0; k < 64; k += 4) {
          float4 e = *(const float4*)&s_ff1[t * SE + k];
          acc = fmaf(e.x, w[k], acc);
          acc = fmaf(e.y, w[k + 1], acc);
          acc = fmaf(e.z, w[k + 2], acc);
          acc = fmaf(e.w, w[k + 3], acc);
        }
        ffacc[tt] = acc;
      }
    }
    __syncthreads();
  }
  {
    float g2v = g2[lane], be2v = be2[lane], b2v = b2[lane];
    float* op = out + (size_t)bn * (T_ * D_);
    for (int tt = 0; tt < 12; ++tt) {
      int t = g * 12 + tt;
      float val = ffacc[tt] + b2v + s_h[t * SE + lane];
      float m = wave_sum(val) * (1.0f / 64.0f);
      float dv = val - m;
      float var = wave_sum(dv * dv) * (1.0f / 64.0f);
      op[t * D_ + lane] = dv * (1.0f / sqrtf(var + EPS_)) * g2v + be2v;
    }
  }
}

extern "C" void kernel_launch(void* const* d_in, const int* in_sizes, int n_in,
                              void* d_out, int out_size, void* d_ws,
                              size_t ws_size, hipStream_t stream) {
  const float* x = (const float*)d_in[0];
  const int* tf = (const int*)d_in[1];
  const int* idxs = (const int*)d_in[2];
  const float* Wq = (const float*)d_in[3];
  const float* Wk = (const float*)d_in[4];
  const float* Wv = (const float*)d_in[5];
  const float* Wo = (const float*)d_in[6];
  const float* bo = (const float*)d_in[7];
  const float* W1 = (const float*)d_in[8];
  const float* b1 = (const float*)d_in[9];
  const float* W2 = (const float*)d_in[10];
  const float* b2 = (const float*)d_in[11];
  const float* g1 = (const float*)d_in[12];
  const float* be1 = (const float*)d_in[13];
  const float* g2 = (const float*)d_in[14];
  const float* be2 = (const float*)d_in[15];
  const float* em = (const float*)d_in[16];
  const float* eh = (const float*)d_in[17];
  const float* ew = (const float*)d_in[18];
  const float* emo = (const float*)d_in[19];
  const float* ey = (const float*)d_in[20];
  float* out = (float*)d_out;

  float* tcpe = (float*)d_ws;  // 24576 f32
  float* Qg = tcpe + 24576;
  float* Kg = Qg + BNTD;
  float* Vg = Kg + BNTD;
  ushort* WoB = (ushort*)(Vg + BNTD);
  ushort* W1B = WoB + 4096;
  ushort* W2B = W1B + 16384;
  size_t need_old = (size_t)(24576 + 3 * (size_t)BNTD) * sizeof(float);
  size_t need_new = need_old + (4096 + 16384 + 16384) * sizeof(ushort);

  hipLaunchKernelGGL(tcpe_kernel, dim3((B_ * T_ * D_ + 255) / 256), dim3(256),
                     0, stream, tf, em, eh, ew, emo, ey, tcpe);
  hipLaunchKernelGGL(qkv_kernel, dim3(B_ * N_), dim3(256), 0, stream, x, tcpe,
                     Wq, Wk, Wv, Qg, Kg, Vg);
  hipLaunchKernelGGL(attn_kernel, dim3(B_ * N_, H_), dim3(64), 0, stream, Qg,
                     Kg, Vg, idxs);
  if (ws_size >= need_new) {
    hipLaunchKernelGGL(wswz_kernel, dim3((36864 + 255) / 256), dim3(256), 0,
                       stream, Wo, W1, W2, WoB, W1B, W2B);
    hipLaunchKernelGGL(tail_mfma_kernel, dim3(ROWS / 64), dim3(256), 0, stream,
                       x, tcpe, Vg, WoB, W1B, W2B, bo, b1, b2, g1, be1, g2,
                       be2, out);
  } else {
    hipLaunchKernelGGL(tail_kernel, dim3(B_ * N_), dim3(256), 0, stream, x,
                       tcpe, Vg, Wo, bo, W1, b1, W2, b2, g1, be1, g2, be2,
                       out);
  }
}

// Round 4
// 232.720 us; speedup vs baseline: 5.0173x; 1.1834x over previous
//
#include <hip/hip_runtime.h>

#define B_ 8
#define N_ 307
#define T_ 48
#define D_ 64
#define H_ 4
#define HD_ 16
#define SK_ 20
#define DFF_ 256
#define EPS_ 1e-5f
#define SE 68    // fp32 row stride for t-indexed LDS tiles (272B, 16B-aligned)
#define STH 72   // bf16 row stride, h/ctx tile (144B)
#define STF 264  // bf16 row stride, f1 tile (528B)

typedef __attribute__((ext_vector_type(8))) short bf16x8;
typedef __attribute__((ext_vector_type(4))) float f32x4;

__device__ inline ushort f2bf(float f) {
  union { float f; uint u; } x;
  x.f = f;
  uint u = x.u;
  return (ushort)((u + 0x7fffu + ((u >> 16) & 1u)) >> 16);  // RNE
}

// ---------------- kernel 1: pe[t] + time-feature embeddings → tcpe[B][T][64]
__global__ void tcpe_kernel(const int* __restrict__ tf,
                            const float* __restrict__ em,
                            const float* __restrict__ eh,
                            const float* __restrict__ ew,
                            const float* __restrict__ emo,
                            const float* __restrict__ ey,
                            float* __restrict__ tcpe) {
  int idx = blockIdx.x * 256 + threadIdx.x;  // B*T*64 = 24576
  if (idx >= B_ * T_ * D_) return;
  int d = idx & (D_ - 1);
  int bt = idx >> 6;
  int t = bt % T_;
  float freq = expf((float)((d >> 1) << 1) * (-logf(10000.0f) / (float)D_));
  float ang = (float)t * freq;
  float pe = (d & 1) ? cosf(ang) : sinf(ang);
  const int* f = tf + bt * 5;
  float v = pe + em[f[0] * D_ + d] + eh[f[1] * D_ + d] + ew[f[2] * D_ + d] +
            emo[f[3] * D_ + d] + ey[f[4] * D_ + d];
  tcpe[idx] = v;
}

__device__ inline float wave_sum(float v) {
#pragma unroll
  for (int off = 32; off >= 1; off >>= 1) v += __shfl_xor(v, off);
  return v;
}
__device__ inline float wave_max(float v) {
#pragma unroll
  for (int off = 32; off >= 1; off >>= 1) v = fmaxf(v, __shfl_xor(v, off));
  return v;
}

// ---------------- kernel 2: pre-swizzle Wo/W1/W2 into bf16 MFMA B-frag order
// frag f=(ko*NT+no); flat idx = (f*64 + lane)*8 + e;
// element = W[ko*32 + (lane>>4)*8 + e][no*16 + (lane&15)]
__global__ void wswz_kernel(const float* __restrict__ Wo,
                            const float* __restrict__ W1,
                            const float* __restrict__ W2,
                            ushort* __restrict__ WoB, ushort* __restrict__ W1B,
                            ushort* __restrict__ W2B) {
  int idx = blockIdx.x * 256 + threadIdx.x;
  if (idx >= 4096 + 16384 + 16384) return;
  const float* W;
  ushort* O;
  int NT, N;
  if (idx < 4096) {
    W = Wo; O = WoB; NT = 4; N = 64;
  } else if (idx < 4096 + 16384) {
    idx -= 4096; W = W1; O = W1B; NT = 16; N = 256;
  } else {
    idx -= 20480; W = W2; O = W2B; NT = 4; N = 64;
  }
  int e = idx & 7;
  int l = (idx >> 3) & 63;
  int f = idx >> 9;
  int no = f % NT, ko = f / NT;
  int k = ko * 32 + (l >> 4) * 8 + e;
  int n = no * 16 + (l & 15);
  O[idx] = f2bf(W[k * N + n]);
}

// 48x64 fp32 GEMM tile: wave g computes rows t=g*12..g*12+11, lane = out col.
__device__ inline void gemm_tile(const float* src, const float* __restrict__ W,
                                 float* dst, int lane, int g) {
  float w[64];
#pragma unroll
  for (int k = 0; k < 64; ++k) w[k] = W[k * D_ + lane];
  for (int tt = 0; tt < 12; ++tt) {
    int t = g * 12 + tt;
    float acc = 0.0f;
#pragma unroll
    for (int k = 0; k < 64; k += 4) {
      float4 e = *(const float4*)&src[t * SE + k];
      acc = fmaf(e.x, w[k + 0], acc);
      acc = fmaf(e.y, w[k + 1], acc);
      acc = fmaf(e.z, w[k + 2], acc);
      acc = fmaf(e.w, w[k + 3], acc);
    }
    dst[t * SE + lane] = acc;
  }
}

// ---------------- kernel 3: the whole layer, one block per (b,n)
// LDS overlay (byte offsets into smem[69120]):
//   phase QKV/attn: enc@0  q@13056  k@26112  v@39168  attn@52224 (ends 67584)
//   phase tail:     enc@0  ctx@13056(=q)  ht@26112(4x2304)  ft@35328(4x8448)
// liveness: k,v,attn dead after the post-scatter barrier; q dead after scores.
__global__ __launch_bounds__(256) void mega_kernel(
    const float* __restrict__ x, const int* __restrict__ idxs,
    const float* __restrict__ Wq, const float* __restrict__ Wk,
    const float* __restrict__ Wv, const ushort* __restrict__ WoB,
    const ushort* __restrict__ W1B, const ushort* __restrict__ W2B,
    const float* __restrict__ bo, const float* __restrict__ b1,
    const float* __restrict__ b2, const float* __restrict__ g1,
    const float* __restrict__ be1, const float* __restrict__ g2,
    const float* __restrict__ be2, const float* __restrict__ tcpe,
    float* __restrict__ out) {
  __shared__ char smem[69120];
  __shared__ float s_M[H_ * T_];
  __shared__ float s_vmean[H_ * HD_];
  __shared__ int s_mtop[H_ * SK_];
  float* s_enc = (float*)smem;
  float* s_q = (float*)(smem + 13056);
  float* s_k = (float*)(smem + 26112);
  float* s_v = (float*)(smem + 39168);
  float* s_attn = (float*)(smem + 52224);
  float* s_ctx = s_q;

  const int tid = threadIdx.x;
  const int l = tid & 63;
  const int g = tid >> 6;  // wave id == head id == tail row-stripe id
  const int bn = blockIdx.x;
  const int b = bn / N_;

  // ---- P0: enc = x + tcpe
  {
    const float4* x4 = (const float4*)(x + (size_t)bn * (T_ * D_));
    const float4* t4 = (const float4*)(tcpe + (size_t)b * (T_ * D_));
#pragma unroll
    for (int r = 0; r < 3; ++r) {
      int i = tid + 256 * r;  // 768 float4s
      float4 xv = x4[i];
      float4 tv = t4[i];
      int t = i >> 4;
      int d = (i & 15) << 2;
      *(float4*)&s_enc[t * SE + d] =
          make_float4(xv.x + tv.x, xv.y + tv.y, xv.z + tv.z, xv.w + tv.w);
    }
  }
  __syncthreads();

  // ---- P1: Q,K,V = enc @ W{q,k,v}  (fp32 — selection precision)
  gemm_tile(s_enc, Wq, s_q, l, g);
  gemm_tile(s_enc, Wk, s_k, l, g);
  gemm_tile(s_enc, Wv, s_v, l, g);
  __syncthreads();

  // ---- P2a: M[t] = max_s q·k_samp − mean_s
  if (l < T_) {
    float q[16];
#pragma unroll
    for (int j = 0; j < 16; j += 4) {
      float4 v4 = *(const float4*)&s_q[l * SE + g * HD_ + j];
      q[j] = v4.x; q[j + 1] = v4.y; q[j + 2] = v4.z; q[j + 3] = v4.w;
    }
    float mx = -1e30f, sm = 0.0f;
    for (int s = 0; s < SK_; ++s) {
      int kt = idxs[l * SK_ + s];
      float acc = 0.0f;
#pragma unroll
      for (int j = 0; j < 16; j += 4) {
        float4 kv = *(const float4*)&s_k[kt * SE + g * HD_ + j];
        acc = fmaf(kv.x, q[j], acc);
        acc = fmaf(kv.y, q[j + 1], acc);
        acc = fmaf(kv.z, q[j + 2], acc);
        acc = fmaf(kv.w, q[j + 3], acc);
      }
      mx = fmaxf(mx, acc);
      sm += acc;
    }
    s_M[g * T_ + l] = mx - sm * (1.0f / (float)SK_);
  }
  __syncthreads();

  // ---- P2b: top-20 by rank (jax.lax.top_k tie-break: lower index first)
  if (l < T_) {
    float mv = s_M[g * T_ + l];
    int rank = 0;
    for (int t2 = 0; t2 < T_; ++t2) {
      float o = s_M[g * T_ + t2];
      rank += (o > mv || (o == mv && t2 < l)) ? 1 : 0;
    }
    if (rank < SK_) s_mtop[g * SK_ + rank] = l;
  }
  __syncthreads();

  // ---- P2c: scores + softmax (lane = key position)
  {
    float kr[16];
    if (l < T_) {
#pragma unroll
      for (int j = 0; j < 16; j += 4) {
        float4 v4 = *(const float4*)&s_k[l * SE + g * HD_ + j];
        kr[j] = v4.x; kr[j + 1] = v4.y; kr[j + 2] = v4.z; kr[j + 3] = v4.w;
      }
    } else {
#pragma unroll
      for (int j = 0; j < 16; ++j) kr[j] = 0.0f;
    }
    for (int u = 0; u < SK_; ++u) {
      int qt = s_mtop[g * SK_ + u];
      float acc = 0.0f;
#pragma unroll
      for (int j = 0; j < 16; j += 4) {
        float4 qv = *(const float4*)&s_q[qt * SE + g * HD_ + j];  // broadcast
        acc = fmaf(qv.x, kr[j], acc);
        acc = fmaf(qv.y, kr[j + 1], acc);
        acc = fmaf(qv.z, kr[j + 2], acc);
        acc = fmaf(qv.w, kr[j + 3], acc);
      }
      float sc = (l < T_) ? acc * 0.25f : -1e30f;  // 1/sqrt(16)
      float mx = wave_max(sc);
      float e = (l < T_) ? __expf(sc - mx) : 0.0f;
      float es = wave_sum(e);
      if (l < T_) s_attn[(g * SK_ + u) * T_ + l] = e / es;
    }
  }
  __syncthreads();  // q dead after this point

  // ---- P2d: upd = attn @ V ; vmean
  float upd[5];
#pragma unroll
  for (int r = 0; r < 5; ++r) {
    int i = l + 64 * r;  // 320 = 20x16
    int u = i >> 4, j = i & 15;
    float acc = 0.0f;
#pragma unroll 4
    for (int t = 0; t < T_; ++t)
      acc = fmaf(s_attn[(g * SK_ + u) * T_ + t], s_v[t * SE + g * HD_ + j],
                 acc);
    upd[r] = acc;
  }
  if (l < HD_) {
    float acc = 0.0f;
    for (int t = 0; t < T_; ++t) acc += s_v[t * SE + g * HD_ + l];
    s_vmean[g * HD_ + l] = acc * (1.0f / (float)T_);
  }
  __syncthreads();

  // ---- ctx = broadcast(vmean) into s_q region; then scatter upd rows
#pragma unroll
  for (int r = 0; r < 12; ++r) {
    int i = l + 64 * r;  // 768 = 48x16
    int t = i >> 4, j = i & 15;
    s_ctx[t * SE + g * HD_ + j] = s_vmean[g * HD_ + j];
  }
  __syncthreads();
#pragma unroll
  for (int r = 0; r < 5; ++r) {
    int i = l + 64 * r;
    int u = i >> 4, j = i & 15;
    s_ctx[s_mtop[g * SK_ + u] * SE + g * HD_ + j] = upd[r];
  }
  __syncthreads();  // k, v, attn dead after this point

  // ================= MFMA tail: per-wave, rows g*12..g*12+11 ===============
  ushort* ht = (ushort*)(smem + 26112) + g * (16 * STH);
  ushort* ft = (ushort*)(smem + 35328) + g * (16 * STF);
  const int kg = l >> 4;  // k-group / C row-group
  const int c = l & 15;   // column within 16-tile / A row
  const int row0 = g * 12;
  const f32x4 z = {0.f, 0.f, 0.f, 0.f};

  // stage ctx stripe → bf16 A-tile (rows 12-15 zero)
  {
    int rr = l >> 2;            // 0..15
    int cb = (l & 3) << 4;      // col block
    float4 v0 = {0, 0, 0, 0}, v1 = v0, v2 = v0, v3 = v0;
    if (rr < 12) {
      const float* src = &s_ctx[(row0 + rr) * SE + cb];
      v0 = *(const float4*)(src);
      v1 = *(const float4*)(src + 4);
      v2 = *(const float4*)(src + 8);
      v3 = *(const float4*)(src + 12);
    }
    ushort* dst = ht + rr * STH + cb;
    uint4 p0, p1;
    p0.x = (uint)f2bf(v0.x) | ((uint)f2bf(v0.y) << 16);
    p0.y = (uint)f2bf(v0.z) | ((uint)f2bf(v0.w) << 16);
    p0.z = (uint)f2bf(v1.x) | ((uint)f2bf(v1.y) << 16);
    p0.w = (uint)f2bf(v1.z) | ((uint)f2bf(v1.w) << 16);
    p1.x = (uint)f2bf(v2.x) | ((uint)f2bf(v2.y) << 16);
    p1.y = (uint)f2bf(v2.z) | ((uint)f2bf(v2.w) << 16);
    p1.z = (uint)f2bf(v3.x) | ((uint)f2bf(v3.y) << 16);
    p1.w = (uint)f2bf(v3.z) | ((uint)f2bf(v3.w) << 16);
    *(uint4*)(dst) = p0;
    *(uint4*)(dst + 8) = p1;
  }

  f32x4 acc[16];
  // Wo GEMM: C[16x64] = ctx[16x64] @ Wo
  {
    bf16x8 a0 = *(const bf16x8*)(const void*)(ht + c * STH + kg * 8);
    bf16x8 a1 = *(const bf16x8*)(const void*)(ht + c * STH + 32 + kg * 8);
#pragma unroll
    for (int no = 0; no < 4; ++no) {
      bf16x8 b0 = *(const bf16x8*)(const void*)(WoB + (no * 64 + l) * 8);
      bf16x8 b1f = *(const bf16x8*)(const void*)(WoB + ((4 + no) * 64 + l) * 8);
      f32x4 t0 = __builtin_amdgcn_mfma_f32_16x16x32_bf16(a0, b0, z, 0, 0, 0);
      acc[no] = __builtin_amdgcn_mfma_f32_16x16x32_bf16(a1, b1f, t0, 0, 0, 0);
    }
  }

  // + bo + enc residual (from LDS), LN1 → h regs; bf16 copy → ht
  float h[16];
  int er[4];
#pragma unroll
  for (int reg = 0; reg < 4; ++reg) {
    int cr = kg * 4 + reg;
    er[reg] = (row0 + (cr < 12 ? cr : 11)) * SE;  // clamp for pad rows
  }
#pragma unroll
  for (int no = 0; no < 4; ++no) {
    int col = no * 16 + c;
    float bov = bo[col];
#pragma unroll
    for (int reg = 0; reg < 4; ++reg)
      h[no * 4 + reg] = acc[no][reg] + bov + s_enc[er[reg] + col];
  }
#pragma unroll
  for (int reg = 0; reg < 4; ++reg) {
    float s = h[reg] + h[4 + reg] + h[8 + reg] + h[12 + reg];
    s += __shfl_xor(s, 1); s += __shfl_xor(s, 2);
    s += __shfl_xor(s, 4); s += __shfl_xor(s, 8);
    float mean = s * (1.0f / 64.0f);
    float d0 = h[reg] - mean, d1 = h[4 + reg] - mean;
    float d2 = h[8 + reg] - mean, d3 = h[12 + reg] - mean;
    float q = d0 * d0 + d1 * d1 + d2 * d2 + d3 * d3;
    q += __shfl_xor(q, 1); q += __shfl_xor(q, 2);
    q += __shfl_xor(q, 4); q += __shfl_xor(q, 8);
    float rstd = 1.0f / sqrtf(q * (1.0f / 64.0f) + EPS_);
#pragma unroll
    for (int no = 0; no < 4; ++no) {
      int col = no * 16 + c;
      h[no * 4 + reg] = (h[no * 4 + reg] - mean) * rstd * g1[col] + be1[col];
    }
  }
#pragma unroll
  for (int no = 0; no < 4; ++no)
#pragma unroll
    for (int reg = 0; reg < 4; ++reg)
      ht[(kg * 4 + reg) * STH + no * 16 + c] = f2bf(h[no * 4 + reg]);

  // W1 GEMM: f1[16x256] = h[16x64] @ W1
  {
    bf16x8 a0 = *(const bf16x8*)(const void*)(ht + c * STH + kg * 8);
    bf16x8 a1 = *(const bf16x8*)(const void*)(ht + c * STH + 32 + kg * 8);
#pragma unroll
    for (int no = 0; no < 16; ++no) {
      bf16x8 b0 = *(const bf16x8*)(const void*)(W1B + (no * 64 + l) * 8);
      bf16x8 b1f =
          *(const bf16x8*)(const void*)(W1B + ((16 + no) * 64 + l) * 8);
      f32x4 t0 = __builtin_amdgcn_mfma_f32_16x16x32_bf16(a0, b0, z, 0, 0, 0);
      acc[no] = __builtin_amdgcn_mfma_f32_16x16x32_bf16(a1, b1f, t0, 0, 0, 0);
    }
  }
  // bias + relu → bf16 f1 tile
#pragma unroll
  for (int no = 0; no < 16; ++no) {
    float bb = b1[no * 16 + c];
#pragma unroll
    for (int reg = 0; reg < 4; ++reg) {
      float vv = fmaxf(acc[no][reg] + bb, 0.0f);
      ft[(kg * 4 + reg) * STF + no * 16 + c] = f2bf(vv);
    }
  }

  // W2 GEMM: o[16x64] = f1[16x256] @ W2
  f32x4 o[4] = {z, z, z, z};
#pragma unroll
  for (int ko = 0; ko < 8; ++ko) {
    bf16x8 fa = *(const bf16x8*)(const void*)(ft + c * STF + ko * 32 + kg * 8);
#pragma unroll
    for (int no = 0; no < 4; ++no) {
      bf16x8 bf_ =
          *(const bf16x8*)(const void*)(W2B + ((ko * 4 + no) * 64 + l) * 8);
      o[no] = __builtin_amdgcn_mfma_f32_16x16x32_bf16(fa, bf_, o[no], 0, 0, 0);
    }
  }

  // + b2 + h, LN2 → out (store only valid rows cr<12)
  float v[16];
#pragma unroll
  for (int no = 0; no < 4; ++no) {
    float b2v = b2[no * 16 + c];
#pragma unroll
    for (int reg = 0; reg < 4; ++reg)
      v[no * 4 + reg] = o[no][reg] + b2v + h[no * 4 + reg];
  }
#pragma unroll
  for (int reg = 0; reg < 4; ++reg) {
    float s = v[reg] + v[4 + reg] + v[8 + reg] + v[12 + reg];
    s += __shfl_xor(s, 1); s += __shfl_xor(s, 2);
    s += __shfl_xor(s, 4); s += __shfl_xor(s, 8);
    float mean = s * (1.0f / 64.0f);
    float d0 = v[reg] - mean, d1 = v[4 + reg] - mean;
    float d2 = v[8 + reg] - mean, d3 = v[12 + reg] - mean;
    float q = d0 * d0 + d1 * d1 + d2 * d2 + d3 * d3;
    q += __shfl_xor(q, 1); q += __shfl_xor(q, 2);
    q += __shfl_xor(q, 4); q += __shfl_xor(q, 8);
    float rstd = 1.0f / sqrtf(q * (1.0f / 64.0f) + EPS_);
    int cr = kg * 4 + reg;
    if (cr < 12) {
      float* op = out + ((size_t)bn * T_ + row0 + cr) * D_;
#pragma unroll
      for (int no = 0; no < 4; ++no) {
        int col = no * 16 + c;
        op[col] = (v[no * 4 + reg] - mean) * rstd * g2[col] + be2[col];
      }
    }
  }
}

extern "C" void kernel_launch(void* const* d_in, const int* in_sizes, int n_in,
                              void* d_out, int out_size, void* d_ws,
                              size_t ws_size, hipStream_t stream) {
  const float* x = (const float*)d_in[0];
  const int* tf = (const int*)d_in[1];
  const int* idxs = (const int*)d_in[2];
  const float* Wq = (const float*)d_in[3];
  const float* Wk = (const float*)d_in[4];
  const float* Wv = (const float*)d_in[5];
  const float* Wo = (const float*)d_in[6];
  const float* bo = (const float*)d_in[7];
  const float* W1 = (const float*)d_in[8];
  const float* b1 = (const float*)d_in[9];
  const float* W2 = (const float*)d_in[10];
  const float* b2 = (const float*)d_in[11];
  const float* g1 = (const float*)d_in[12];
  const float* be1 = (const float*)d_in[13];
  const float* g2 = (const float*)d_in[14];
  const float* be2 = (const float*)d_in[15];
  const float* em = (const float*)d_in[16];
  const float* eh = (const float*)d_in[17];
  const float* ew = (const float*)d_in[18];
  const float* emo = (const float*)d_in[19];
  const float* ey = (const float*)d_in[20];
  float* out = (float*)d_out;

  float* tcpe = (float*)d_ws;  // 24576 f32 = 96 KiB
  ushort* WoB = (ushort*)((char*)d_ws + 98304);
  ushort* W1B = WoB + 4096;
  ushort* W2B = W1B + 16384;

  hipLaunchKernelGGL(tcpe_kernel, dim3((B_ * T_ * D_ + 255) / 256), dim3(256),
                     0, stream, tf, em, eh, ew, emo, ey, tcpe);
  hipLaunchKernelGGL(wswz_kernel, dim3((36864 + 255) / 256), dim3(256), 0,
                     stream, Wo, W1, W2, WoB, W1B, W2B);
  hipLaunchKernelGGL(mega_kernel, dim3(B_ * N_), dim3(256), 0, stream, x, idxs,
                     Wq, Wk, Wv, WoB, W1B, W2B, bo, b1, b2, g1, be1, g2, be2,
                     tcpe, out);
}

// Round 5
// 144.175 us; speedup vs baseline: 8.0986x; 1.6141x over previous
//
#include <hip/hip_runtime.h>

#define B_ 8
#define N_ 307
#define T_ 48
#define D_ 64
#define H_ 4
#define HD_ 16
#define SK_ 20
#define EPS_ 1e-5f

typedef __attribute__((ext_vector_type(8))) short bf16x8;
typedef __attribute__((ext_vector_type(4))) float f32x4;

__device__ inline ushort f2bf(float f) {
  union { float f; uint u; } x;
  x.f = f;
  uint u = x.u;
  return (ushort)((u + 0x7fffu + ((u >> 16) & 1u)) >> 16);  // RNE
}
__device__ inline float bflo(uint w) { return __uint_as_float(w << 16); }
__device__ inline float bfhi(uint w) {
  return __uint_as_float(w & 0xffff0000u);
}

// ---------------- kernel 1: pe[t] + time-feature embeddings → tcpe[B][T][64]
__global__ void tcpe_kernel(const int* __restrict__ tf,
                            const float* __restrict__ em,
                            const float* __restrict__ eh,
                            const float* __restrict__ ew,
                            const float* __restrict__ emo,
                            const float* __restrict__ ey,
                            float* __restrict__ tcpe) {
  int idx = blockIdx.x * 256 + threadIdx.x;  // B*T*64 = 24576
  if (idx >= B_ * T_ * D_) return;
  int d = idx & (D_ - 1);
  int bt = idx >> 6;
  int t = bt % T_;
  float freq = expf((float)((d >> 1) << 1) * (-logf(10000.0f) / (float)D_));
  float ang = (float)t * freq;
  float pe = (d & 1) ? cosf(ang) : sinf(ang);
  const int* f = tf + bt * 5;
  float v = pe + em[f[0] * D_ + d] + eh[f[1] * D_ + d] + ew[f[2] * D_ + d] +
            emo[f[3] * D_ + d] + ey[f[4] * D_ + d];
  tcpe[idx] = v;
}

// ---------------- kernel 2: pre-swizzle Wo/W1/W2 into bf16 MFMA B-frag order
__global__ void wswz_kernel(const float* __restrict__ Wo,
                            const float* __restrict__ W1,
                            const float* __restrict__ W2,
                            ushort* __restrict__ WoB, ushort* __restrict__ W1B,
                            ushort* __restrict__ W2B) {
  int idx = blockIdx.x * 256 + threadIdx.x;
  if (idx >= 4096 + 16384 + 16384) return;
  const float* W;
  ushort* O;
  int NT, N;
  if (idx < 4096) {
    W = Wo; O = WoB; NT = 4; N = 64;
  } else if (idx < 4096 + 16384) {
    idx -= 4096; W = W1; O = W1B; NT = 16; N = 256;
  } else {
    idx -= 20480; W = W2; O = W2B; NT = 4; N = 64;
  }
  int e = idx & 7;
  int l = (idx >> 3) & 63;
  int f = idx >> 9;
  int no = f % NT, ko = f / NT;
  int k = ko * 32 + (l >> 4) * 8 + e;
  int n = no * 16 + (l & 15);
  O[idx] = f2bf(W[k * N + n]);
}

// ---------------- kernel 3: whole layer, one block per (b,n), 3 blocks/CU
// LDS layout (byte offsets in smem[52224]):
//   enc f32[48][68] @0 | k f32[48][68] @13056 | q f32[48][64] @26112
//   v  u32[24][64] @38400 (bf16 t-pairs) | attn u32[4][20][24] @44544
// tail overlays: hs ushort[52][72] @13056 (k dead) ;
//   ft per-wave ushort[16][136] @26112+g*4352 (q,v dead)
__global__ __launch_bounds__(256, 3) void mega_kernel(
    const float* __restrict__ x, const int* __restrict__ idxs,
    const float* __restrict__ Wq, const float* __restrict__ Wk,
    const float* __restrict__ Wv, const ushort* __restrict__ WoB,
    const ushort* __restrict__ W1B, const ushort* __restrict__ W2B,
    const float* __restrict__ bo, const float* __restrict__ b1,
    const float* __restrict__ b2, const float* __restrict__ g1,
    const float* __restrict__ be1, const float* __restrict__ g2,
    const float* __restrict__ be2, const float* __restrict__ tcpe,
    float* __restrict__ out) {
  __shared__ char smem[52224];
  __shared__ float s_M[H_ * T_];
  __shared__ float s_rden[H_ * SK_];
  __shared__ int s_mtop[H_ * SK_];
  float* s_enc = (float*)smem;
  float* s_k = (float*)(smem + 13056);
  float* s_q = (float*)(smem + 26112);
  uint* s_v = (uint*)(smem + 38400);
  uint* s_at = (uint*)(smem + 44544);
  ushort* hs = (ushort*)(smem + 13056);

  const int tid = threadIdx.x;
  const int l = tid & 63;
  const int g = tid >> 6;  // wave id == head id == row-stripe id
  const int bn = blockIdx.x;
  const int b = bn / N_;

  // ---- P0: enc = x + tcpe  (stride 68)
  {
    const float4* x4 = (const float4*)(x + (size_t)bn * (T_ * D_));
    const float4* t4 = (const float4*)(tcpe + (size_t)b * (T_ * D_));
#pragma unroll
    for (int r = 0; r < 3; ++r) {
      int i = tid + 256 * r;  // 768 float4s
      float4 xv = x4[i];
      float4 tv = t4[i];
      int t = i >> 4;
      int d = (i & 15) << 2;
      *(float4*)&s_enc[t * 68 + d] =
          make_float4(xv.x + tv.x, xv.y + tv.y, xv.z + tv.z, xv.w + tv.w);
    }
  }
  __syncthreads();

  // ---- P1: fused QKV (fp32, k-chunked; one row read feeds 3 GEMMs)
  {
    float accq[12], acck[12], accv[12];
#pragma unroll
    for (int i = 0; i < 12; ++i) accq[i] = acck[i] = accv[i] = 0.0f;
#pragma unroll 1
    for (int kc = 0; kc < 4; ++kc) {
      float wq[16], wk[16], wv[16];
#pragma unroll
      for (int i = 0; i < 16; ++i) {
        int k = kc * 16 + i;
        wq[i] = Wq[k * D_ + l];
        wk[i] = Wk[k * D_ + l];
        wv[i] = Wv[k * D_ + l];
      }
#pragma unroll
      for (int tt = 0; tt < 12; ++tt) {
        const float* row = &s_enc[(g * 12 + tt) * 68 + kc * 16];
        float4 r0 = ((const float4*)row)[0];
        float4 r1 = ((const float4*)row)[1];
        float4 r2 = ((const float4*)row)[2];
        float4 r3 = ((const float4*)row)[3];
        float rr[16] = {r0.x, r0.y, r0.z, r0.w, r1.x, r1.y, r1.z, r1.w,
                        r2.x, r2.y, r2.z, r2.w, r3.x, r3.y, r3.z, r3.w};
#pragma unroll
        for (int i = 0; i < 16; ++i) {
          accq[tt] = fmaf(rr[i], wq[i], accq[tt]);
          acck[tt] = fmaf(rr[i], wk[i], acck[tt]);
          accv[tt] = fmaf(rr[i], wv[i], accv[tt]);
        }
      }
    }
    ushort* vp = (ushort*)s_v;
#pragma unroll
    for (int tt = 0; tt < 12; ++tt) {
      int t = g * 12 + tt;
      s_q[t * 64 + l] = accq[tt];
      s_k[t * 68 + l] = acck[tt];
      vp[((t >> 1) * 64 + l) * 2 + (t & 1)] = f2bf(accv[tt]);
    }
  }
  __syncthreads();

  // ---- P2a: M[t] = max_s q·k_samp − mean_s   (fp32 — selection-critical)
  if (l < T_) {
    float q[16];
#pragma unroll
    for (int j = 0; j < 16; j += 4) {
      float4 v4 = *(const float4*)&s_q[l * 64 + g * HD_ + j];
      q[j] = v4.x; q[j + 1] = v4.y; q[j + 2] = v4.z; q[j + 3] = v4.w;
    }
    float mx = -1e30f, sm = 0.0f;
    for (int s = 0; s < SK_; ++s) {
      int kt = idxs[l * SK_ + s];
      float acc = 0.0f;
#pragma unroll
      for (int j = 0; j < 16; j += 4) {
        float4 kv = *(const float4*)&s_k[kt * 68 + g * HD_ + j];
        acc = fmaf(kv.x, q[j], acc);
        acc = fmaf(kv.y, q[j + 1], acc);
        acc = fmaf(kv.z, q[j + 2], acc);
        acc = fmaf(kv.w, q[j + 3], acc);
      }
      mx = fmaxf(mx, acc);
      sm += acc;
    }
    s_M[g * T_ + l] = mx - sm * (1.0f / (float)SK_);
  }
  __syncthreads();

  // ---- P2b: top-20 by rank (jax.lax.top_k tie-break: lower index first)
  if (l < T_) {
    float mv = s_M[g * T_ + l];
    int rank = 0;
    for (int t2 = 0; t2 < T_; ++t2) {
      float o = s_M[g * T_ + t2];
      rank += (o > mv || (o == mv && t2 < l)) ? 1 : 0;
    }
    if (rank < SK_) s_mtop[g * SK_ + rank] = l;
  }
  __syncthreads();

  // ---- P2c: scores + UNNORMALIZED exp (no max-sub; |score|max ~8 << 88)
  {
    float kr[16];
    if (l < T_) {
#pragma unroll
      for (int j = 0; j < 16; j += 4) {
        float4 v4 = *(const float4*)&s_k[l * 68 + g * HD_ + j];
        kr[j] = v4.x; kr[j + 1] = v4.y; kr[j + 2] = v4.z; kr[j + 3] = v4.w;
      }
    } else {
#pragma unroll
      for (int j = 0; j < 16; ++j) kr[j] = 0.0f;
    }
    ushort* ap = (ushort*)s_at;
#pragma unroll 1
    for (int u = 0; u < SK_; ++u) {
      int qt = s_mtop[g * SK_ + u];
      const float4* qp = (const float4*)&s_q[qt * 64 + g * HD_];
      float acc = 0.0f;
#pragma unroll
      for (int j = 0; j < 4; ++j) {
        float4 qv = qp[j];  // broadcast
        acc = fmaf(qv.x, kr[4 * j], acc);
        acc = fmaf(qv.y, kr[4 * j + 1], acc);
        acc = fmaf(qv.z, kr[4 * j + 2], acc);
        acc = fmaf(qv.w, kr[4 * j + 3], acc);
      }
      if (l < T_) ap[(g * SK_ + u) * T_ + l] = f2bf(__expf(acc * 0.25f));
    }
  }
  // denominators (same wave; lanes 0..19)
  if (l < SK_) {
    const uint* ap = s_at + (g * SK_ + l) * 24;
    float s0 = 0.0f, s1 = 0.0f;
#pragma unroll
    for (int tp = 0; tp < 24; ++tp) {
      uint w = ap[tp];
      s0 += bflo(w);
      s1 += bfhi(w);
    }
    s_rden[g * SK_ + l] = 1.0f / (s0 + s1);
  }

  // ---- P2d: upd = e @ V (bf16 pairs) ; vmean per-lane register
  const int u0 = l >> 4, jj = l & 15;
  float upd[5] = {0, 0, 0, 0, 0};
  float vm = 0.0f;
  {
    const uint* a32 = s_at + g * SK_ * 24;
    const uint* v32 = s_v + g * HD_ + jj;
#pragma unroll 4
    for (int tp = 0; tp < 24; ++tp) {
      uint vw = v32[tp * 64];
      float vlo = bflo(vw), vhi = bfhi(vw);
      vm += vlo + vhi;
#pragma unroll
      for (int r = 0; r < 5; ++r) {
        uint aw = a32[(u0 + 4 * r) * 24 + tp];
        upd[r] = fmaf(bflo(aw), vlo, fmaf(bfhi(aw), vhi, upd[r]));
      }
    }
    vm *= (1.0f / (float)T_);
#pragma unroll
    for (int r = 0; r < 5; ++r) upd[r] *= s_rden[g * SK_ + u0 + 4 * r];
  }
  __syncthreads();  // all waves past q/k/v/attn reads

  // ---- ctx → hs (bf16, k region): vmean fill + top-k scatter + zero pad
  {
    ushort cvm = f2bf(vm);
#pragma unroll
    for (int r = 0; r < 12; ++r) {
      int i = l + 64 * r;  // 768 = 48x16
      int t = i >> 4;
      hs[t * 72 + g * HD_ + jj] = cvm;
    }
    hs[(48 + u0) * 72 + g * HD_ + jj] = 0;  // pad rows 48..51
#pragma unroll
    for (int r = 0; r < 5; ++r) {
      int row = s_mtop[g * SK_ + u0 + 4 * r];
      hs[row * 72 + g * HD_ + jj] = f2bf(upd[r]);
    }
  }
  __syncthreads();  // hs complete (cross-wave rows)

  // ================= MFMA tail: wave g owns output rows g*12..g*12+11 ======
  ushort* ft = (ushort*)(smem + 26112) + g * 2176;  // [16][136]
  const int kg = l >> 4, c = l & 15;
  const int row0 = g * 12;
  const f32x4 z = {0.f, 0.f, 0.f, 0.f};

  f32x4 co[4];
  {
    bf16x8 a0 = *(const bf16x8*)(const void*)(hs + (row0 + c) * 72 + kg * 8);
    bf16x8 a1 =
        *(const bf16x8*)(const void*)(hs + (row0 + c) * 72 + 32 + kg * 8);
#pragma unroll
    for (int no = 0; no < 4; ++no) {
      bf16x8 b0 = *(const bf16x8*)(const void*)(WoB + (no * 64 + l) * 8);
      bf16x8 b1f = *(const bf16x8*)(const void*)(WoB + ((4 + no) * 64 + l) * 8);
      f32x4 t0 = __builtin_amdgcn_mfma_f32_16x16x32_bf16(a0, b0, z, 0, 0, 0);
      co[no] = __builtin_amdgcn_mfma_f32_16x16x32_bf16(a1, b1f, t0, 0, 0, 0);
    }
  }
  __syncthreads();  // Wo A-reads done before h overwrites hs

  // + bo + enc residual (fp32 LDS), LN1 → h regs; h → hs (bf16)
  float h[16];
  int er[4];
#pragma unroll
  for (int reg = 0; reg < 4; ++reg) {
    int cr = kg * 4 + reg;
    er[reg] = (row0 + (cr < 12 ? cr : 11)) * 68;
  }
#pragma unroll
  for (int no = 0; no < 4; ++no) {
    int col = no * 16 + c;
    float bov = bo[col];
#pragma unroll
    for (int reg = 0; reg < 4; ++reg)
      h[no * 4 + reg] = co[no][reg] + bov + s_enc[er[reg] + col];
  }
#pragma unroll
  for (int reg = 0; reg < 4; ++reg) {
    float s = h[reg] + h[4 + reg] + h[8 + reg] + h[12 + reg];
    s += __shfl_xor(s, 1); s += __shfl_xor(s, 2);
    s += __shfl_xor(s, 4); s += __shfl_xor(s, 8);
    float mean = s * (1.0f / 64.0f);
    float d0 = h[reg] - mean, d1 = h[4 + reg] - mean;
    float d2 = h[8 + reg] - mean, d3 = h[12 + reg] - mean;
    float q = d0 * d0 + d1 * d1 + d2 * d2 + d3 * d3;
    q += __shfl_xor(q, 1); q += __shfl_xor(q, 2);
    q += __shfl_xor(q, 4); q += __shfl_xor(q, 8);
    float rstd = 1.0f / sqrtf(q * (1.0f / 64.0f) + EPS_);
#pragma unroll
    for (int no = 0; no < 4; ++no) {
      int col = no * 16 + c;
      h[no * 4 + reg] = (h[no * 4 + reg] - mean) * rstd * g1[col] + be1[col];
    }
  }
#pragma unroll
  for (int no = 0; no < 4; ++no)
#pragma unroll
    for (int reg = 0; reg < 4; ++reg) {
      int cr = kg * 4 + reg;
      if (cr < 12) hs[(row0 + cr) * 72 + no * 16 + c] = f2bf(h[no * 4 + reg]);
    }
  __syncthreads();  // h complete (cross-wave rows)

  // FFN: W1 → relu → W2, two 128-col passes through wave-private ft
  f32x4 o[4] = {z, z, z, z};
  {
    bf16x8 ha0 = *(const bf16x8*)(const void*)(hs + (row0 + c) * 72 + kg * 8);
    bf16x8 ha1 =
        *(const bf16x8*)(const void*)(hs + (row0 + c) * 72 + 32 + kg * 8);
#pragma unroll 1
    for (int p = 0; p < 2; ++p) {
      f32x4 f1[8];
#pragma unroll
      for (int q = 0; q < 8; ++q) {
        int no = p * 8 + q;
        bf16x8 b0 = *(const bf16x8*)(const void*)(W1B + (no * 64 + l) * 8);
        bf16x8 b1f =
            *(const bf16x8*)(const void*)(W1B + ((16 + no) * 64 + l) * 8);
        f32x4 t0 = __builtin_amdgcn_mfma_f32_16x16x32_bf16(ha0, b0, z, 0, 0, 0);
        f1[q] = __builtin_amdgcn_mfma_f32_16x16x32_bf16(ha1, b1f, t0, 0, 0, 0);
      }
#pragma unroll
      for (int q = 0; q < 8; ++q) {
        float bb = b1[(p * 8 + q) * 16 + c];
#pragma unroll
        for (int reg = 0; reg < 4; ++reg) {
          float vv = fmaxf(f1[q][reg] + bb, 0.0f);
          ft[(kg * 4 + reg) * 136 + q * 16 + c] = f2bf(vv);
        }
      }
#pragma unroll
      for (int ko = 0; ko < 4; ++ko) {
        bf16x8 fa =
            *(const bf16x8*)(const void*)(ft + c * 136 + ko * 32 + kg * 8);
#pragma unroll
        for (int no = 0; no < 4; ++no) {
          bf16x8 bf_ = *(const bf16x8*)(const void*)(
              W2B + (((p * 4 + ko) * 4 + no) * 64 + l) * 8);
          o[no] =
              __builtin_amdgcn_mfma_f32_16x16x32_bf16(fa, bf_, o[no], 0, 0, 0);
        }
      }
    }
  }

  // + b2 + h, LN2 → out (valid rows only)
  float v[16];
#pragma unroll
  for (int no = 0; no < 4; ++no) {
    float b2v = b2[no * 16 + c];
#pragma unroll
    for (int reg = 0; reg < 4; ++reg)
      v[no * 4 + reg] = o[no][reg] + b2v + h[no * 4 + reg];
  }
#pragma unroll
  for (int reg = 0; reg < 4; ++reg) {
    float s = v[reg] + v[4 + reg] + v[8 + reg] + v[12 + reg];
    s += __shfl_xor(s, 1); s += __shfl_xor(s, 2);
    s += __shfl_xor(s, 4); s += __shfl_xor(s, 8);
    float mean = s * (1.0f / 64.0f);
    float d0 = v[reg] - mean, d1 = v[4 + reg] - mean;
    float d2 = v[8 + reg] - mean, d3 = v[12 + reg] - mean;
    float q = d0 * d0 + d1 * d1 + d2 * d2 + d3 * d3;
    q += __shfl_xor(q, 1); q += __shfl_xor(q, 2);
    q += __shfl_xor(q, 4); q += __shfl_xor(q, 8);
    float rstd = 1.0f / sqrtf(q * (1.0f / 64.0f) + EPS_);
    int cr = kg * 4 + reg;
    if (cr < 12) {
      float* op = out + ((size_t)bn * T_ + row0 + cr) * D_;
#pragma unroll
      for (int no = 0; no < 4; ++no) {
        int col = no * 16 + c;
        op[col] = (v[no * 4 + reg] - mean) * rstd * g2[col] + be2[col];
      }
    }
  }
}

extern "C" void kernel_launch(void* const* d_in, const int* in_sizes, int n_in,
                              void* d_out, int out_size, void* d_ws,
                              size_t ws_size, hipStream_t stream) {
  const float* x = (const float*)d_in[0];
  const int* tf = (const int*)d_in[1];
  const int* idxs = (const int*)d_in[2];
  const float* Wq = (const float*)d_in[3];
  const float* Wk = (const float*)d_in[4];
  const float* Wv = (const float*)d_in[5];
  const float* Wo = (const float*)d_in[6];
  const float* bo = (const float*)d_in[7];
  const float* W1 = (const float*)d_in[8];
  const float* b1 = (const float*)d_in[9];
  const float* W2 = (const float*)d_in[10];
  const float* b2 = (const float*)d_in[11];
  const float* g1 = (const float*)d_in[12];
  const float* be1 = (const float*)d_in[13];
  const float* g2 = (const float*)d_in[14];
  const float* be2 = (const float*)d_in[15];
  const float* em = (const float*)d_in[16];
  const float* eh = (const float*)d_in[17];
  const float* ew = (const float*)d_in[18];
  const float* emo = (const float*)d_in[19];
  const float* ey = (const float*)d_in[20];
  float* out = (float*)d_out;

  float* tcpe = (float*)d_ws;  // 24576 f32 = 96 KiB
  ushort* WoB = (ushort*)((char*)d_ws + 98304);
  ushort* W1B = WoB + 4096;
  ushort* W2B = W1B + 16384;

  hipLaunchKernelGGL(tcpe_kernel, dim3((B_ * T_ * D_ + 255) / 256), dim3(256),
                     0, stream, tf, em, eh, ew, emo, ey, tcpe);
  hipLaunchKernelGGL(wswz_kernel, dim3((36864 + 255) / 256), dim3(256), 0,
                     stream, Wo, W1, W2, WoB, W1B, W2B);
  hipLaunchKernelGGL(mega_kernel, dim3(B_ * N_), dim3(256), 0, stream, x, idxs,
                     Wq, Wk, Wv, WoB, W1B, W2B, bo, b1, b2, g1, be1, g2, be2,
                     tcpe, out);
}

// Round 6
// 141.235 us; speedup vs baseline: 8.2672x; 1.0208x over previous
//
#include <hip/hip_runtime.h>

#define B_ 8
#define N_ 307
#define T_ 48
#define D_ 64
#define H_ 4
#define HD_ 16
#define SK_ 20
#define EPS_ 1e-5f

typedef __attribute__((ext_vector_type(8))) short bf16x8;
typedef __attribute__((ext_vector_type(4))) float f32x4;

__device__ inline ushort f2bf(float f) {
  union { float f; uint u; } x;
  x.f = f;
  uint u = x.u;
  return (ushort)((u + 0x7fffu + ((u >> 16) & 1u)) >> 16);  // RNE
}
__device__ inline float bflo(uint w) { return __uint_as_float(w << 16); }
__device__ inline float bfhi(uint w) {
  return __uint_as_float(w & 0xffff0000u);
}

// ---------------- kernel 1 (merged prep):
// blocks 0..95   : tcpe[B][T][64] = pe + time-feature embeddings
// blocks 96..239 : Wo/W1/W2 → bf16 MFMA B-frag order
__global__ void prep_kernel(const int* __restrict__ tf,
                            const float* __restrict__ em,
                            const float* __restrict__ eh,
                            const float* __restrict__ ew,
                            const float* __restrict__ emo,
                            const float* __restrict__ ey,
                            float* __restrict__ tcpe,
                            const float* __restrict__ Wo,
                            const float* __restrict__ W1,
                            const float* __restrict__ W2,
                            ushort* __restrict__ WoB, ushort* __restrict__ W1B,
                            ushort* __restrict__ W2B) {
  if (blockIdx.x < 96) {
    int idx = blockIdx.x * 256 + threadIdx.x;  // B*T*64 = 24576
    if (idx >= B_ * T_ * D_) return;
    int d = idx & (D_ - 1);
    int bt = idx >> 6;
    int t = bt % T_;
    float freq = expf((float)((d >> 1) << 1) * (-logf(10000.0f) / (float)D_));
    float ang = (float)t * freq;
    float pe = (d & 1) ? cosf(ang) : sinf(ang);
    const int* f = tf + bt * 5;
    tcpe[idx] = pe + em[f[0] * D_ + d] + eh[f[1] * D_ + d] +
                ew[f[2] * D_ + d] + emo[f[3] * D_ + d] + ey[f[4] * D_ + d];
  } else {
    int idx = (blockIdx.x - 96) * 256 + threadIdx.x;
    if (idx >= 4096 + 16384 + 16384) return;
    const float* W;
    ushort* O;
    int NT, N;
    if (idx < 4096) {
      W = Wo; O = WoB; NT = 4; N = 64;
    } else if (idx < 4096 + 16384) {
      idx -= 4096; W = W1; O = W1B; NT = 16; N = 256;
    } else {
      idx -= 20480; W = W2; O = W2B; NT = 4; N = 64;
    }
    int e = idx & 7;
    int l = (idx >> 3) & 63;
    int f = idx >> 9;
    int no = f % NT, ko = f / NT;
    int k = ko * 32 + (l >> 4) * 8 + e;
    int n = no * 16 + (l & 15);
    O[idx] = f2bf(W[k * N + n]);
  }
}

// ---------------- kernel 2: whole layer, one block per (b,n), 3 blocks/CU
// LDS layout (byte offsets in smem[52224]):
//   enc f32[48][68] @0 | k f32[48][68] @13056 | q f32[48][64] @26112
//   v  u32[24][64] @38400 (bf16 t-pairs) | attn u32[4][20][24] @44544
//   s_M f32[4][48] ALIASED @44544 (dead before first attn write: P2b barrier)
// tail overlays: hs ushort[52][72] @13056 (k dead) ;
//   ft per-wave ushort[16][136] @26112+g*4352 (q,v dead)
__global__ __launch_bounds__(256, 3) void mega_kernel(
    const float* __restrict__ x, const int* __restrict__ idxs,
    const float* __restrict__ Wq, const float* __restrict__ Wk,
    const float* __restrict__ Wv, const ushort* __restrict__ WoB,
    const ushort* __restrict__ W1B, const ushort* __restrict__ W2B,
    const float* __restrict__ bo, const float* __restrict__ b1,
    const float* __restrict__ b2, const float* __restrict__ g1,
    const float* __restrict__ be1, const float* __restrict__ g2,
    const float* __restrict__ be2, const float* __restrict__ tcpe,
    float* __restrict__ out) {
  __shared__ char smem[52224];
  __shared__ float s_rden[H_ * SK_];
  __shared__ int s_mtop[H_ * SK_];
  float* s_enc = (float*)smem;
  float* s_k = (float*)(smem + 13056);
  float* s_q = (float*)(smem + 26112);
  uint* s_v = (uint*)(smem + 38400);
  uint* s_at = (uint*)(smem + 44544);
  float* s_M = (float*)(smem + 44544);  // aliases attn region (see liveness)
  ushort* hs = (ushort*)(smem + 13056);

  const int tid = threadIdx.x;
  const int l = tid & 63;
  const int g = tid >> 6;  // wave id == head id == row-stripe id
  const int bn = blockIdx.x;
  const int b = bn / N_;

  // ---- P0: enc = x + tcpe  (stride 68)
  {
    const float4* x4 = (const float4*)(x + (size_t)bn * (T_ * D_));
    const float4* t4 = (const float4*)(tcpe + (size_t)b * (T_ * D_));
#pragma unroll
    for (int r = 0; r < 3; ++r) {
      int i = tid + 256 * r;  // 768 float4s
      float4 xv = x4[i];
      float4 tv = t4[i];
      int t = i >> 4;
      int d = (i & 15) << 2;
      *(float4*)&s_enc[t * 68 + d] =
          make_float4(xv.x + tv.x, xv.y + tv.y, xv.z + tv.z, xv.w + tv.w);
    }
  }
  __syncthreads();

  // ---- P1: fused QKV (fp32, k-chunked; one row read feeds 3 GEMMs)
  {
    float accq[12], acck[12], accv[12];
#pragma unroll
    for (int i = 0; i < 12; ++i) accq[i] = acck[i] = accv[i] = 0.0f;
#pragma unroll 1
    for (int kc = 0; kc < 4; ++kc) {
      float wq[16], wk[16], wv[16];
#pragma unroll
      for (int i = 0; i < 16; ++i) {
        int k = kc * 16 + i;
        wq[i] = Wq[k * D_ + l];
        wk[i] = Wk[k * D_ + l];
        wv[i] = Wv[k * D_ + l];
      }
#pragma unroll
      for (int tt = 0; tt < 12; ++tt) {
        const float* row = &s_enc[(g * 12 + tt) * 68 + kc * 16];
        float4 r0 = ((const float4*)row)[0];
        float4 r1 = ((const float4*)row)[1];
        float4 r2 = ((const float4*)row)[2];
        float4 r3 = ((const float4*)row)[3];
        float rr[16] = {r0.x, r0.y, r0.z, r0.w, r1.x, r1.y, r1.z, r1.w,
                        r2.x, r2.y, r2.z, r2.w, r3.x, r3.y, r3.z, r3.w};
#pragma unroll
        for (int i = 0; i < 16; ++i) {
          accq[tt] = fmaf(rr[i], wq[i], accq[tt]);
          acck[tt] = fmaf(rr[i], wk[i], acck[tt]);
          accv[tt] = fmaf(rr[i], wv[i], accv[tt]);
        }
      }
    }
    ushort* vp = (ushort*)s_v;
#pragma unroll
    for (int tt = 0; tt < 12; ++tt) {
      int t = g * 12 + tt;
      s_q[t * 64 + l] = accq[tt];
      s_k[t * 68 + l] = acck[tt];
      vp[((t >> 1) * 64 + l) * 2 + (t & 1)] = f2bf(accv[tt]);
    }
  }
  __syncthreads();

  // ---- P2a: M[t] = max_s q·k_samp − mean_s   (fp32 — selection-critical)
  if (l < T_) {
    float q[16];
#pragma unroll
    for (int j = 0; j < 16; j += 4) {
      float4 v4 = *(const float4*)&s_q[l * 64 + g * HD_ + j];
      q[j] = v4.x; q[j + 1] = v4.y; q[j + 2] = v4.z; q[j + 3] = v4.w;
    }
    float mx = -1e30f, sm = 0.0f;
    for (int s = 0; s < SK_; ++s) {
      int kt = idxs[l * SK_ + s];
      float acc = 0.0f;
#pragma unroll
      for (int j = 0; j < 16; j += 4) {
        float4 kv = *(const float4*)&s_k[kt * 68 + g * HD_ + j];
        acc = fmaf(kv.x, q[j], acc);
        acc = fmaf(kv.y, q[j + 1], acc);
        acc = fmaf(kv.z, q[j + 2], acc);
        acc = fmaf(kv.w, q[j + 3], acc);
      }
      mx = fmaxf(mx, acc);
      sm += acc;
    }
    s_M[g * T_ + l] = mx - sm * (1.0f / (float)SK_);
  }
  __syncthreads();

  // ---- P2b: top-20 by rank (jax.lax.top_k tie-break: lower index first)
  if (l < T_) {
    float mv = s_M[g * T_ + l];
    int rank = 0;
    for (int t2 = 0; t2 < T_; ++t2) {
      float o = s_M[g * T_ + t2];
      rank += (o > mv || (o == mv && t2 < l)) ? 1 : 0;
    }
    if (rank < SK_) s_mtop[g * SK_ + rank] = l;
  }
  __syncthreads();  // s_M dead beyond this barrier → attn may overwrite

  // ---- P2c: scores + UNNORMALIZED exp (no max-sub; |score|max ~8 << 88)
  {
    float kr[16];
    if (l < T_) {
#pragma unroll
      for (int j = 0; j < 16; j += 4) {
        float4 v4 = *(const float4*)&s_k[l * 68 + g * HD_ + j];
        kr[j] = v4.x; kr[j + 1] = v4.y; kr[j + 2] = v4.z; kr[j + 3] = v4.w;
      }
    } else {
#pragma unroll
      for (int j = 0; j < 16; ++j) kr[j] = 0.0f;
    }
    ushort* ap = (ushort*)s_at;
#pragma unroll 1
    for (int u = 0; u < SK_; ++u) {
      int qt = s_mtop[g * SK_ + u];
      const float4* qp = (const float4*)&s_q[qt * 64 + g * HD_];
      float acc = 0.0f;
#pragma unroll
      for (int j = 0; j < 4; ++j) {
        float4 qv = qp[j];  // broadcast
        acc = fmaf(qv.x, kr[4 * j], acc);
        acc = fmaf(qv.y, kr[4 * j + 1], acc);
        acc = fmaf(qv.z, kr[4 * j + 2], acc);
        acc = fmaf(qv.w, kr[4 * j + 3], acc);
      }
      if (l < T_) ap[(g * SK_ + u) * T_ + l] = f2bf(__expf(acc * 0.25f));
    }
  }
  // denominators (same wave; lanes 0..19)
  if (l < SK_) {
    const uint* ap = s_at + (g * SK_ + l) * 24;
    float s0 = 0.0f, s1 = 0.0f;
#pragma unroll
    for (int tp = 0; tp < 24; ++tp) {
      uint w = ap[tp];
      s0 += bflo(w);
      s1 += bfhi(w);
    }
    s_rden[g * SK_ + l] = 1.0f / (s0 + s1);
  }

  // ---- P2d: upd = e @ V (bf16 pairs) ; vmean per-lane register
  const int u0 = l >> 4, jj = l & 15;
  float upd[5] = {0, 0, 0, 0, 0};
  float vm = 0.0f;
  {
    const uint* a32 = s_at + g * SK_ * 24;
    const uint* v32 = s_v + g * HD_ + jj;
#pragma unroll 4
    for (int tp = 0; tp < 24; ++tp) {
      uint vw = v32[tp * 64];
      float vlo = bflo(vw), vhi = bfhi(vw);
      vm += vlo + vhi;
#pragma unroll
      for (int r = 0; r < 5; ++r) {
        uint aw = a32[(u0 + 4 * r) * 24 + tp];
        upd[r] = fmaf(bflo(aw), vlo, fmaf(bfhi(aw), vhi, upd[r]));
      }
    }
    vm *= (1.0f / (float)T_);
#pragma unroll
    for (int r = 0; r < 5; ++r) upd[r] *= s_rden[g * SK_ + u0 + 4 * r];
  }
  __syncthreads();  // all waves past q/k/v/attn reads

  // ---- ctx → hs (bf16, k region): vmean fill + top-k scatter + zero pad
  {
    ushort cvm = f2bf(vm);
#pragma unroll
    for (int r = 0; r < 12; ++r) {
      int i = l + 64 * r;  // 768 = 48x16
      int t = i >> 4;
      hs[t * 72 + g * HD_ + jj] = cvm;
    }
    hs[(48 + u0) * 72 + g * HD_ + jj] = 0;  // pad rows 48..51
#pragma unroll
    for (int r = 0; r < 5; ++r) {
      int row = s_mtop[g * SK_ + u0 + 4 * r];
      hs[row * 72 + g * HD_ + jj] = f2bf(upd[r]);
    }
  }
  __syncthreads();  // hs complete (cross-wave rows)

  // ================= MFMA tail: wave g owns output rows g*12..g*12+11 ======
  ushort* ft = (ushort*)(smem + 26112) + g * 2176;  // [16][136]
  const int kg = l >> 4, c = l & 15;
  const int row0 = g * 12;
  const f32x4 z = {0.f, 0.f, 0.f, 0.f};

  f32x4 co[4];
  {
    bf16x8 a0 = *(const bf16x8*)(const void*)(hs + (row0 + c) * 72 + kg * 8);
    bf16x8 a1 =
        *(const bf16x8*)(const void*)(hs + (row0 + c) * 72 + 32 + kg * 8);
#pragma unroll
    for (int no = 0; no < 4; ++no) {
      bf16x8 b0 = *(const bf16x8*)(const void*)(WoB + (no * 64 + l) * 8);
      bf16x8 b1f = *(const bf16x8*)(const void*)(WoB + ((4 + no) * 64 + l) * 8);
      f32x4 t0 = __builtin_amdgcn_mfma_f32_16x16x32_bf16(a0, b0, z, 0, 0, 0);
      co[no] = __builtin_amdgcn_mfma_f32_16x16x32_bf16(a1, b1f, t0, 0, 0, 0);
    }
  }
  __syncthreads();  // Wo A-reads done before h overwrites hs

  // + bo + enc residual (fp32 LDS), LN1 → h regs; h → hs (bf16)
  float h[16];
  int er[4];
#pragma unroll
  for (int reg = 0; reg < 4; ++reg) {
    int cr = kg * 4 + reg;
    er[reg] = (row0 + (cr < 12 ? cr : 11)) * 68;
  }
#pragma unroll
  for (int no = 0; no < 4; ++no) {
    int col = no * 16 + c;
    float bov = bo[col];
#pragma unroll
    for (int reg = 0; reg < 4; ++reg)
      h[no * 4 + reg] = co[no][reg] + bov + s_enc[er[reg] + col];
  }
#pragma unroll
  for (int reg = 0; reg < 4; ++reg) {
    float s = h[reg] + h[4 + reg] + h[8 + reg] + h[12 + reg];
    s += __shfl_xor(s, 1); s += __shfl_xor(s, 2);
    s += __shfl_xor(s, 4); s += __shfl_xor(s, 8);
    float mean = s * (1.0f / 64.0f);
    float d0 = h[reg] - mean, d1 = h[4 + reg] - mean;
    float d2 = h[8 + reg] - mean, d3 = h[12 + reg] - mean;
    float q = d0 * d0 + d1 * d1 + d2 * d2 + d3 * d3;
    q += __shfl_xor(q, 1); q += __shfl_xor(q, 2);
    q += __shfl_xor(q, 4); q += __shfl_xor(q, 8);
    float rstd = 1.0f / sqrtf(q * (1.0f / 64.0f) + EPS_);
#pragma unroll
    for (int no = 0; no < 4; ++no) {
      int col = no * 16 + c;
      h[no * 4 + reg] = (h[no * 4 + reg] - mean) * rstd * g1[col] + be1[col];
    }
  }
#pragma unroll
  for (int no = 0; no < 4; ++no)
#pragma unroll
    for (int reg = 0; reg < 4; ++reg) {
      int cr = kg * 4 + reg;
      if (cr < 12) hs[(row0 + cr) * 72 + no * 16 + c] = f2bf(h[no * 4 + reg]);
    }
  __syncthreads();  // h complete (cross-wave rows)

  // FFN: W1 → relu → W2, two 128-col passes through wave-private ft
  f32x4 o[4] = {z, z, z, z};
  {
    bf16x8 ha0 = *(const bf16x8*)(const void*)(hs + (row0 + c) * 72 + kg * 8);
    bf16x8 ha1 =
        *(const bf16x8*)(const void*)(hs + (row0 + c) * 72 + 32 + kg * 8);
#pragma unroll 1
    for (int p = 0; p < 2; ++p) {
      f32x4 f1[8];
#pragma unroll
      for (int q = 0; q < 8; ++q) {
        int no = p * 8 + q;
        bf16x8 b0 = *(const bf16x8*)(const void*)(W1B + (no * 64 + l) * 8);
        bf16x8 b1f =
            *(const bf16x8*)(const void*)(W1B + ((16 + no) * 64 + l) * 8);
        f32x4 t0 = __builtin_amdgcn_mfma_f32_16x16x32_bf16(ha0, b0, z, 0, 0, 0);
        f1[q] = __builtin_amdgcn_mfma_f32_16x16x32_bf16(ha1, b1f, t0, 0, 0, 0);
      }
#pragma unroll
      for (int q = 0; q < 8; ++q) {
        float bb = b1[(p * 8 + q) * 16 + c];
#pragma unroll
        for (int reg = 0; reg < 4; ++reg) {
          float vv = fmaxf(f1[q][reg] + bb, 0.0f);
          ft[(kg * 4 + reg) * 136 + q * 16 + c] = f2bf(vv);
        }
      }
#pragma unroll
      for (int ko = 0; ko < 4; ++ko) {
        bf16x8 fa =
            *(const bf16x8*)(const void*)(ft + c * 136 + ko * 32 + kg * 8);
#pragma unroll
        for (int no = 0; no < 4; ++no) {
          bf16x8 bf_ = *(const bf16x8*)(const void*)(
              W2B + (((p * 4 + ko) * 4 + no) * 64 + l) * 8);
          o[no] =
              __builtin_amdgcn_mfma_f32_16x16x32_bf16(fa, bf_, o[no], 0, 0, 0);
        }
      }
    }
  }

  // + b2 + h, LN2 → out (valid rows only)
  float v[16];
#pragma unroll
  for (int no = 0; no < 4; ++no) {
    float b2v = b2[no * 16 + c];
#pragma unroll
    for (int reg = 0; reg < 4; ++reg)
      v[no * 4 + reg] = o[no][reg] + b2v + h[no * 4 + reg];
  }
#pragma unroll
  for (int reg = 0; reg < 4; ++reg) {
    float s = v[reg] + v[4 + reg] + v[8 + reg] + v[12 + reg];
    s += __shfl_xor(s, 1); s += __shfl_xor(s, 2);
    s += __shfl_xor(s, 4); s += __shfl_xor(s, 8);
    float mean = s * (1.0f / 64.0f);
    float d0 = v[reg] - mean, d1 = v[4 + reg] - mean;
    float d2 = v[8 + reg] - mean, d3 = v[12 + reg] - mean;
    float q = d0 * d0 + d1 * d1 + d2 * d2 + d3 * d3;
    q += __shfl_xor(q, 1); q += __shfl_xor(q, 2);
    q += __shfl_xor(q, 4); q += __shfl_xor(q, 8);
    float rstd = 1.0f / sqrtf(q * (1.0f / 64.0f) + EPS_);
    int cr = kg * 4 + reg;
    if (cr < 12) {
      float* op = out + ((size_t)bn * T_ + row0 + cr) * D_;
#pragma unroll
      for (int no = 0; no < 4; ++no) {
        int col = no * 16 + c;
        op[col] = (v[no * 4 + reg] - mean) * rstd * g2[col] + be2[col];
      }
    }
  }
}

extern "C" void kernel_launch(void* const* d_in, const int* in_sizes, int n_in,
                              void* d_out, int out_size, void* d_ws,
                              size_t ws_size, hipStream_t stream) {
  const float* x = (const float*)d_in[0];
  const int* tf = (const int*)d_in[1];
  const int* idxs = (const int*)d_in[2];
  const float* Wq = (const float*)d_in[3];
  const float* Wk = (const float*)d_in[4];
  const float* Wv = (const float*)d_in[5];
  const float* Wo = (const float*)d_in[6];
  const float* bo = (const float*)d_in[7];
  const float* W1 = (const float*)d_in[8];
  const float* b1 = (const float*)d_in[9];
  const float* W2 = (const float*)d_in[10];
  const float* b2 = (const float*)d_in[11];
  const float* g1 = (const float*)d_in[12];
  const float* be1 = (const float*)d_in[13];
  const float* g2 = (const float*)d_in[14];
  const float* be2 = (const float*)d_in[15];
  const float* em = (const float*)d_in[16];
  const float* eh = (const float*)d_in[17];
  const float* ew = (const float*)d_in[18];
  const float* emo = (const float*)d_in[19];
  const float* ey = (const float*)d_in[20];
  float* out = (float*)d_out;

  float* tcpe = (float*)d_ws;  // 24576 f32 = 96 KiB
  ushort* WoB = (ushort*)((char*)d_ws + 98304);
  ushort* W1B = WoB + 4096;
  ushort* W2B = W1B + 16384;

  hipLaunchKernelGGL(prep_kernel, dim3(240), dim3(256), 0, stream, tf, em, eh,
                     ew, emo, ey, tcpe, Wo, W1, W2, WoB, W1B, W2B);
  hipLaunchKernelGGL(mega_kernel, dim3(B_ * N_), dim3(256), 0, stream, x, idxs,
                     Wq, Wk, Wv, WoB, W1B, W2B, bo, b1, b2, g1, be1, g2, be2,
                     tcpe, out);
}

// Round 7
// 138.918 us; speedup vs baseline: 8.4051x; 1.0167x over previous
//
#include <hip/hip_runtime.h>

#define B_ 8
#define N_ 307
#define T_ 48
#define D_ 64
#define H_ 4
#define HD_ 16
#define SK_ 20
#define EPS_ 1e-5f

typedef __attribute__((ext_vector_type(8))) short bf16x8;
typedef __attribute__((ext_vector_type(4))) float f32x4;

__device__ inline ushort f2bf(float f) {
  union { float f; uint u; } x;
  x.f = f;
  uint u = x.u;
  return (ushort)((u + 0x7fffu + ((u >> 16) & 1u)) >> 16);  // RNE
}
__device__ inline float bflo(uint w) { return __uint_as_float(w << 16); }
__device__ inline float bfhi(uint w) {
  return __uint_as_float(w & 0xffff0000u);
}

// ---------------- kernel 1 (merged prep):
// blocks 0..95   : tcpe[B][T][64] = pe + time-feature embeddings
// blocks 96..239 : Wo/W1/W2 → bf16 MFMA B-frag order
__global__ void prep_kernel(const int* __restrict__ tf,
                            const float* __restrict__ em,
                            const float* __restrict__ eh,
                            const float* __restrict__ ew,
                            const float* __restrict__ emo,
                            const float* __restrict__ ey,
                            float* __restrict__ tcpe,
                            const float* __restrict__ Wo,
                            const float* __restrict__ W1,
                            const float* __restrict__ W2,
                            ushort* __restrict__ WoB, ushort* __restrict__ W1B,
                            ushort* __restrict__ W2B) {
  if (blockIdx.x < 96) {
    int idx = blockIdx.x * 256 + threadIdx.x;  // B*T*64 = 24576
    if (idx >= B_ * T_ * D_) return;
    int d = idx & (D_ - 1);
    int bt = idx >> 6;
    int t = bt % T_;
    float freq = expf((float)((d >> 1) << 1) * (-logf(10000.0f) / (float)D_));
    float ang = (float)t * freq;
    float pe = (d & 1) ? cosf(ang) : sinf(ang);
    const int* f = tf + bt * 5;
    tcpe[idx] = pe + em[f[0] * D_ + d] + eh[f[1] * D_ + d] +
                ew[f[2] * D_ + d] + emo[f[3] * D_ + d] + ey[f[4] * D_ + d];
  } else {
    int idx = (blockIdx.x - 96) * 256 + threadIdx.x;
    if (idx >= 4096 + 16384 + 16384) return;
    const float* W;
    ushort* O;
    int NT, N;
    if (idx < 4096) {
      W = Wo; O = WoB; NT = 4; N = 64;
    } else if (idx < 4096 + 16384) {
      idx -= 4096; W = W1; O = W1B; NT = 16; N = 256;
    } else {
      idx -= 20480; W = W2; O = W2B; NT = 4; N = 64;
    }
    int e = idx & 7;
    int l = (idx >> 3) & 63;
    int f = idx >> 9;
    int no = f % NT, ko = f / NT;
    int k = ko * 32 + (l >> 4) * 8 + e;
    int n = no * 16 + (l & 15);
    O[idx] = f2bf(W[k * N + n]);
  }
}

// ---------------- kernel 2: whole layer, one block per (b,n), 4 blocks/CU
// LDS (smem[38400] + 1.4KB small arrays ≈ 39.9KB):
//   enc f32[48][68] @0      → tail(post-LN1): out-bounce f32[12][68]/wave @g*3264
//   k   f32[48][68] @13056  → P2c+: attn u16[4*20][48] → tail: hs u16[52][72]
//   q   f32[48][64] @26112  → tail: ft u16[16][72]/wave @+g*2304
// V: bf16-pair packed u32[24][64] per bn in global ws (same-block RT, L1/L2-hot)
__global__ __launch_bounds__(256, 4) void mega_kernel(
    const float* __restrict__ x, const int* __restrict__ idxs,
    const float* __restrict__ Wq, const float* __restrict__ Wk,
    const float* __restrict__ Wv, const ushort* __restrict__ WoB,
    const ushort* __restrict__ W1B, const ushort* __restrict__ W2B,
    const float* __restrict__ bo, const float* __restrict__ b1,
    const float* __restrict__ b2, const float* __restrict__ g1,
    const float* __restrict__ be1, const float* __restrict__ g2,
    const float* __restrict__ be2, const float* __restrict__ tcpe,
    uint* __restrict__ Vg, float* __restrict__ out) {
  __shared__ char smem[38400];
  __shared__ float s_M[H_ * T_];
  __shared__ float s_rden[H_ * SK_];
  __shared__ int s_mtop[H_ * SK_];
  float* s_enc = (float*)smem;
  float* s_k = (float*)(smem + 13056);
  float* s_q = (float*)(smem + 26112);
  ushort* ap = (ushort*)(smem + 13056);  // attn, overlays k after kr snapshot
  ushort* hs = (ushort*)(smem + 13056);  // ctx/h tile, after attn dead

  const int tid = threadIdx.x;
  const int l = tid & 63;
  const int g = tid >> 6;  // wave id == head id == row-stripe id
  const int bn = blockIdx.x;
  const int b = bn / N_;

  // ---- P0: enc = x + tcpe  (stride 68)
  {
    const float4* x4 = (const float4*)(x + (size_t)bn * (T_ * D_));
    const float4* t4 = (const float4*)(tcpe + (size_t)b * (T_ * D_));
#pragma unroll
    for (int r = 0; r < 3; ++r) {
      int i = tid + 256 * r;  // 768 float4s
      float4 xv = x4[i];
      float4 tv = t4[i];
      int t = i >> 4;
      int d = (i & 15) << 2;
      *(float4*)&s_enc[t * 68 + d] =
          make_float4(xv.x + tv.x, xv.y + tv.y, xv.z + tv.z, xv.w + tv.w);
    }
  }
  __syncthreads();

  // ---- P1: fused QKV (fp32, k-chunked); Q,K → LDS, V → global bf16 pairs
  {
    float accq[12], acck[12], accv[12];
#pragma unroll
    for (int i = 0; i < 12; ++i) accq[i] = acck[i] = accv[i] = 0.0f;
#pragma unroll 1
    for (int kc = 0; kc < 4; ++kc) {
      float wq[16], wk[16], wv[16];
#pragma unroll
      for (int i = 0; i < 16; ++i) {
        int k = kc * 16 + i;
        wq[i] = Wq[k * D_ + l];
        wk[i] = Wk[k * D_ + l];
        wv[i] = Wv[k * D_ + l];
      }
#pragma unroll
      for (int tt = 0; tt < 12; ++tt) {
        const float* row = &s_enc[(g * 12 + tt) * 68 + kc * 16];
        float4 r0 = ((const float4*)row)[0];
        float4 r1 = ((const float4*)row)[1];
        float4 r2 = ((const float4*)row)[2];
        float4 r3 = ((const float4*)row)[3];
        float rr[16] = {r0.x, r0.y, r0.z, r0.w, r1.x, r1.y, r1.z, r1.w,
                        r2.x, r2.y, r2.z, r2.w, r3.x, r3.y, r3.z, r3.w};
#pragma unroll
        for (int i = 0; i < 16; ++i) {
          accq[tt] = fmaf(rr[i], wq[i], accq[tt]);
          acck[tt] = fmaf(rr[i], wk[i], acck[tt]);
          accv[tt] = fmaf(rr[i], wv[i], accv[tt]);
        }
      }
    }
#pragma unroll
    for (int tt = 0; tt < 12; ++tt) {
      int t = g * 12 + tt;
      s_q[t * 64 + l] = accq[tt];
      s_k[t * 68 + l] = acck[tt];
    }
    uint* vp = Vg + (size_t)bn * 1536 + g * 6 * 64 + l;
#pragma unroll
    for (int i = 0; i < 6; ++i)
      vp[i * 64] =
          (uint)f2bf(accv[2 * i]) | ((uint)f2bf(accv[2 * i + 1]) << 16);
  }
  __syncthreads();

  // ---- P2a: M[t] = max_s q·k_samp − mean_s   (fp32 — selection-critical)
  if (l < T_) {
    float q[16];
#pragma unroll
    for (int j = 0; j < 16; j += 4) {
      float4 v4 = *(const float4*)&s_q[l * 64 + g * HD_ + j];
      q[j] = v4.x; q[j + 1] = v4.y; q[j + 2] = v4.z; q[j + 3] = v4.w;
    }
    float mx = -1e30f, sm = 0.0f;
    for (int s = 0; s < SK_; ++s) {
      int kt = idxs[l * SK_ + s];
      float acc = 0.0f;
#pragma unroll
      for (int j = 0; j < 16; j += 4) {
        float4 kv = *(const float4*)&s_k[kt * 68 + g * HD_ + j];
        acc = fmaf(kv.x, q[j], acc);
        acc = fmaf(kv.y, q[j + 1], acc);
        acc = fmaf(kv.z, q[j + 2], acc);
        acc = fmaf(kv.w, q[j + 3], acc);
      }
      mx = fmaxf(mx, acc);
      sm += acc;
    }
    s_M[g * T_ + l] = mx - sm * (1.0f / (float)SK_);
  }
  __syncthreads();

  // ---- P2b: top-20 by rank (jax.lax.top_k tie-break: lower index first)
  if (l < T_) {
    float mv = s_M[g * T_ + l];
    int rank = 0;
    for (int t2 = 0; t2 < T_; ++t2) {
      float o = s_M[g * T_ + t2];
      rank += (o > mv || (o == mv && t2 < l)) ? 1 : 0;
    }
    if (rank < SK_) s_mtop[g * SK_ + rank] = l;
  }
  __syncthreads();

  // ---- P2c: snapshot K row → regs, then scores + UNNORMALIZED exp into
  //      the K region (attn overlay). |score| ≲ 8 << 88 so no max-sub.
  {
    float kr[16];
    if (l < T_) {
#pragma unroll
      for (int j = 0; j < 16; j += 4) {
        float4 v4 = *(const float4*)&s_k[l * 68 + g * HD_ + j];
        kr[j] = v4.x; kr[j + 1] = v4.y; kr[j + 2] = v4.z; kr[j + 3] = v4.w;
      }
    } else {
#pragma unroll
      for (int j = 0; j < 16; ++j) kr[j] = 0.0f;
    }
    __syncthreads();  // all kr snapshots done; k region → attn
#pragma unroll 1
    for (int u = 0; u < SK_; ++u) {
      int qt = s_mtop[g * SK_ + u];
      const float4* qp = (const float4*)&s_q[qt * 64 + g * HD_];
      float acc = 0.0f;
#pragma unroll
      for (int j = 0; j < 4; ++j) {
        float4 qv = qp[j];  // broadcast
        acc = fmaf(qv.x, kr[4 * j], acc);
        acc = fmaf(qv.y, kr[4 * j + 1], acc);
        acc = fmaf(qv.z, kr[4 * j + 2], acc);
        acc = fmaf(qv.w, kr[4 * j + 3], acc);
      }
      if (l < T_) ap[(g * SK_ + u) * T_ + l] = f2bf(__expf(acc * 0.25f));
    }
  }
  // denominators (same wave; lanes 0..19)
  if (l < SK_) {
    const uint* a32 = (const uint*)(smem + 13056) + (g * SK_ + l) * 24;
    float s0 = 0.0f, s1 = 0.0f;
#pragma unroll
    for (int tp = 0; tp < 24; ++tp) {
      uint w = a32[tp];
      s0 += bflo(w);
      s1 += bfhi(w);
    }
    s_rden[g * SK_ + l] = 1.0f / (s0 + s1);
  }

  // ---- P2d: upd = e @ V (V streamed from global, L1-hot) ; vmean in reg
  const int u0 = l >> 4, jj = l & 15;
  float upd[5] = {0, 0, 0, 0, 0};
  float vm = 0.0f;
  {
    const uint* a32 = (const uint*)(smem + 13056) + g * SK_ * 24;
    const uint* v32 = Vg + (size_t)bn * 1536 + g * HD_ + jj;
#pragma unroll 4
    for (int tp = 0; tp < 24; ++tp) {
      uint vw = v32[tp * 64];
      float vlo = bflo(vw), vhi = bfhi(vw);
      vm += vlo + vhi;
#pragma unroll
      for (int r = 0; r < 5; ++r) {
        uint aw = a32[(u0 + 4 * r) * 24 + tp];
        upd[r] = fmaf(bflo(aw), vlo, fmaf(bfhi(aw), vhi, upd[r]));
      }
    }
    vm *= (1.0f / (float)T_);
#pragma unroll
    for (int r = 0; r < 5; ++r) upd[r] *= s_rden[g * SK_ + u0 + 4 * r];
  }
  __syncthreads();  // all waves past attn reads; region → hs

  // ---- ctx → hs (bf16): vmean fill + top-k scatter + zero pad rows 48..51
  {
    ushort cvm = f2bf(vm);
#pragma unroll
    for (int r = 0; r < 12; ++r) {
      int i = l + 64 * r;  // 768 = 48x16
      int t = i >> 4;
      hs[t * 72 + g * HD_ + jj] = cvm;
    }
    hs[(48 + u0) * 72 + g * HD_ + jj] = 0;
#pragma unroll
    for (int r = 0; r < 5; ++r) {
      int row = s_mtop[g * SK_ + u0 + 4 * r];
      hs[row * 72 + g * HD_ + jj] = f2bf(upd[r]);
    }
  }
  __syncthreads();  // hs complete (cross-wave rows)

  // ================= MFMA tail: wave g owns output rows g*12..g*12+11 ======
  ushort* ft = (ushort*)(smem + 26112) + g * 1152;  // [16][72] per wave
  const int kg = l >> 4, c = l & 15;
  const int row0 = g * 12;
  const f32x4 z = {0.f, 0.f, 0.f, 0.f};

  f32x4 co[4];
  {
    bf16x8 a0 = *(const bf16x8*)(const void*)(hs + (row0 + c) * 72 + kg * 8);
    bf16x8 a1 =
        *(const bf16x8*)(const void*)(hs + (row0 + c) * 72 + 32 + kg * 8);
#pragma unroll
    for (int no = 0; no < 4; ++no) {
      bf16x8 b0 = *(const bf16x8*)(const void*)(WoB + (no * 64 + l) * 8);
      bf16x8 b1f = *(const bf16x8*)(const void*)(WoB + ((4 + no) * 64 + l) * 8);
      f32x4 t0 = __builtin_amdgcn_mfma_f32_16x16x32_bf16(a0, b0, z, 0, 0, 0);
      co[no] = __builtin_amdgcn_mfma_f32_16x16x32_bf16(a1, b1f, t0, 0, 0, 0);
    }
  }
  __syncthreads();  // Wo A-reads done before h overwrites hs

  // + bo + enc residual (fp32 LDS), LN1 → h regs; h → hs (bf16)
  float h[16];
  int er[4];
#pragma unroll
  for (int reg = 0; reg < 4; ++reg) {
    int cr = kg * 4 + reg;
    er[reg] = (row0 + (cr < 12 ? cr : 11)) * 68;
  }
#pragma unroll
  for (int no = 0; no < 4; ++no) {
    int col = no * 16 + c;
    float bov = bo[col];
#pragma unroll
    for (int reg = 0; reg < 4; ++reg)
      h[no * 4 + reg] = co[no][reg] + bov + s_enc[er[reg] + col];
  }
#pragma unroll
  for (int reg = 0; reg < 4; ++reg) {
    float s = h[reg] + h[4 + reg] + h[8 + reg] + h[12 + reg];
    s += __shfl_xor(s, 1); s += __shfl_xor(s, 2);
    s += __shfl_xor(s, 4); s += __shfl_xor(s, 8);
    float mean = s * (1.0f / 64.0f);
    float d0 = h[reg] - mean, d1 = h[4 + reg] - mean;
    float d2 = h[8 + reg] - mean, d3 = h[12 + reg] - mean;
    float q = d0 * d0 + d1 * d1 + d2 * d2 + d3 * d3;
    q += __shfl_xor(q, 1); q += __shfl_xor(q, 2);
    q += __shfl_xor(q, 4); q += __shfl_xor(q, 8);
    float rstd = 1.0f / sqrtf(q * (1.0f / 64.0f) + EPS_);
#pragma unroll
    for (int no = 0; no < 4; ++no) {
      int col = no * 16 + c;
      h[no * 4 + reg] = (h[no * 4 + reg] - mean) * rstd * g1[col] + be1[col];
    }
  }
#pragma unroll
  for (int no = 0; no < 4; ++no)
#pragma unroll
    for (int reg = 0; reg < 4; ++reg) {
      int cr = kg * 4 + reg;
      if (cr < 12) hs[(row0 + cr) * 72 + no * 16 + c] = f2bf(h[no * 4 + reg]);
    }
  __syncthreads();  // h complete (cross-wave rows)

  // FFN: W1 → relu → W2 in four 64-col passes through wave-private ft
  f32x4 o[4] = {z, z, z, z};
  {
    bf16x8 ha0 = *(const bf16x8*)(const void*)(hs + (row0 + c) * 72 + kg * 8);
    bf16x8 ha1 =
        *(const bf16x8*)(const void*)(hs + (row0 + c) * 72 + 32 + kg * 8);
#pragma unroll 1
    for (int p = 0; p < 4; ++p) {
      f32x4 f1[4];
#pragma unroll
      for (int q = 0; q < 4; ++q) {
        int no = p * 4 + q;
        bf16x8 b0 = *(const bf16x8*)(const void*)(W1B + (no * 64 + l) * 8);
        bf16x8 b1f =
            *(const bf16x8*)(const void*)(W1B + ((16 + no) * 64 + l) * 8);
        f32x4 t0 = __builtin_amdgcn_mfma_f32_16x16x32_bf16(ha0, b0, z, 0, 0, 0);
        f1[q] = __builtin_amdgcn_mfma_f32_16x16x32_bf16(ha1, b1f, t0, 0, 0, 0);
      }
#pragma unroll
      for (int q = 0; q < 4; ++q) {
        float bb = b1[(p * 4 + q) * 16 + c];
#pragma unroll
        for (int reg = 0; reg < 4; ++reg) {
          float vv = fmaxf(f1[q][reg] + bb, 0.0f);
          ft[(kg * 4 + reg) * 72 + q * 16 + c] = f2bf(vv);
        }
      }
#pragma unroll
      for (int koi = 0; koi < 2; ++koi) {
        bf16x8 fa =
            *(const bf16x8*)(const void*)(ft + c * 72 + koi * 32 + kg * 8);
#pragma unroll
        for (int no = 0; no < 4; ++no) {
          bf16x8 bf_ = *(const bf16x8*)(const void*)(
              W2B + (((p * 2 + koi) * 4 + no) * 64 + l) * 8);
          o[no] =
              __builtin_amdgcn_mfma_f32_16x16x32_bf16(fa, bf_, o[no], 0, 0, 0);
        }
      }
    }
  }

  // + b2 + h, LN2 → wave-private bounce tile (enc region, dead) → coalesced out
  float* bt = (float*)smem + g * 816;  // [12][68]
  float v[16];
#pragma unroll
  for (int no = 0; no < 4; ++no) {
    float b2v = b2[no * 16 + c];
#pragma unroll
    for (int reg = 0; reg < 4; ++reg)
      v[no * 4 + reg] = o[no][reg] + b2v + h[no * 4 + reg];
  }
#pragma unroll
  for (int reg = 0; reg < 4; ++reg) {
    float s = v[reg] + v[4 + reg] + v[8 + reg] + v[12 + reg];
    s += __shfl_xor(s, 1); s += __shfl_xor(s, 2);
    s += __shfl_xor(s, 4); s += __shfl_xor(s, 8);
    float mean = s * (1.0f / 64.0f);
    float d0 = v[reg] - mean, d1 = v[4 + reg] - mean;
    float d2 = v[8 + reg] - mean, d3 = v[12 + reg] - mean;
    float q = d0 * d0 + d1 * d1 + d2 * d2 + d3 * d3;
    q += __shfl_xor(q, 1); q += __shfl_xor(q, 2);
    q += __shfl_xor(q, 4); q += __shfl_xor(q, 8);
    float rstd = 1.0f / sqrtf(q * (1.0f / 64.0f) + EPS_);
    int cr = kg * 4 + reg;
    if (cr < 12) {
#pragma unroll
      for (int no = 0; no < 4; ++no) {
        int col = no * 16 + c;
        bt[cr * 68 + col] = (v[no * 4 + reg] - mean) * rstd * g2[col] + be2[col];
      }
    }
  }
  // wave-private RAW through LDS (lgkmcnt-ordered), then full-row stores
  {
    float* op = out + ((size_t)bn * T_ + row0) * D_;
#pragma unroll
    for (int rr = 0; rr < 3; ++rr) {
      int i = l + 64 * rr;  // 192 float4 = 12 rows x 16
      int row = i >> 4;
      int c4 = (i & 15) << 2;
      *(float4*)&op[row * D_ + c4] = *(const float4*)&bt[row * 68 + c4];
    }
  }
}

extern "C" void kernel_launch(void* const* d_in, const int* in_sizes, int n_in,
                              void* d_out, int out_size, void* d_ws,
                              size_t ws_size, hipStream_t stream) {
  const float* x = (const float*)d_in[0];
  const int* tf = (const int*)d_in[1];
  const int* idxs = (const int*)d_in[2];
  const float* Wq = (const float*)d_in[3];
  const float* Wk = (const float*)d_in[4];
  const float* Wv = (const float*)d_in[5];
  const float* Wo = (const float*)d_in[6];
  const float* bo = (const float*)d_in[7];
  const float* W1 = (const float*)d_in[8];
  const float* b1 = (const float*)d_in[9];
  const float* W2 = (const float*)d_in[10];
  const float* b2 = (const float*)d_in[11];
  const float* g1 = (const float*)d_in[12];
  const float* be1 = (const float*)d_in[13];
  const float* g2 = (const float*)d_in[14];
  const float* be2 = (const float*)d_in[15];
  const float* em = (const float*)d_in[16];
  const float* eh = (const float*)d_in[17];
  const float* ew = (const float*)d_in[18];
  const float* emo = (const float*)d_in[19];
  const float* ey = (const float*)d_in[20];
  float* out = (float*)d_out;

  float* tcpe = (float*)d_ws;  // 24576 f32 = 96 KiB
  ushort* WoB = (ushort*)((char*)d_ws + 98304);   // 8 KiB
  ushort* W1B = WoB + 4096;                        // 32 KiB
  ushort* W2B = W1B + 16384;                       // 32 KiB
  uint* Vg = (uint*)((char*)d_ws + 172032);        // 2456*1536 u32 ≈ 15 MiB

  hipLaunchKernelGGL(prep_kernel, dim3(240), dim3(256), 0, stream, tf, em, eh,
                     ew, emo, ey, tcpe, Wo, W1, W2, WoB, W1B, W2B);
  hipLaunchKernelGGL(mega_kernel, dim3(B_ * N_), dim3(256), 0, stream, x, idxs,
                     Wq, Wk, Wv, WoB, W1B, W2B, bo, b1, b2, g1, be1, g2, be2,
                     tcpe, Vg, out);
}

// Round 8
// 136.746 us; speedup vs baseline: 8.5386x; 1.0159x over previous
//
#include <hip/hip_runtime.h>

#define B_ 8
#define N_ 307
#define T_ 48
#define D_ 64
#define H_ 4
#define HD_ 16
#define SK_ 20
#define EPS_ 1e-5f

typedef __attribute__((ext_vector_type(8))) short bf16x8;
typedef __attribute__((ext_vector_type(4))) float f32x4;

__device__ inline ushort f2bf(float f) {
  union { float f; uint u; } x;
  x.f = f;
  uint u = x.u;
  return (ushort)((u + 0x7fffu + ((u >> 16) & 1u)) >> 16);  // RNE
}
__device__ inline float bflo(uint w) { return __uint_as_float(w << 16); }
__device__ inline float bfhi(uint w) {
  return __uint_as_float(w & 0xffff0000u);
}

// ---------------- kernel 1 (merged prep):
// blocks 0..95   : tcpe[B][T][64] = pe + time-feature embeddings
// blocks 96..239 : Wo/W1/W2 → bf16 MFMA B-frag order
__global__ void prep_kernel(const int* __restrict__ tf,
                            const float* __restrict__ em,
                            const float* __restrict__ eh,
                            const float* __restrict__ ew,
                            const float* __restrict__ emo,
                            const float* __restrict__ ey,
                            float* __restrict__ tcpe,
                            const float* __restrict__ Wo,
                            const float* __restrict__ W1,
                            const float* __restrict__ W2,
                            ushort* __restrict__ WoB, ushort* __restrict__ W1B,
                            ushort* __restrict__ W2B) {
  if (blockIdx.x < 96) {
    int idx = blockIdx.x * 256 + threadIdx.x;  // B*T*64 = 24576
    if (idx >= B_ * T_ * D_) return;
    int d = idx & (D_ - 1);
    int bt = idx >> 6;
    int t = bt % T_;
    float freq = expf((float)((d >> 1) << 1) * (-logf(10000.0f) / (float)D_));
    float ang = (float)t * freq;
    float pe = (d & 1) ? cosf(ang) : sinf(ang);
    const int* f = tf + bt * 5;
    tcpe[idx] = pe + em[f[0] * D_ + d] + eh[f[1] * D_ + d] +
                ew[f[2] * D_ + d] + emo[f[3] * D_ + d] + ey[f[4] * D_ + d];
  } else {
    int idx = (blockIdx.x - 96) * 256 + threadIdx.x;
    if (idx >= 4096 + 16384 + 16384) return;
    const float* W;
    ushort* O;
    int NT, N;
    if (idx < 4096) {
      W = Wo; O = WoB; NT = 4; N = 64;
    } else if (idx < 4096 + 16384) {
      idx -= 4096; W = W1; O = W1B; NT = 16; N = 256;
    } else {
      idx -= 20480; W = W2; O = W2B; NT = 4; N = 64;
    }
    int e = idx & 7;
    int l = (idx >> 3) & 63;
    int f = idx >> 9;
    int no = f % NT, ko = f / NT;
    int k = ko * 32 + (l >> 4) * 8 + e;
    int n = no * 16 + (l & 15);
    O[idx] = f2bf(W[k * N + n]);
  }
}

// ---------------- kernel 2: whole layer, one block per (b,n), 4 blocks/CU
// LDS (smem[38400] + ~1.4KB small arrays):
//   [0,13056):     enc f32[48][68] (P0-P1) → V u32[24][64] bf16-pairs (P1b-P2d)
//                  → bt out-bounce f32[12][68]/wave (epilogue)
//   [13056,26112): k f32[48][68] → attn u16[80][48] (P2c-P2d) → hs u16[52][72]
//   [26112,38400): q f32[48][64] → ft u16[16][72]/wave (FFN)
// LN1 residual re-materialized from x+tcpe (global, L2/L3-hot, prefetched).
__global__ __launch_bounds__(256, 4) void mega_kernel(
    const float* __restrict__ x, const int* __restrict__ idxs,
    const float* __restrict__ Wq, const float* __restrict__ Wk,
    const float* __restrict__ Wv, const ushort* __restrict__ WoB,
    const ushort* __restrict__ W1B, const ushort* __restrict__ W2B,
    const float* __restrict__ bo, const float* __restrict__ b1,
    const float* __restrict__ b2, const float* __restrict__ g1,
    const float* __restrict__ be1, const float* __restrict__ g2,
    const float* __restrict__ be2, const float* __restrict__ tcpe,
    float* __restrict__ out) {
  __shared__ char smem[38400];
  __shared__ float s_M[H_ * T_];
  __shared__ float s_rden[H_ * SK_];
  __shared__ int s_mtop[H_ * SK_];
  float* s_enc = (float*)smem;
  float* s_k = (float*)(smem + 13056);
  float* s_q = (float*)(smem + 26112);
  uint* s_v = (uint*)smem;               // V overlay on dead enc region
  ushort* ap = (ushort*)(smem + 13056);  // attn, overlays k after kr snapshot
  ushort* hs = (ushort*)(smem + 13056);  // ctx/h tile, after attn dead

  const int tid = threadIdx.x;
  const int l = tid & 63;
  const int g = tid >> 6;  // wave id == head id == row-stripe id
  const int bn = blockIdx.x;
  const int b = bn / N_;
  const int kg = l >> 4, c = l & 15;
  const int row0 = g * 12;

  // ---- P0: enc = x + tcpe  (stride 68)
  {
    const float4* x4 = (const float4*)(x + (size_t)bn * (T_ * D_));
    const float4* t4 = (const float4*)(tcpe + (size_t)b * (T_ * D_));
#pragma unroll
    for (int r = 0; r < 3; ++r) {
      int i = tid + 256 * r;  // 768 float4s
      float4 xv = x4[i];
      float4 tv = t4[i];
      int t = i >> 4;
      int d = (i & 15) << 2;
      *(float4*)&s_enc[t * 68 + d] =
          make_float4(xv.x + tv.x, xv.y + tv.y, xv.z + tv.z, xv.w + tv.w);
    }
  }
  __syncthreads();

  // ---- P1: fused QKV (fp32, k-chunked); Q,K → LDS; V → regs, then overlay
  {
    float accq[12], acck[12], accv[12];
#pragma unroll
    for (int i = 0; i < 12; ++i) accq[i] = acck[i] = accv[i] = 0.0f;
#pragma unroll 1
    for (int kc = 0; kc < 4; ++kc) {
      float wq[16], wk[16], wv[16];
#pragma unroll
      for (int i = 0; i < 16; ++i) {
        int k = kc * 16 + i;
        wq[i] = Wq[k * D_ + l];
        wk[i] = Wk[k * D_ + l];
        wv[i] = Wv[k * D_ + l];
      }
#pragma unroll
      for (int tt = 0; tt < 12; ++tt) {
        const float* row = &s_enc[(g * 12 + tt) * 68 + kc * 16];
        float4 r0 = ((const float4*)row)[0];
        float4 r1 = ((const float4*)row)[1];
        float4 r2 = ((const float4*)row)[2];
        float4 r3 = ((const float4*)row)[3];
        float rr[16] = {r0.x, r0.y, r0.z, r0.w, r1.x, r1.y, r1.z, r1.w,
                        r2.x, r2.y, r2.z, r2.w, r3.x, r3.y, r3.z, r3.w};
#pragma unroll
        for (int i = 0; i < 16; ++i) {
          accq[tt] = fmaf(rr[i], wq[i], accq[tt]);
          acck[tt] = fmaf(rr[i], wk[i], acck[tt]);
          accv[tt] = fmaf(rr[i], wv[i], accv[tt]);
        }
      }
    }
#pragma unroll
    for (int tt = 0; tt < 12; ++tt) {
      int t = g * 12 + tt;
      s_q[t * 64 + l] = accq[tt];
      s_k[t * 68 + l] = acck[tt];
    }
    __syncthreads();  // ALL waves' enc reads done; q,k visible; enc → V
    uint* vl = s_v + g * 6 * 64 + l;
#pragma unroll
    for (int i = 0; i < 6; ++i)
      vl[i * 64] =
          (uint)f2bf(accv[2 * i]) | ((uint)f2bf(accv[2 * i + 1]) << 16);
  }
  // (V writes ordered before P2d reads by the P2a-end barrier)

  // ---- P2a: M[t] = max_s q·k_samp − mean_s   (fp32 — selection-critical)
  if (l < T_) {
    float q[16];
#pragma unroll
    for (int j = 0; j < 16; j += 4) {
      float4 v4 = *(const float4*)&s_q[l * 64 + g * HD_ + j];
      q[j] = v4.x; q[j + 1] = v4.y; q[j + 2] = v4.z; q[j + 3] = v4.w;
    }
    const int4* ip = (const int4*)(idxs + l * SK_);
    float mx = -1e30f, sm = 0.0f;
#pragma unroll
    for (int sg = 0; sg < 5; ++sg) {
      int4 iv = ip[sg];
      int kts[4] = {iv.x, iv.y, iv.z, iv.w};
#pragma unroll
      for (int si = 0; si < 4; ++si) {
        int kt = kts[si];
        float acc = 0.0f;
#pragma unroll
        for (int j = 0; j < 16; j += 4) {
          float4 kv = *(const float4*)&s_k[kt * 68 + g * HD_ + j];
          acc = fmaf(kv.x, q[j], acc);
          acc = fmaf(kv.y, q[j + 1], acc);
          acc = fmaf(kv.z, q[j + 2], acc);
          acc = fmaf(kv.w, q[j + 3], acc);
        }
        mx = fmaxf(mx, acc);
        sm += acc;
      }
    }
    s_M[g * T_ + l] = mx - sm * (1.0f / (float)SK_);
  }
  __syncthreads();

  // ---- P2b: top-20 by rank (jax.lax.top_k tie-break: lower index first)
  if (l < T_) {
    float mv = s_M[g * T_ + l];
    int rank = 0;
    for (int t2 = 0; t2 < T_; ++t2) {
      float o = s_M[g * T_ + t2];
      rank += (o > mv || (o == mv && t2 < l)) ? 1 : 0;
    }
    if (rank < SK_) s_mtop[g * SK_ + rank] = l;
  }
  __syncthreads();

  // ---- P2c: snapshot K row → regs, then scores + UNNORMALIZED exp into
  //      the K region (attn overlay). |score| ≲ 8 << 88 so no max-sub.
  {
    float kr[16];
    if (l < T_) {
#pragma unroll
      for (int j = 0; j < 16; j += 4) {
        float4 v4 = *(const float4*)&s_k[l * 68 + g * HD_ + j];
        kr[j] = v4.x; kr[j + 1] = v4.y; kr[j + 2] = v4.z; kr[j + 3] = v4.w;
      }
    } else {
#pragma unroll
      for (int j = 0; j < 16; ++j) kr[j] = 0.0f;
    }
    __syncthreads();  // all kr snapshots done; k region → attn
#pragma unroll 1
    for (int u = 0; u < SK_; ++u) {
      int qt = s_mtop[g * SK_ + u];
      const float4* qp = (const float4*)&s_q[qt * 64 + g * HD_];
      float acc = 0.0f;
#pragma unroll
      for (int j = 0; j < 4; ++j) {
        float4 qv = qp[j];  // broadcast
        acc = fmaf(qv.x, kr[4 * j], acc);
        acc = fmaf(qv.y, kr[4 * j + 1], acc);
        acc = fmaf(qv.z, kr[4 * j + 2], acc);
        acc = fmaf(qv.w, kr[4 * j + 3], acc);
      }
      if (l < T_) ap[(g * SK_ + u) * T_ + l] = f2bf(__expf(acc * 0.25f));
    }
  }
  // denominators (same wave; lanes 0..19)
  if (l < SK_) {
    const uint* a32 = (const uint*)(smem + 13056) + (g * SK_ + l) * 24;
    float s0 = 0.0f, s1 = 0.0f;
#pragma unroll
    for (int tp = 0; tp < 24; ++tp) {
      uint w = a32[tp];
      s0 += bflo(w);
      s1 += bfhi(w);
    }
    s_rden[g * SK_ + l] = 1.0f / (s0 + s1);
  }

  // ---- P2d: upd = e @ V (V in LDS, conflict-free) ; vmean per-lane register
  const int u0 = l >> 4, jj = l & 15;
  float upd[5] = {0, 0, 0, 0, 0};
  float vm = 0.0f;
  {
    const uint* a32 = (const uint*)(smem + 13056) + g * SK_ * 24;
    const uint* v32 = s_v + g * HD_ + jj;
#pragma unroll 4
    for (int tp = 0; tp < 24; ++tp) {
      uint vw = v32[tp * 64];
      float vlo = bflo(vw), vhi = bfhi(vw);
      vm += vlo + vhi;
#pragma unroll
      for (int r = 0; r < 5; ++r) {
        uint aw = a32[(u0 + 4 * r) * 24 + tp];
        upd[r] = fmaf(bflo(aw), vlo, fmaf(bfhi(aw), vhi, upd[r]));
      }
    }
    vm *= (1.0f / (float)T_);
#pragma unroll
    for (int r = 0; r < 5; ++r) upd[r] *= s_rden[g * SK_ + u0 + 4 * r];
  }
  __syncthreads();  // all waves past attn/V reads; overlays → hs / (enc free)

  // ---- prefetch LN1 residual (x+tcpe) — hidden under scatter + Wo MFMA
  float xr[16], tr[16];
  {
    const float* xp = x + (size_t)bn * (T_ * D_);
    const float* tp2 = tcpe + (size_t)b * (T_ * D_);
#pragma unroll
    for (int reg = 0; reg < 4; ++reg) {
      int cr = kg * 4 + reg;
      int rowc = row0 + (cr < 12 ? cr : 11);  // clamp for pad rows
#pragma unroll
      for (int no = 0; no < 4; ++no) {
        xr[no * 4 + reg] = xp[rowc * D_ + no * 16 + c];
        tr[no * 4 + reg] = tp2[rowc * D_ + no * 16 + c];
      }
    }
  }

  // ---- ctx → hs (bf16): vmean fill + top-k scatter + zero pad rows 48..51
  {
    ushort cvm = f2bf(vm);
#pragma unroll
    for (int r = 0; r < 12; ++r) {
      int i = l + 64 * r;  // 768 = 48x16
      int t = i >> 4;
      hs[t * 72 + g * HD_ + jj] = cvm;
    }
    hs[(48 + u0) * 72 + g * HD_ + jj] = 0;
#pragma unroll
    for (int r = 0; r < 5; ++r) {
      int row = s_mtop[g * SK_ + u0 + 4 * r];
      hs[row * 72 + g * HD_ + jj] = f2bf(upd[r]);
    }
  }
  __syncthreads();  // hs complete (cross-wave rows)

  // ================= MFMA tail: wave g owns output rows g*12..g*12+11 ======
  ushort* ft = (ushort*)(smem + 26112) + g * 1152;  // [16][72] per wave
  const f32x4 z = {0.f, 0.f, 0.f, 0.f};

  f32x4 co[4];
  {
    bf16x8 a0 = *(const bf16x8*)(const void*)(hs + (row0 + c) * 72 + kg * 8);
    bf16x8 a1 =
        *(const bf16x8*)(const void*)(hs + (row0 + c) * 72 + 32 + kg * 8);
#pragma unroll
    for (int no = 0; no < 4; ++no) {
      bf16x8 b0 = *(const bf16x8*)(const void*)(WoB + (no * 64 + l) * 8);
      bf16x8 b1f = *(const bf16x8*)(const void*)(WoB + ((4 + no) * 64 + l) * 8);
      f32x4 t0 = __builtin_amdgcn_mfma_f32_16x16x32_bf16(a0, b0, z, 0, 0, 0);
      co[no] = __builtin_amdgcn_mfma_f32_16x16x32_bf16(a1, b1f, t0, 0, 0, 0);
    }
  }
  __syncthreads();  // Wo A-reads done before h overwrites hs

  // + bo + residual (regs), LN1 → h regs; h → hs (bf16)
  float h[16];
#pragma unroll
  for (int no = 0; no < 4; ++no) {
    int col = no * 16 + c;
    float bov = bo[col];
#pragma unroll
    for (int reg = 0; reg < 4; ++reg)
      h[no * 4 + reg] =
          co[no][reg] + bov + xr[no * 4 + reg] + tr[no * 4 + reg];
  }
#pragma unroll
  for (int reg = 0; reg < 4; ++reg) {
    float s = h[reg] + h[4 + reg] + h[8 + reg] + h[12 + reg];
    s += __shfl_xor(s, 1); s += __shfl_xor(s, 2);
    s += __shfl_xor(s, 4); s += __shfl_xor(s, 8);
    float mean = s * (1.0f / 64.0f);
    float d0 = h[reg] - mean, d1 = h[4 + reg] - mean;
    float d2 = h[8 + reg] - mean, d3 = h[12 + reg] - mean;
    float q = d0 * d0 + d1 * d1 + d2 * d2 + d3 * d3;
    q += __shfl_xor(q, 1); q += __shfl_xor(q, 2);
    q += __shfl_xor(q, 4); q += __shfl_xor(q, 8);
    float rstd = 1.0f / sqrtf(q * (1.0f / 64.0f) + EPS_);
#pragma unroll
    for (int no = 0; no < 4; ++no) {
      int col = no * 16 + c;
      h[no * 4 + reg] = (h[no * 4 + reg] - mean) * rstd * g1[col] + be1[col];
    }
  }
#pragma unroll
  for (int no = 0; no < 4; ++no)
#pragma unroll
    for (int reg = 0; reg < 4; ++reg) {
      int cr = kg * 4 + reg;
      if (cr < 12) hs[(row0 + cr) * 72 + no * 16 + c] = f2bf(h[no * 4 + reg]);
    }
  __syncthreads();  // h complete (cross-wave rows)

  // FFN: W1 → relu → W2 in four 64-col passes through wave-private ft
  f32x4 o[4] = {z, z, z, z};
  {
    bf16x8 ha0 = *(const bf16x8*)(const void*)(hs + (row0 + c) * 72 + kg * 8);
    bf16x8 ha1 =
        *(const bf16x8*)(const void*)(hs + (row0 + c) * 72 + 32 + kg * 8);
#pragma unroll 1
    for (int p = 0; p < 4; ++p) {
      f32x4 f1[4];
#pragma unroll
      for (int q = 0; q < 4; ++q) {
        int no = p * 4 + q;
        bf16x8 b0 = *(const bf16x8*)(const void*)(W1B + (no * 64 + l) * 8);
        bf16x8 b1f =
            *(const bf16x8*)(const void*)(W1B + ((16 + no) * 64 + l) * 8);
        f32x4 t0 = __builtin_amdgcn_mfma_f32_16x16x32_bf16(ha0, b0, z, 0, 0, 0);
        f1[q] = __builtin_amdgcn_mfma_f32_16x16x32_bf16(ha1, b1f, t0, 0, 0, 0);
      }
#pragma unroll
      for (int q = 0; q < 4; ++q) {
        float bb = b1[(p * 4 + q) * 16 + c];
#pragma unroll
        for (int reg = 0; reg < 4; ++reg) {
          float vv = fmaxf(f1[q][reg] + bb, 0.0f);
          ft[(kg * 4 + reg) * 72 + q * 16 + c] = f2bf(vv);
        }
      }
#pragma unroll
      for (int koi = 0; koi < 2; ++koi) {
        bf16x8 fa =
            *(const bf16x8*)(const void*)(ft + c * 72 + koi * 32 + kg * 8);
#pragma unroll
        for (int no = 0; no < 4; ++no) {
          bf16x8 bf_ = *(const bf16x8*)(const void*)(
              W2B + (((p * 2 + koi) * 4 + no) * 64 + l) * 8);
          o[no] =
              __builtin_amdgcn_mfma_f32_16x16x32_bf16(fa, bf_, o[no], 0, 0, 0);
        }
      }
    }
  }

  // + b2 + h, LN2 → wave-private bounce tile (V/enc region, dead) → out
  float* bt = (float*)smem + g * 816;  // [12][68]
  float v[16];
#pragma unroll
  for (int no = 0; no < 4; ++no) {
    float b2v = b2[no * 16 + c];
#pragma unroll
    for (int reg = 0; reg < 4; ++reg)
      v[no * 4 + reg] = o[no][reg] + b2v + h[no * 4 + reg];
  }
#pragma unroll
  for (int reg = 0; reg < 4; ++reg) {
    float s = v[reg] + v[4 + reg] + v[8 + reg] + v[12 + reg];
    s += __shfl_xor(s, 1); s += __shfl_xor(s, 2);
    s += __shfl_xor(s, 4); s += __shfl_xor(s, 8);
    float mean = s * (1.0f / 64.0f);
    float d0 = v[reg] - mean, d1 = v[4 + reg] - mean;
    float d2 = v[8 + reg] - mean, d3 = v[12 + reg] - mean;
    float q = d0 * d0 + d1 * d1 + d2 * d2 + d3 * d3;
    q += __shfl_xor(q, 1); q += __shfl_xor(q, 2);
    q += __shfl_xor(q, 4); q += __shfl_xor(q, 8);
    float rstd = 1.0f / sqrtf(q * (1.0f / 64.0f) + EPS_);
    int cr = kg * 4 + reg;
    if (cr < 12) {
#pragma unroll
      for (int no = 0; no < 4; ++no) {
        int col = no * 16 + c;
        bt[cr * 68 + col] = (v[no * 4 + reg] - mean) * rstd * g2[col] + be2[col];
      }
    }
  }
  // wave-private RAW through LDS (lgkmcnt-ordered), then full-row stores
  {
    float* op = out + ((size_t)bn * T_ + row0) * D_;
#pragma unroll
    for (int rr = 0; rr < 3; ++rr) {
      int i = l + 64 * rr;  // 192 float4 = 12 rows x 16
      int row = i >> 4;
      int c4 = (i & 15) << 2;
      *(float4*)&op[row * D_ + c4] = *(const float4*)&bt[row * 68 + c4];
    }
  }
}

extern "C" void kernel_launch(void* const* d_in, const int* in_sizes, int n_in,
                              void* d_out, int out_size, void* d_ws,
                              size_t ws_size, hipStream_t stream) {
  const float* x = (const float*)d_in[0];
  const int* tf = (const int*)d_in[1];
  const int* idxs = (const int*)d_in[2];
  const float* Wq = (const float*)d_in[3];
  const float* Wk = (const float*)d_in[4];
  const float* Wv = (const float*)d_in[5];
  const float* Wo = (const float*)d_in[6];
  const float* bo = (const float*)d_in[7];
  const float* W1 = (const float*)d_in[8];
  const float* b1 = (const float*)d_in[9];
  const float* W2 = (const float*)d_in[10];
  const float* b2 = (const float*)d_in[11];
  const float* g1 = (const float*)d_in[12];
  const float* be1 = (const float*)d_in[13];
  const float* g2 = (const float*)d_in[14];
  const float* be2 = (const float*)d_in[15];
  const float* em = (const float*)d_in[16];
  const float* eh = (const float*)d_in[17];
  const float* ew = (const float*)d_in[18];
  const float* emo = (const float*)d_in[19];
  const float* ey = (const float*)d_in[20];
  float* out = (float*)d_out;

  float* tcpe = (float*)d_ws;  // 24576 f32 = 96 KiB
  ushort* WoB = (ushort*)((char*)d_ws + 98304);  // 8 KiB
  ushort* W1B = WoB + 4096;                       // 32 KiB
  ushort* W2B = W1B + 16384;                      // 32 KiB

  hipLaunchKernelGGL(prep_kernel, dim3(240), dim3(256), 0, stream, tf, em, eh,
                     ew, emo, ey, tcpe, Wo, W1, W2, WoB, W1B, W2B);
  hipLaunchKernelGGL(mega_kernel, dim3(B_ * N_), dim3(256), 0, stream, x, idxs,
                     Wq, Wk, Wv, WoB, W1B, W2B, bo, b1, b2, g1, be1, g2, be2,
                     tcpe, out);
}

// Round 9
// 124.723 us; speedup vs baseline: 9.3616x; 1.0964x over previous
//
#include <hip/hip_runtime.h>

#define B_ 8
#define N_ 307
#define T_ 48
#define D_ 64
#define H_ 4
#define HD_ 16
#define SK_ 20
#define EPS_ 1e-5f

typedef __attribute__((ext_vector_type(8))) short bf16x8;
typedef __attribute__((ext_vector_type(4))) float f32x4;

__device__ inline ushort f2bf(float f) {
  union { float f; uint u; } x;
  x.f = f;
  uint u = x.u;
  return (ushort)((u + 0x7fffu + ((u >> 16) & 1u)) >> 16);  // RNE
}
__device__ inline float bflo(uint w) { return __uint_as_float(w << 16); }
__device__ inline float bfhi(uint w) {
  return __uint_as_float(w & 0xffff0000u);
}

// ---------------- kernel 1 (merged prep):
// blocks 0..95   : tcpe[B][T][64] = pe + time-feature embeddings
// blocks 96..239 : Wo/W1/W2 → bf16 MFMA B-frag order
__global__ void prep_kernel(const int* __restrict__ tf,
                            const float* __restrict__ em,
                            const float* __restrict__ eh,
                            const float* __restrict__ ew,
                            const float* __restrict__ emo,
                            const float* __restrict__ ey,
                            float* __restrict__ tcpe,
                            const float* __restrict__ Wo,
                            const float* __restrict__ W1,
                            const float* __restrict__ W2,
                            ushort* __restrict__ WoB, ushort* __restrict__ W1B,
                            ushort* __restrict__ W2B) {
  if (blockIdx.x < 96) {
    int idx = blockIdx.x * 256 + threadIdx.x;  // B*T*64 = 24576
    if (idx >= B_ * T_ * D_) return;
    int d = idx & (D_ - 1);
    int bt = idx >> 6;
    int t = bt % T_;
    float freq = expf((float)((d >> 1) << 1) * (-logf(10000.0f) / (float)D_));
    float ang = (float)t * freq;
    float pe = (d & 1) ? cosf(ang) : sinf(ang);
    const int* f = tf + bt * 5;
    tcpe[idx] = pe + em[f[0] * D_ + d] + eh[f[1] * D_ + d] +
                ew[f[2] * D_ + d] + emo[f[3] * D_ + d] + ey[f[4] * D_ + d];
  } else {
    int idx = (blockIdx.x - 96) * 256 + threadIdx.x;
    if (idx >= 4096 + 16384 + 16384) return;
    const float* W;
    ushort* O;
    int NT, N;
    if (idx < 4096) {
      W = Wo; O = WoB; NT = 4; N = 64;
    } else if (idx < 4096 + 16384) {
      idx -= 4096; W = W1; O = W1B; NT = 16; N = 256;
    } else {
      idx -= 20480; W = W2; O = W2B; NT = 4; N = 64;
    }
    int e = idx & 7;
    int l = (idx >> 3) & 63;
    int f = idx >> 9;
    int no = f % NT, ko = f / NT;
    int k = ko * 32 + (l >> 4) * 8 + e;
    int n = no * 16 + (l & 15);
    O[idx] = f2bf(W[k * N + n]);
  }
}

// ---------------- kernel 2: whole layer, one block per (b,n), 3 blocks/CU
// (launch_bounds 3 waves/EU → reg cap ~170: spill-free; LDS 39.9KB)
// LDS (smem[38400] + ~1.4KB small arrays):
//   [0,13056):     enc f32[48][68] (P0-P1) → V u32[24][64] bf16-pairs (P1b-P2d)
//                  → bt out-bounce f32[12][68]/wave (epilogue)
//   [13056,26112): k f32[48][68] → attn u16[80][48] (P2c-P2d) → hs u16[52][72]
//   [26112,38400): q f32[48][64] → ft u16[16][72]/wave (FFN)
// LN1 residual re-materialized from x+tcpe (global, L2/L3-hot, under Wo MFMA).
__global__ __launch_bounds__(256, 3) void mega_kernel(
    const float* __restrict__ x, const int* __restrict__ idxs,
    const float* __restrict__ Wq, const float* __restrict__ Wk,
    const float* __restrict__ Wv, const ushort* __restrict__ WoB,
    const ushort* __restrict__ W1B, const ushort* __restrict__ W2B,
    const float* __restrict__ bo, const float* __restrict__ b1,
    const float* __restrict__ b2, const float* __restrict__ g1,
    const float* __restrict__ be1, const float* __restrict__ g2,
    const float* __restrict__ be2, const float* __restrict__ tcpe,
    float* __restrict__ out) {
  __shared__ char smem[38400];
  __shared__ float s_M[H_ * T_];
  __shared__ float s_rden[H_ * SK_];
  __shared__ int s_mtop[H_ * SK_];
  float* s_enc = (float*)smem;
  float* s_k = (float*)(smem + 13056);
  float* s_q = (float*)(smem + 26112);
  uint* s_v = (uint*)smem;               // V overlay on dead enc region
  ushort* ap = (ushort*)(smem + 13056);  // attn, overlays k after kr snapshot
  ushort* hs = (ushort*)(smem + 13056);  // ctx/h tile, after attn dead

  const int tid = threadIdx.x;
  const int l = tid & 63;
  const int g = tid >> 6;  // wave id == head id == row-stripe id
  const int bn = blockIdx.x;
  const int b = bn / N_;
  const int kg = l >> 4, c = l & 15;
  const int row0 = g * 12;

  // ---- P0: enc = x + tcpe  (stride 68)
  {
    const float4* x4 = (const float4*)(x + (size_t)bn * (T_ * D_));
    const float4* t4 = (const float4*)(tcpe + (size_t)b * (T_ * D_));
#pragma unroll
    for (int r = 0; r < 3; ++r) {
      int i = tid + 256 * r;  // 768 float4s
      float4 xv = x4[i];
      float4 tv = t4[i];
      int t = i >> 4;
      int d = (i & 15) << 2;
      *(float4*)&s_enc[t * 68 + d] =
          make_float4(xv.x + tv.x, xv.y + tv.y, xv.z + tv.z, xv.w + tv.w);
    }
  }
  __syncthreads();

  // ---- P1: fused QKV (fp32, 8-wide k-chunks — low reg pressure);
  //      Q,K → LDS; V → regs, then overlay onto dead enc region
  {
    float accq[12], acck[12], accv[12];
#pragma unroll
    for (int i = 0; i < 12; ++i) accq[i] = acck[i] = accv[i] = 0.0f;
#pragma unroll 1
    for (int kc = 0; kc < 8; ++kc) {
      float wq[8], wk[8], wv[8];
#pragma unroll
      for (int i = 0; i < 8; ++i) {
        int k = kc * 8 + i;
        wq[i] = Wq[k * D_ + l];
        wk[i] = Wk[k * D_ + l];
        wv[i] = Wv[k * D_ + l];
      }
#pragma unroll
      for (int tt = 0; tt < 12; ++tt) {
        const float* row = &s_enc[(g * 12 + tt) * 68 + kc * 8];
        float4 r0 = ((const float4*)row)[0];
        float4 r1 = ((const float4*)row)[1];
        float rr[8] = {r0.x, r0.y, r0.z, r0.w, r1.x, r1.y, r1.z, r1.w};
#pragma unroll
        for (int i = 0; i < 8; ++i) {
          accq[tt] = fmaf(rr[i], wq[i], accq[tt]);
          acck[tt] = fmaf(rr[i], wk[i], acck[tt]);
          accv[tt] = fmaf(rr[i], wv[i], accv[tt]);
        }
      }
    }
#pragma unroll
    for (int tt = 0; tt < 12; ++tt) {
      int t = g * 12 + tt;
      s_q[t * 64 + l] = accq[tt];
      s_k[t * 68 + l] = acck[tt];
    }
    __syncthreads();  // ALL waves' enc reads done; q,k visible; enc → V
    uint* vl = s_v + g * 6 * 64 + l;
#pragma unroll
    for (int i = 0; i < 6; ++i)
      vl[i * 64] =
          (uint)f2bf(accv[2 * i]) | ((uint)f2bf(accv[2 * i + 1]) << 16);
  }
  // (V writes ordered before P2d reads by the P2a-end barrier)

  // ---- P2a: M[t] = max_s q·k_samp − mean_s   (fp32 — selection-critical)
  if (l < T_) {
    float q[16];
#pragma unroll
    for (int j = 0; j < 16; j += 4) {
      float4 v4 = *(const float4*)&s_q[l * 64 + g * HD_ + j];
      q[j] = v4.x; q[j + 1] = v4.y; q[j + 2] = v4.z; q[j + 3] = v4.w;
    }
    const int4* ip = (const int4*)(idxs + l * SK_);
    float mx = -1e30f, sm = 0.0f;
#pragma unroll
    for (int sg = 0; sg < 5; ++sg) {
      int4 iv = ip[sg];
      int kts[4] = {iv.x, iv.y, iv.z, iv.w};
#pragma unroll
      for (int si = 0; si < 4; ++si) {
        int kt = kts[si];
        float acc = 0.0f;
#pragma unroll
        for (int j = 0; j < 16; j += 4) {
          float4 kv = *(const float4*)&s_k[kt * 68 + g * HD_ + j];
          acc = fmaf(kv.x, q[j], acc);
          acc = fmaf(kv.y, q[j + 1], acc);
          acc = fmaf(kv.z, q[j + 2], acc);
          acc = fmaf(kv.w, q[j + 3], acc);
        }
        mx = fmaxf(mx, acc);
        sm += acc;
      }
    }
    s_M[g * T_ + l] = mx - sm * (1.0f / (float)SK_);
  }
  __syncthreads();

  // ---- P2b: top-20 by rank (jax.lax.top_k tie-break: lower index first)
  if (l < T_) {
    float mv = s_M[g * T_ + l];
    int rank = 0;
    for (int t2 = 0; t2 < T_; ++t2) {
      float o = s_M[g * T_ + t2];
      rank += (o > mv || (o == mv && t2 < l)) ? 1 : 0;
    }
    if (rank < SK_) s_mtop[g * SK_ + rank] = l;
  }
  __syncthreads();

  // ---- P2c: snapshot K row → regs, then scores + UNNORMALIZED exp into
  //      the K region (attn overlay). |score| ≲ 8 << 88 so no max-sub.
  {
    float kr[16];
    if (l < T_) {
#pragma unroll
      for (int j = 0; j < 16; j += 4) {
        float4 v4 = *(const float4*)&s_k[l * 68 + g * HD_ + j];
        kr[j] = v4.x; kr[j + 1] = v4.y; kr[j + 2] = v4.z; kr[j + 3] = v4.w;
      }
    } else {
#pragma unroll
      for (int j = 0; j < 16; ++j) kr[j] = 0.0f;
    }
    __syncthreads();  // all kr snapshots done; k region → attn
#pragma unroll 1
    for (int u = 0; u < SK_; ++u) {
      int qt = s_mtop[g * SK_ + u];
      const float4* qp = (const float4*)&s_q[qt * 64 + g * HD_];
      float acc = 0.0f;
#pragma unroll
      for (int j = 0; j < 4; ++j) {
        float4 qv = qp[j];  // broadcast
        acc = fmaf(qv.x, kr[4 * j], acc);
        acc = fmaf(qv.y, kr[4 * j + 1], acc);
        acc = fmaf(qv.z, kr[4 * j + 2], acc);
        acc = fmaf(qv.w, kr[4 * j + 3], acc);
      }
      if (l < T_) ap[(g * SK_ + u) * T_ + l] = f2bf(__expf(acc * 0.25f));
    }
  }
  // denominators (same wave; lanes 0..19)
  if (l < SK_) {
    const uint* a32 = (const uint*)(smem + 13056) + (g * SK_ + l) * 24;
    float s0 = 0.0f, s1 = 0.0f;
#pragma unroll
    for (int tp = 0; tp < 24; ++tp) {
      uint w = a32[tp];
      s0 += bflo(w);
      s1 += bfhi(w);
    }
    s_rden[g * SK_ + l] = 1.0f / (s0 + s1);
  }

  // ---- P2d: upd = e @ V (V in LDS, conflict-free) ; vmean per-lane register
  const int u0 = l >> 4, jj = l & 15;
  float upd[5] = {0, 0, 0, 0, 0};
  float vm = 0.0f;
  {
    const uint* a32 = (const uint*)(smem + 13056) + g * SK_ * 24;
    const uint* v32 = s_v + g * HD_ + jj;
#pragma unroll 4
    for (int tp = 0; tp < 24; ++tp) {
      uint vw = v32[tp * 64];
      float vlo = bflo(vw), vhi = bfhi(vw);
      vm += vlo + vhi;
#pragma unroll
      for (int r = 0; r < 5; ++r) {
        uint aw = a32[(u0 + 4 * r) * 24 + tp];
        upd[r] = fmaf(bflo(aw), vlo, fmaf(bfhi(aw), vhi, upd[r]));
      }
    }
    vm *= (1.0f / (float)T_);
#pragma unroll
    for (int r = 0; r < 5; ++r) upd[r] *= s_rden[g * SK_ + u0 + 4 * r];
  }
  __syncthreads();  // all waves past attn/V reads; overlays → hs / (enc free)

  // ---- ctx → hs (bf16): vmean fill + top-k scatter + zero pad rows 48..51
  {
    ushort cvm = f2bf(vm);
#pragma unroll
    for (int r = 0; r < 12; ++r) {
      int i = l + 64 * r;  // 768 = 48x16
      int t = i >> 4;
      hs[t * 72 + g * HD_ + jj] = cvm;
    }
    hs[(48 + u0) * 72 + g * HD_ + jj] = 0;
#pragma unroll
    for (int r = 0; r < 5; ++r) {
      int row = s_mtop[g * SK_ + u0 + 4 * r];
      hs[row * 72 + g * HD_ + jj] = f2bf(upd[r]);
    }
  }
  __syncthreads();  // hs complete (cross-wave rows)

  // ================= MFMA tail: wave g owns output rows g*12..g*12+11 ======
  ushort* ft = (ushort*)(smem + 26112) + g * 1152;  // [16][72] per wave
  const f32x4 z = {0.f, 0.f, 0.f, 0.f};

  // residual er = x+tcpe (L2/L3-hot; loads hidden under Wo MFMA below)
  float er[16];
  {
    const float* xp = x + (size_t)bn * (T_ * D_);
    const float* tp2 = tcpe + (size_t)b * (T_ * D_);
#pragma unroll
    for (int reg = 0; reg < 4; ++reg) {
      int cr = kg * 4 + reg;
      int rowc = row0 + (cr < 12 ? cr : 11);  // clamp for pad rows
#pragma unroll
      for (int no = 0; no < 4; ++no)
        er[no * 4 + reg] =
            xp[rowc * D_ + no * 16 + c] + tp2[rowc * D_ + no * 16 + c];
    }
  }

  f32x4 co[4];
  {
    bf16x8 a0 = *(const bf16x8*)(const void*)(hs + (row0 + c) * 72 + kg * 8);
    bf16x8 a1 =
        *(const bf16x8*)(const void*)(hs + (row0 + c) * 72 + 32 + kg * 8);
#pragma unroll
    for (int no = 0; no < 4; ++no) {
      bf16x8 b0 = *(const bf16x8*)(const void*)(WoB + (no * 64 + l) * 8);
      bf16x8 b1f = *(const bf16x8*)(const void*)(WoB + ((4 + no) * 64 + l) * 8);
      f32x4 t0 = __builtin_amdgcn_mfma_f32_16x16x32_bf16(a0, b0, z, 0, 0, 0);
      co[no] = __builtin_amdgcn_mfma_f32_16x16x32_bf16(a1, b1f, t0, 0, 0, 0);
    }
  }
  __syncthreads();  // Wo A-reads done before h overwrites hs

  // + bo + residual, LN1 → h regs; h → hs (bf16)
  float h[16];
#pragma unroll
  for (int no = 0; no < 4; ++no) {
    int col = no * 16 + c;
    float bov = bo[col];
#pragma unroll
    for (int reg = 0; reg < 4; ++reg)
      h[no * 4 + reg] = co[no][reg] + bov + er[no * 4 + reg];
  }
#pragma unroll
  for (int reg = 0; reg < 4; ++reg) {
    float s = h[reg] + h[4 + reg] + h[8 + reg] + h[12 + reg];
    s += __shfl_xor(s, 1); s += __shfl_xor(s, 2);
    s += __shfl_xor(s, 4); s += __shfl_xor(s, 8);
    float mean = s * (1.0f / 64.0f);
    float d0 = h[reg] - mean, d1 = h[4 + reg] - mean;
    float d2 = h[8 + reg] - mean, d3 = h[12 + reg] - mean;
    float q = d0 * d0 + d1 * d1 + d2 * d2 + d3 * d3;
    q += __shfl_xor(q, 1); q += __shfl_xor(q, 2);
    q += __shfl_xor(q, 4); q += __shfl_xor(q, 8);
    float rstd = 1.0f / sqrtf(q * (1.0f / 64.0f) + EPS_);
#pragma unroll
    for (int no = 0; no < 4; ++no) {
      int col = no * 16 + c;
      h[no * 4 + reg] = (h[no * 4 + reg] - mean) * rstd * g1[col] + be1[col];
    }
  }
#pragma unroll
  for (int no = 0; no < 4; ++no)
#pragma unroll
    for (int reg = 0; reg < 4; ++reg) {
      int cr = kg * 4 + reg;
      if (cr < 12) hs[(row0 + cr) * 72 + no * 16 + c] = f2bf(h[no * 4 + reg]);
    }
  __syncthreads();  // h complete (cross-wave rows)

  // FFN: W1 → relu → W2 in four 64-col passes through wave-private ft
  f32x4 o[4] = {z, z, z, z};
  {
    bf16x8 ha0 = *(const bf16x8*)(const void*)(hs + (row0 + c) * 72 + kg * 8);
    bf16x8 ha1 =
        *(const bf16x8*)(const void*)(hs + (row0 + c) * 72 + 32 + kg * 8);
#pragma unroll 1
    for (int p = 0; p < 4; ++p) {
      f32x4 f1[4];
#pragma unroll
      for (int q = 0; q < 4; ++q) {
        int no = p * 4 + q;
        bf16x8 b0 = *(const bf16x8*)(const void*)(W1B + (no * 64 + l) * 8);
        bf16x8 b1f =
            *(const bf16x8*)(const void*)(W1B + ((16 + no) * 64 + l) * 8);
        f32x4 t0 = __builtin_amdgcn_mfma_f32_16x16x32_bf16(ha0, b0, z, 0, 0, 0);
        f1[q] = __builtin_amdgcn_mfma_f32_16x16x32_bf16(ha1, b1f, t0, 0, 0, 0);
      }
#pragma unroll
      for (int q = 0; q < 4; ++q) {
        float bb = b1[(p * 4 + q) * 16 + c];
#pragma unroll
        for (int reg = 0; reg < 4; ++reg) {
          float vv = fmaxf(f1[q][reg] + bb, 0.0f);
          ft[(kg * 4 + reg) * 72 + q * 16 + c] = f2bf(vv);
        }
      }
#pragma unroll
      for (int koi = 0; koi < 2; ++koi) {
        bf16x8 fa =
            *(const bf16x8*)(const void*)(ft + c * 72 + koi * 32 + kg * 8);
#pragma unroll
        for (int no = 0; no < 4; ++no) {
          bf16x8 bf_ = *(const bf16x8*)(const void*)(
              W2B + (((p * 2 + koi) * 4 + no) * 64 + l) * 8);
          o[no] =
              __builtin_amdgcn_mfma_f32_16x16x32_bf16(fa, bf_, o[no], 0, 0, 0);
        }
      }
    }
  }

  // + b2 + h, LN2 → wave-private bounce tile (V/enc region, dead) → out
  float* bt = (float*)smem + g * 816;  // [12][68]
  float v[16];
#pragma unroll
  for (int no = 0; no < 4; ++no) {
    float b2v = b2[no * 16 + c];
#pragma unroll
    for (int reg = 0; reg < 4; ++reg)
      v[no * 4 + reg] = o[no][reg] + b2v + h[no * 4 + reg];
  }
#pragma unroll
  for (int reg = 0; reg < 4; ++reg) {
    float s = v[reg] + v[4 + reg] + v[8 + reg] + v[12 + reg];
    s += __shfl_xor(s, 1); s += __shfl_xor(s, 2);
    s += __shfl_xor(s, 4); s += __shfl_xor(s, 8);
    float mean = s * (1.0f / 64.0f);
    float d0 = v[reg] - mean, d1 = v[4 + reg] - mean;
    float d2 = v[8 + reg] - mean, d3 = v[12 + reg] - mean;
    float q = d0 * d0 + d1 * d1 + d2 * d2 + d3 * d3;
    q += __shfl_xor(q, 1); q += __shfl_xor(q, 2);
    q += __shfl_xor(q, 4); q += __shfl_xor(q, 8);
    float rstd = 1.0f / sqrtf(q * (1.0f / 64.0f) + EPS_);
    int cr = kg * 4 + reg;
    if (cr < 12) {
#pragma unroll
      for (int no = 0; no < 4; ++no) {
        int col = no * 16 + c;
        bt[cr * 68 + col] = (v[no * 4 + reg] - mean) * rstd * g2[col] + be2[col];
      }
    }
  }
  // wave-private RAW through LDS (lgkmcnt-ordered), then full-row stores
  {
    float* op = out + ((size_t)bn * T_ + row0) * D_;
#pragma unroll
    for (int rr = 0; rr < 3; ++rr) {
      int i = l + 64 * rr;  // 192 float4 = 12 rows x 16
      int row = i >> 4;
      int c4 = (i & 15) << 2;
      *(float4*)&op[row * D_ + c4] = *(const float4*)&bt[row * 68 + c4];
    }
  }
}

extern "C" void kernel_launch(void* const* d_in, const int* in_sizes, int n_in,
                              void* d_out, int out_size, void* d_ws,
                              size_t ws_size, hipStream_t stream) {
  const float* x = (const float*)d_in[0];
  const int* tf = (const int*)d_in[1];
  const int* idxs = (const int*)d_in[2];
  const float* Wq = (const float*)d_in[3];
  const float* Wk = (const float*)d_in[4];
  const float* Wv = (const float*)d_in[5];
  const float* Wo = (const float*)d_in[6];
  const float* bo = (const float*)d_in[7];
  const float* W1 = (const float*)d_in[8];
  const float* b1 = (const float*)d_in[9];
  const float* W2 = (const float*)d_in[10];
  const float* b2 = (const float*)d_in[11];
  const float* g1 = (const float*)d_in[12];
  const float* be1 = (const float*)d_in[13];
  const float* g2 = (const float*)d_in[14];
  const float* be2 = (const float*)d_in[15];
  const float* em = (const float*)d_in[16];
  const float* eh = (const float*)d_in[17];
  const float* ew = (const float*)d_in[18];
  const float* emo = (const float*)d_in[19];
  const float* ey = (const float*)d_in[20];
  float* out = (float*)d_out;

  float* tcpe = (float*)d_ws;  // 24576 f32 = 96 KiB
  ushort* WoB = (ushort*)((char*)d_ws + 98304);  // 8 KiB
  ushort* W1B = WoB + 4096;                       // 32 KiB
  ushort* W2B = W1B + 16384;                      // 32 KiB

  hipLaunchKernelGGL(prep_kernel, dim3(240), dim3(256), 0, stream, tf, em, eh,
                     ew, emo, ey, tcpe, Wo, W1, W2, WoB, W1B, W2B);
  hipLaunchKernelGGL(mega_kernel, dim3(B_ * N_), dim3(256), 0, stream, x, idxs,
                     Wq, Wk, Wv, WoB, W1B, W2B, bo, b1, b2, g1, be1, g2, be2,
                     tcpe, out);
}

// Round 10
// 116.815 us; speedup vs baseline: 9.9955x; 1.0677x over previous
//
#include <hip/hip_runtime.h>

#define B_ 8
#define N_ 307
#define T_ 48
#define D_ 64
#define H_ 4
#define HD_ 16
#define SK_ 20
#define EPS_ 1e-5f

typedef __attribute__((ext_vector_type(8))) short bf16x8;
typedef __attribute__((ext_vector_type(4))) float f32x4;

__device__ inline ushort f2bf(float f) {
  union { float f; uint u; } x;
  x.f = f;
  uint u = x.u;
  return (ushort)((u + 0x7fffu + ((u >> 16) & 1u)) >> 16);  // RNE
}
__device__ inline float bflo(uint w) { return __uint_as_float(w << 16); }
__device__ inline float bfhi(uint w) {
  return __uint_as_float(w & 0xffff0000u);
}

// ---------------- kernel 1 (merged prep):
// blocks 0..95   : tcpe[B][T][64] = pe + time-feature embeddings
// blocks 96..239 : Wo/W1/W2 → bf16 MFMA B-frag order
__global__ void prep_kernel(const int* __restrict__ tf,
                            const float* __restrict__ em,
                            const float* __restrict__ eh,
                            const float* __restrict__ ew,
                            const float* __restrict__ emo,
                            const float* __restrict__ ey,
                            float* __restrict__ tcpe,
                            const float* __restrict__ Wo,
                            const float* __restrict__ W1,
                            const float* __restrict__ W2,
                            ushort* __restrict__ WoB, ushort* __restrict__ W1B,
                            ushort* __restrict__ W2B) {
  if (blockIdx.x < 96) {
    int idx = blockIdx.x * 256 + threadIdx.x;  // B*T*64 = 24576
    if (idx >= B_ * T_ * D_) return;
    int d = idx & (D_ - 1);
    int bt = idx >> 6;
    int t = bt % T_;
    float freq = expf((float)((d >> 1) << 1) * (-logf(10000.0f) / (float)D_));
    float ang = (float)t * freq;
    float pe = (d & 1) ? cosf(ang) : sinf(ang);
    const int* f = tf + bt * 5;
    tcpe[idx] = pe + em[f[0] * D_ + d] + eh[f[1] * D_ + d] +
                ew[f[2] * D_ + d] + emo[f[3] * D_ + d] + ey[f[4] * D_ + d];
  } else {
    int idx = (blockIdx.x - 96) * 256 + threadIdx.x;
    if (idx >= 4096 + 16384 + 16384) return;
    const float* W;
    ushort* O;
    int NT, N;
    if (idx < 4096) {
      W = Wo; O = WoB; NT = 4; N = 64;
    } else if (idx < 4096 + 16384) {
      idx -= 4096; W = W1; O = W1B; NT = 16; N = 256;
    } else {
      idx -= 20480; W = W2; O = W2B; NT = 4; N = 64;
    }
    int e = idx & 7;
    int l = (idx >> 3) & 63;
    int f = idx >> 9;
    int no = f % NT, ko = f / NT;
    int k = ko * 32 + (l >> 4) * 8 + e;
    int n = no * 16 + (l & 15);
    O[idx] = f2bf(W[k * N + n]);
  }
}

// ---------------- kernel 2: whole layer, one block per (b,n), 4 blocks/CU
// (slim register build: 8-wide P1 chunks + 16-reg residual → ~68 arch VGPR,
//  fits the 128-unified cap of 4 waves/EU without scratch spill)
// LDS (smem[38400] + ~1.4KB small arrays = 39936B; ×4 = 159744 ≤ 160KiB):
//   [0,13056):     enc f32[48][68] (P0-P1) → V u32[24][64] bf16-pairs (P1b-P2d)
//                  → bt out-bounce f32[12][68]/wave (epilogue)
//   [13056,26112): k f32[48][68] → attn u16[80][48] (P2c-P2d) → hs u16[52][72]
//   [26112,38400): q f32[48][64] → ft u16[16][72]/wave (FFN)
// LN1 residual re-materialized from x+tcpe (global, L2/L3-hot, under Wo MFMA).
__global__ __launch_bounds__(256, 4) void mega_kernel(
    const float* __restrict__ x, const int* __restrict__ idxs,
    const float* __restrict__ Wq, const float* __restrict__ Wk,
    const float* __restrict__ Wv, const ushort* __restrict__ WoB,
    const ushort* __restrict__ W1B, const ushort* __restrict__ W2B,
    const float* __restrict__ bo, const float* __restrict__ b1,
    const float* __restrict__ b2, const float* __restrict__ g1,
    const float* __restrict__ be1, const float* __restrict__ g2,
    const float* __restrict__ be2, const float* __restrict__ tcpe,
    float* __restrict__ out) {
  __shared__ char smem[38400];
  __shared__ float s_M[H_ * T_];
  __shared__ float s_rden[H_ * SK_];
  __shared__ int s_mtop[H_ * SK_];
  float* s_enc = (float*)smem;
  float* s_k = (float*)(smem + 13056);
  float* s_q = (float*)(smem + 26112);
  uint* s_v = (uint*)smem;               // V overlay on dead enc region
  ushort* ap = (ushort*)(smem + 13056);  // attn, overlays k after kr snapshot
  ushort* hs = (ushort*)(smem + 13056);  // ctx/h tile, after attn dead

  const int tid = threadIdx.x;
  const int l = tid & 63;
  const int g = tid >> 6;  // wave id == head id == row-stripe id
  const int bn = blockIdx.x;
  const int b = bn / N_;
  const int kg = l >> 4, c = l & 15;
  const int row0 = g * 12;

  // ---- P0: enc = x + tcpe  (stride 68)
  {
    const float4* x4 = (const float4*)(x + (size_t)bn * (T_ * D_));
    const float4* t4 = (const float4*)(tcpe + (size_t)b * (T_ * D_));
#pragma unroll
    for (int r = 0; r < 3; ++r) {
      int i = tid + 256 * r;  // 768 float4s
      float4 xv = x4[i];
      float4 tv = t4[i];
      int t = i >> 4;
      int d = (i & 15) << 2;
      *(float4*)&s_enc[t * 68 + d] =
          make_float4(xv.x + tv.x, xv.y + tv.y, xv.z + tv.z, xv.w + tv.w);
    }
  }
  __syncthreads();

  // ---- P1: fused QKV (fp32, 8-wide k-chunks — low reg pressure);
  //      Q,K → LDS; V → regs, then overlay onto dead enc region
  {
    float accq[12], acck[12], accv[12];
#pragma unroll
    for (int i = 0; i < 12; ++i) accq[i] = acck[i] = accv[i] = 0.0f;
#pragma unroll 1
    for (int kc = 0; kc < 8; ++kc) {
      float wq[8], wk[8], wv[8];
#pragma unroll
      for (int i = 0; i < 8; ++i) {
        int k = kc * 8 + i;
        wq[i] = Wq[k * D_ + l];
        wk[i] = Wk[k * D_ + l];
        wv[i] = Wv[k * D_ + l];
      }
#pragma unroll
      for (int tt = 0; tt < 12; ++tt) {
        const float* row = &s_enc[(g * 12 + tt) * 68 + kc * 8];
        float4 r0 = ((const float4*)row)[0];
        float4 r1 = ((const float4*)row)[1];
        float rr[8] = {r0.x, r0.y, r0.z, r0.w, r1.x, r1.y, r1.z, r1.w};
#pragma unroll
        for (int i = 0; i < 8; ++i) {
          accq[tt] = fmaf(rr[i], wq[i], accq[tt]);
          acck[tt] = fmaf(rr[i], wk[i], acck[tt]);
          accv[tt] = fmaf(rr[i], wv[i], accv[tt]);
        }
      }
    }
#pragma unroll
    for (int tt = 0; tt < 12; ++tt) {
      int t = g * 12 + tt;
      s_q[t * 64 + l] = accq[tt];
      s_k[t * 68 + l] = acck[tt];
    }
    __syncthreads();  // ALL waves' enc reads done; q,k visible; enc → V
    uint* vl = s_v + g * 6 * 64 + l;
#pragma unroll
    for (int i = 0; i < 6; ++i)
      vl[i * 64] =
          (uint)f2bf(accv[2 * i]) | ((uint)f2bf(accv[2 * i + 1]) << 16);
  }
  // (V writes ordered before P2d reads by the P2a-end barrier)

  // ---- P2a: M[t] = max_s q·k_samp − mean_s   (fp32 — selection-critical)
  if (l < T_) {
    float q[16];
#pragma unroll
    for (int j = 0; j < 16; j += 4) {
      float4 v4 = *(const float4*)&s_q[l * 64 + g * HD_ + j];
      q[j] = v4.x; q[j + 1] = v4.y; q[j + 2] = v4.z; q[j + 3] = v4.w;
    }
    const int4* ip = (const int4*)(idxs + l * SK_);
    float mx = -1e30f, sm = 0.0f;
#pragma unroll
    for (int sg = 0; sg < 5; ++sg) {
      int4 iv = ip[sg];
      int kts[4] = {iv.x, iv.y, iv.z, iv.w};
#pragma unroll
      for (int si = 0; si < 4; ++si) {
        int kt = kts[si];
        float acc = 0.0f;
#pragma unroll
        for (int j = 0; j < 16; j += 4) {
          float4 kv = *(const float4*)&s_k[kt * 68 + g * HD_ + j];
          acc = fmaf(kv.x, q[j], acc);
          acc = fmaf(kv.y, q[j + 1], acc);
          acc = fmaf(kv.z, q[j + 2], acc);
          acc = fmaf(kv.w, q[j + 3], acc);
        }
        mx = fmaxf(mx, acc);
        sm += acc;
      }
    }
    s_M[g * T_ + l] = mx - sm * (1.0f / (float)SK_);
  }
  __syncthreads();

  // ---- P2b: top-20 by rank (jax.lax.top_k tie-break: lower index first)
  if (l < T_) {
    float mv = s_M[g * T_ + l];
    int rank = 0;
    for (int t2 = 0; t2 < T_; ++t2) {
      float o = s_M[g * T_ + t2];
      rank += (o > mv || (o == mv && t2 < l)) ? 1 : 0;
    }
    if (rank < SK_) s_mtop[g * SK_ + rank] = l;
  }
  __syncthreads();

  // ---- P2c: snapshot K row → regs, then scores + UNNORMALIZED exp into
  //      the K region (attn overlay). |score| ≲ 8 << 88 so no max-sub.
  {
    float kr[16];
    if (l < T_) {
#pragma unroll
      for (int j = 0; j < 16; j += 4) {
        float4 v4 = *(const float4*)&s_k[l * 68 + g * HD_ + j];
        kr[j] = v4.x; kr[j + 1] = v4.y; kr[j + 2] = v4.z; kr[j + 3] = v4.w;
      }
    } else {
#pragma unroll
      for (int j = 0; j < 16; ++j) kr[j] = 0.0f;
    }
    __syncthreads();  // all kr snapshots done; k region → attn
#pragma unroll 1
    for (int u = 0; u < SK_; ++u) {
      int qt = s_mtop[g * SK_ + u];
      const float4* qp = (const float4*)&s_q[qt * 64 + g * HD_];
      float acc = 0.0f;
#pragma unroll
      for (int j = 0; j < 4; ++j) {
        float4 qv = qp[j];  // broadcast
        acc = fmaf(qv.x, kr[4 * j], acc);
        acc = fmaf(qv.y, kr[4 * j + 1], acc);
        acc = fmaf(qv.z, kr[4 * j + 2], acc);
        acc = fmaf(qv.w, kr[4 * j + 3], acc);
      }
      if (l < T_) ap[(g * SK_ + u) * T_ + l] = f2bf(__expf(acc * 0.25f));
    }
  }
  // denominators (same wave; lanes 0..19)
  if (l < SK_) {
    const uint* a32 = (const uint*)(smem + 13056) + (g * SK_ + l) * 24;
    float s0 = 0.0f, s1 = 0.0f;
#pragma unroll
    for (int tp = 0; tp < 24; ++tp) {
      uint w = a32[tp];
      s0 += bflo(w);
      s1 += bfhi(w);
    }
    s_rden[g * SK_ + l] = 1.0f / (s0 + s1);
  }

  // ---- P2d: upd = e @ V (V in LDS, conflict-free) ; vmean per-lane register
  const int u0 = l >> 4, jj = l & 15;
  float upd[5] = {0, 0, 0, 0, 0};
  float vm = 0.0f;
  {
    const uint* a32 = (const uint*)(smem + 13056) + g * SK_ * 24;
    const uint* v32 = s_v + g * HD_ + jj;
#pragma unroll 4
    for (int tp = 0; tp < 24; ++tp) {
      uint vw = v32[tp * 64];
      float vlo = bflo(vw), vhi = bfhi(vw);
      vm += vlo + vhi;
#pragma unroll
      for (int r = 0; r < 5; ++r) {
        uint aw = a32[(u0 + 4 * r) * 24 + tp];
        upd[r] = fmaf(bflo(aw), vlo, fmaf(bfhi(aw), vhi, upd[r]));
      }
    }
    vm *= (1.0f / (float)T_);
#pragma unroll
    for (int r = 0; r < 5; ++r) upd[r] *= s_rden[g * SK_ + u0 + 4 * r];
  }
  __syncthreads();  // all waves past attn/V reads; overlays → hs / (enc free)

  // ---- ctx → hs (bf16): vmean fill + top-k scatter + zero pad rows 48..51
  {
    ushort cvm = f2bf(vm);
#pragma unroll
    for (int r = 0; r < 12; ++r) {
      int i = l + 64 * r;  // 768 = 48x16
      int t = i >> 4;
      hs[t * 72 + g * HD_ + jj] = cvm;
    }
    hs[(48 + u0) * 72 + g * HD_ + jj] = 0;
#pragma unroll
    for (int r = 0; r < 5; ++r) {
      int row = s_mtop[g * SK_ + u0 + 4 * r];
      hs[row * 72 + g * HD_ + jj] = f2bf(upd[r]);
    }
  }
  __syncthreads();  // hs complete (cross-wave rows)

  // ================= MFMA tail: wave g owns output rows g*12..g*12+11 ======
  ushort* ft = (ushort*)(smem + 26112) + g * 1152;  // [16][72] per wave
  const f32x4 z = {0.f, 0.f, 0.f, 0.f};

  // residual er = x+tcpe (L2/L3-hot; loads hidden under Wo MFMA below)
  float er[16];
  {
    const float* xp = x + (size_t)bn * (T_ * D_);
    const float* tp2 = tcpe + (size_t)b * (T_ * D_);
#pragma unroll
    for (int reg = 0; reg < 4; ++reg) {
      int cr = kg * 4 + reg;
      int rowc = row0 + (cr < 12 ? cr : 11);  // clamp for pad rows
#pragma unroll
      for (int no = 0; no < 4; ++no)
        er[no * 4 + reg] =
            xp[rowc * D_ + no * 16 + c] + tp2[rowc * D_ + no * 16 + c];
    }
  }

  f32x4 co[4];
  {
    bf16x8 a0 = *(const bf16x8*)(const void*)(hs + (row0 + c) * 72 + kg * 8);
    bf16x8 a1 =
        *(const bf16x8*)(const void*)(hs + (row0 + c) * 72 + 32 + kg * 8);
#pragma unroll
    for (int no = 0; no < 4; ++no) {
      bf16x8 b0 = *(const bf16x8*)(const void*)(WoB + (no * 64 + l) * 8);
      bf16x8 b1f = *(const bf16x8*)(const void*)(WoB + ((4 + no) * 64 + l) * 8);
      f32x4 t0 = __builtin_amdgcn_mfma_f32_16x16x32_bf16(a0, b0, z, 0, 0, 0);
      co[no] = __builtin_amdgcn_mfma_f32_16x16x32_bf16(a1, b1f, t0, 0, 0, 0);
    }
  }
  __syncthreads();  // Wo A-reads done before h overwrites hs

  // + bo + residual, LN1 → h regs; h → hs (bf16)
  float h[16];
#pragma unroll
  for (int no = 0; no < 4; ++no) {
    int col = no * 16 + c;
    float bov = bo[col];
#pragma unroll
    for (int reg = 0; reg < 4; ++reg)
      h[no * 4 + reg] = co[no][reg] + bov + er[no * 4 + reg];
  }
#pragma unroll
  for (int reg = 0; reg < 4; ++reg) {
    float s = h[reg] + h[4 + reg] + h[8 + reg] + h[12 + reg];
    s += __shfl_xor(s, 1); s += __shfl_xor(s, 2);
    s += __shfl_xor(s, 4); s += __shfl_xor(s, 8);
    float mean = s * (1.0f / 64.0f);
    float d0 = h[reg] - mean, d1 = h[4 + reg] - mean;
    float d2 = h[8 + reg] - mean, d3 = h[12 + reg] - mean;
    float q = d0 * d0 + d1 * d1 + d2 * d2 + d3 * d3;
    q += __shfl_xor(q, 1); q += __shfl_xor(q, 2);
    q += __shfl_xor(q, 4); q += __shfl_xor(q, 8);
    float rstd = 1.0f / sqrtf(q * (1.0f / 64.0f) + EPS_);
#pragma unroll
    for (int no = 0; no < 4; ++no) {
      int col = no * 16 + c;
      h[no * 4 + reg] = (h[no * 4 + reg] - mean) * rstd * g1[col] + be1[col];
    }
  }
#pragma unroll
  for (int no = 0; no < 4; ++no)
#pragma unroll
    for (int reg = 0; reg < 4; ++reg) {
      int cr = kg * 4 + reg;
      if (cr < 12) hs[(row0 + cr) * 72 + no * 16 + c] = f2bf(h[no * 4 + reg]);
    }
  __syncthreads();  // h complete (cross-wave rows)

  // FFN: W1 → relu → W2 in four 64-col passes through wave-private ft
  f32x4 o[4] = {z, z, z, z};
  {
    bf16x8 ha0 = *(const bf16x8*)(const void*)(hs + (row0 + c) * 72 + kg * 8);
    bf16x8 ha1 =
        *(const bf16x8*)(const void*)(hs + (row0 + c) * 72 + 32 + kg * 8);
#pragma unroll 1
    for (int p = 0; p < 4; ++p) {
      f32x4 f1[4];
#pragma unroll
      for (int q = 0; q < 4; ++q) {
        int no = p * 4 + q;
        bf16x8 b0 = *(const bf16x8*)(const void*)(W1B + (no * 64 + l) * 8);
        bf16x8 b1f =
            *(const bf16x8*)(const void*)(W1B + ((16 + no) * 64 + l) * 8);
        f32x4 t0 = __builtin_amdgcn_mfma_f32_16x16x32_bf16(ha0, b0, z, 0, 0, 0);
        f1[q] = __builtin_amdgcn_mfma_f32_16x16x32_bf16(ha1, b1f, t0, 0, 0, 0);
      }
#pragma unroll
      for (int q = 0; q < 4; ++q) {
        float bb = b1[(p * 4 + q) * 16 + c];
#pragma unroll
        for (int reg = 0; reg < 4; ++reg) {
          float vv = fmaxf(f1[q][reg] + bb, 0.0f);
          ft[(kg * 4 + reg) * 72 + q * 16 + c] = f2bf(vv);
        }
      }
#pragma unroll
      for (int koi = 0; koi < 2; ++koi) {
        bf16x8 fa =
            *(const bf16x8*)(const void*)(ft + c * 72 + koi * 32 + kg * 8);
#pragma unroll
        for (int no = 0; no < 4; ++no) {
          bf16x8 bf_ = *(const bf16x8*)(const void*)(
              W2B + (((p * 2 + koi) * 4 + no) * 64 + l) * 8);
          o[no] =
              __builtin_amdgcn_mfma_f32_16x16x32_bf16(fa, bf_, o[no], 0, 0, 0);
        }
      }
    }
  }

  // + b2 + h, LN2 → wave-private bounce tile (V/enc region, dead) → out
  float* bt = (float*)smem + g * 816;  // [12][68]
  float v[16];
#pragma unroll
  for (int no = 0; no < 4; ++no) {
    float b2v = b2[no * 16 + c];
#pragma unroll
    for (int reg = 0; reg < 4; ++reg)
      v[no * 4 + reg] = o[no][reg] + b2v + h[no * 4 + reg];
  }
#pragma unroll
  for (int reg = 0; reg < 4; ++reg) {
    float s = v[reg] + v[4 + reg] + v[8 + reg] + v[12 + reg];
    s += __shfl_xor(s, 1); s += __shfl_xor(s, 2);
    s += __shfl_xor(s, 4); s += __shfl_xor(s, 8);
    float mean = s * (1.0f / 64.0f);
    float d0 = v[reg] - mean, d1 = v[4 + reg] - mean;
    float d2 = v[8 + reg] - mean, d3 = v[12 + reg] - mean;
    float q = d0 * d0 + d1 * d1 + d2 * d2 + d3 * d3;
    q += __shfl_xor(q, 1); q += __shfl_xor(q, 2);
    q += __shfl_xor(q, 4); q += __shfl_xor(q, 8);
    float rstd = 1.0f / sqrtf(q * (1.0f / 64.0f) + EPS_);
    int cr = kg * 4 + reg;
    if (cr < 12) {
#pragma unroll
      for (int no = 0; no < 4; ++no) {
        int col = no * 16 + c;
        bt[cr * 68 + col] = (v[no * 4 + reg] - mean) * rstd * g2[col] + be2[col];
      }
    }
  }
  // wave-private RAW through LDS (lgkmcnt-ordered), then full-row stores
  {
    float* op = out + ((size_t)bn * T_ + row0) * D_;
#pragma unroll
    for (int rr = 0; rr < 3; ++rr) {
      int i = l + 64 * rr;  // 192 float4 = 12 rows x 16
      int row = i >> 4;
      int c4 = (i & 15) << 2;
      *(float4*)&op[row * D_ + c4] = *(const float4*)&bt[row * 68 + c4];
    }
  }
}

extern "C" void kernel_launch(void* const* d_in, const int* in_sizes, int n_in,
                              void* d_out, int out_size, void* d_ws,
                              size_t ws_size, hipStream_t stream) {
  const float* x = (const float*)d_in[0];
  const int* tf = (const int*)d_in[1];
  const int* idxs = (const int*)d_in[2];
  const float* Wq = (const float*)d_in[3];
  const float* Wk = (const float*)d_in[4];
  const float* Wv = (const float*)d_in[5];
  const float* Wo = (const float*)d_in[6];
  const float* bo = (const float*)d_in[7];
  const float* W1 = (const float*)d_in[8];
  const float* b1 = (const float*)d_in[9];
  const float* W2 = (const float*)d_in[10];
  const float* b2 = (const float*)d_in[11];
  const float* g1 = (const float*)d_in[12];
  const float* be1 = (const float*)d_in[13];
  const float* g2 = (const float*)d_in[14];
  const float* be2 = (const float*)d_in[15];
  const float* em = (const float*)d_in[16];
  const float* eh = (const float*)d_in[17];
  const float* ew = (const float*)d_in[18];
  const float* emo = (const float*)d_in[19];
  const float* ey = (const float*)d_in[20];
  float* out = (float*)d_out;

  float* tcpe = (float*)d_ws;  // 24576 f32 = 96 KiB
  ushort* WoB = (ushort*)((char*)d_ws + 98304);  // 8 KiB
  ushort* W1B = WoB + 4096;                       // 32 KiB
  ushort* W2B = W1B + 16384;                      // 32 KiB

  hipLaunchKernelGGL(prep_kernel, dim3(240), dim3(256), 0, stream, tf, em, eh,
                     ew, emo, ey, tcpe, Wo, W1, W2, WoB, W1B, W2B);
  hipLaunchKernelGGL(mega_kernel, dim3(B_ * N_), dim3(256), 0, stream, x, idxs,
                     Wq, Wk, Wv, WoB, W1B, W2B, bo, b1, b2, g1, be1, g2, be2,
                     tcpe, out);
}

// Round 14
// 116.735 us; speedup vs baseline: 10.0023x; 1.0007x over previous
//
#include <hip/hip_runtime.h>

#define B_ 8
#define N_ 307
#define T_ 48
#define D_ 64
#define H_ 4
#define HD_ 16
#define SK_ 20
#define EPS_ 1e-5f

typedef __attribute__((ext_vector_type(8))) short bf16x8;
typedef __attribute__((ext_vector_type(4))) float f32x4;

__device__ inline ushort f2bf(float f) {
  union { float f; uint u; } x;
  x.f = f;
  uint u = x.u;
  return (ushort)((u + 0x7fffu + ((u >> 16) & 1u)) >> 16);  // RNE
}
__device__ inline float bflo(uint w) { return __uint_as_float(w << 16); }
__device__ inline float bfhi(uint w) {
  return __uint_as_float(w & 0xffff0000u);
}

// ---------------- kernel 1 (merged prep):
// blocks 0..95   : tcpe[B][T][64] = pe + time-feature embeddings
// blocks 96..239 : Wo/W1/W2 → bf16 MFMA B-frag order
__global__ void prep_kernel(const int* __restrict__ tf,
                            const float* __restrict__ em,
                            const float* __restrict__ eh,
                            const float* __restrict__ ew,
                            const float* __restrict__ emo,
                            const float* __restrict__ ey,
                            float* __restrict__ tcpe,
                            const float* __restrict__ Wo,
                            const float* __restrict__ W1,
                            const float* __restrict__ W2,
                            ushort* __restrict__ WoB, ushort* __restrict__ W1B,
                            ushort* __restrict__ W2B) {
  if (blockIdx.x < 96) {
    int idx = blockIdx.x * 256 + threadIdx.x;  // B*T*64 = 24576
    if (idx >= B_ * T_ * D_) return;
    int d = idx & (D_ - 1);
    int bt = idx >> 6;
    int t = bt % T_;
    float freq = expf((float)((d >> 1) << 1) * (-logf(10000.0f) / (float)D_));
    float ang = (float)t * freq;
    float pe = (d & 1) ? cosf(ang) : sinf(ang);
    const int* f = tf + bt * 5;
    tcpe[idx] = pe + em[f[0] * D_ + d] + eh[f[1] * D_ + d] +
                ew[f[2] * D_ + d] + emo[f[3] * D_ + d] + ey[f[4] * D_ + d];
  } else {
    int idx = (blockIdx.x - 96) * 256 + threadIdx.x;
    if (idx >= 4096 + 16384 + 16384) return;
    const float* W;
    ushort* O;
    int NT, N;
    if (idx < 4096) {
      W = Wo; O = WoB; NT = 4; N = 64;
    } else if (idx < 4096 + 16384) {
      idx -= 4096; W = W1; O = W1B; NT = 16; N = 256;
    } else {
      idx -= 20480; W = W2; O = W2B; NT = 4; N = 64;
    }
    int e = idx & 7;
    int l = (idx >> 3) & 63;
    int f = idx >> 9;
    int no = f % NT, ko = f / NT;
    int k = ko * 32 + (l >> 4) * 8 + e;
    int n = no * 16 + (l & 15);
    O[idx] = f2bf(W[k * N + n]);
  }
}

// ---------------- kernel 2: whole layer, one block per (b,n), 4 blocks/CU
// (slim register build: 8-wide P1 chunks + 16-reg residual → ~68 arch VGPR,
//  fits the 128-unified cap of 4 waves/EU without scratch spill)
// LDS (smem[38400] + ~1.4KB small arrays = 39936B; ×4 = 159744 ≤ 160KiB):
//   [0,13056):     enc f32[48][68] (P0-P1) → V u32[24][64] bf16-pairs (P1b-P2d)
//                  → bt out-bounce f32[12][68]/wave (epilogue)
//   [13056,26112): k f32[48][68] → attn u16[80][48] (P2c-P2d) → hs u16[52][72]
//   [26112,38400): q f32[48][64] → ft u16[16][72]/wave (FFN)
// LN1 residual re-materialized from x+tcpe (global, L2/L3-hot, under Wo MFMA).
__global__ __launch_bounds__(256, 4) void mega_kernel(
    const float* __restrict__ x, const int* __restrict__ idxs,
    const float* __restrict__ Wq, const float* __restrict__ Wk,
    const float* __restrict__ Wv, const ushort* __restrict__ WoB,
    const ushort* __restrict__ W1B, const ushort* __restrict__ W2B,
    const float* __restrict__ bo, const float* __restrict__ b1,
    const float* __restrict__ b2, const float* __restrict__ g1,
    const float* __restrict__ be1, const float* __restrict__ g2,
    const float* __restrict__ be2, const float* __restrict__ tcpe,
    float* __restrict__ out) {
  __shared__ char smem[38400];
  __shared__ float s_M[H_ * T_];
  __shared__ float s_rden[H_ * SK_];
  __shared__ int s_mtop[H_ * SK_];
  float* s_enc = (float*)smem;
  float* s_k = (float*)(smem + 13056);
  float* s_q = (float*)(smem + 26112);
  uint* s_v = (uint*)smem;               // V overlay on dead enc region
  ushort* ap = (ushort*)(smem + 13056);  // attn, overlays k after kr snapshot
  ushort* hs = (ushort*)(smem + 13056);  // ctx/h tile, after attn dead

  const int tid = threadIdx.x;
  const int l = tid & 63;
  const int g = tid >> 6;  // wave id == head id == row-stripe id
  const int bn = blockIdx.x;
  const int b = bn / N_;
  const int kg = l >> 4, c = l & 15;
  const int row0 = g * 12;

  // ---- P0: enc = x + tcpe  (stride 68)
  {
    const float4* x4 = (const float4*)(x + (size_t)bn * (T_ * D_));
    const float4* t4 = (const float4*)(tcpe + (size_t)b * (T_ * D_));
#pragma unroll
    for (int r = 0; r < 3; ++r) {
      int i = tid + 256 * r;  // 768 float4s
      float4 xv = x4[i];
      float4 tv = t4[i];
      int t = i >> 4;
      int d = (i & 15) << 2;
      *(float4*)&s_enc[t * 68 + d] =
          make_float4(xv.x + tv.x, xv.y + tv.y, xv.z + tv.z, xv.w + tv.w);
    }
  }
  __syncthreads();

  // ---- P1: fused QKV (fp32, 8-wide k-chunks — low reg pressure);
  //      Q,K → LDS; V → regs, then overlay onto dead enc region
  {
    float accq[12], acck[12], accv[12];
#pragma unroll
    for (int i = 0; i < 12; ++i) accq[i] = acck[i] = accv[i] = 0.0f;
#pragma unroll 1
    for (int kc = 0; kc < 8; ++kc) {
      float wq[8], wk[8], wv[8];
#pragma unroll
      for (int i = 0; i < 8; ++i) {
        int k = kc * 8 + i;
        wq[i] = Wq[k * D_ + l];
        wk[i] = Wk[k * D_ + l];
        wv[i] = Wv[k * D_ + l];
      }
#pragma unroll
      for (int tt = 0; tt < 12; ++tt) {
        const float* row = &s_enc[(g * 12 + tt) * 68 + kc * 8];
        float4 r0 = ((const float4*)row)[0];
        float4 r1 = ((const float4*)row)[1];
        float rr[8] = {r0.x, r0.y, r0.z, r0.w, r1.x, r1.y, r1.z, r1.w};
#pragma unroll
        for (int i = 0; i < 8; ++i) {
          accq[tt] = fmaf(rr[i], wq[i], accq[tt]);
          acck[tt] = fmaf(rr[i], wk[i], acck[tt]);
          accv[tt] = fmaf(rr[i], wv[i], accv[tt]);
        }
      }
    }
#pragma unroll
    for (int tt = 0; tt < 12; ++tt) {
      int t = g * 12 + tt;
      s_q[t * 64 + l] = accq[tt];
      s_k[t * 68 + l] = acck[tt];
    }
    __syncthreads();  // ALL waves' enc reads done; q,k visible; enc → V
    uint* vl = s_v + g * 6 * 64 + l;
#pragma unroll
    for (int i = 0; i < 6; ++i)
      vl[i * 64] =
          (uint)f2bf(accv[2 * i]) | ((uint)f2bf(accv[2 * i + 1]) << 16);
  }
  // (V writes ordered before P2d reads by the P2a-end barrier)

  // ---- P2a: M[t] = max_s q·k_samp − mean_s   (fp32 — selection-critical)
  if (l < T_) {
    float q[16];
#pragma unroll
    for (int j = 0; j < 16; j += 4) {
      float4 v4 = *(const float4*)&s_q[l * 64 + g * HD_ + j];
      q[j] = v4.x; q[j + 1] = v4.y; q[j + 2] = v4.z; q[j + 3] = v4.w;
    }
    const int4* ip = (const int4*)(idxs + l * SK_);
    float mx = -1e30f, sm = 0.0f;
#pragma unroll
    for (int sg = 0; sg < 5; ++sg) {
      int4 iv = ip[sg];
      int kts[4] = {iv.x, iv.y, iv.z, iv.w};
#pragma unroll
      for (int si = 0; si < 4; ++si) {
        int kt = kts[si];
        float acc = 0.0f;
#pragma unroll
        for (int j = 0; j < 16; j += 4) {
          float4 kv = *(const float4*)&s_k[kt * 68 + g * HD_ + j];
          acc = fmaf(kv.x, q[j], acc);
          acc = fmaf(kv.y, q[j + 1], acc);
          acc = fmaf(kv.z, q[j + 2], acc);
          acc = fmaf(kv.w, q[j + 3], acc);
        }
        mx = fmaxf(mx, acc);
        sm += acc;
      }
    }
    s_M[g * T_ + l] = mx - sm * (1.0f / (float)SK_);
  }
  __syncthreads();

  // ---- P2b: top-20 by rank (jax.lax.top_k tie-break: lower index first)
  if (l < T_) {
    float mv = s_M[g * T_ + l];
    int rank = 0;
    for (int t2 = 0; t2 < T_; ++t2) {
      float o = s_M[g * T_ + t2];
      rank += (o > mv || (o == mv && t2 < l)) ? 1 : 0;
    }
    if (rank < SK_) s_mtop[g * SK_ + rank] = l;
  }
  __syncthreads();

  // ---- P2c: snapshot K row → regs, then scores + UNNORMALIZED exp into
  //      the K region (attn overlay). |score| ≲ 8 << 88 so no max-sub.
  {
    float kr[16];
    if (l < T_) {
#pragma unroll
      for (int j = 0; j < 16; j += 4) {
        float4 v4 = *(const float4*)&s_k[l * 68 + g * HD_ + j];
        kr[j] = v4.x; kr[j + 1] = v4.y; kr[j + 2] = v4.z; kr[j + 3] = v4.w;
      }
    } else {
#pragma unroll
      for (int j = 0; j < 16; ++j) kr[j] = 0.0f;
    }
    __syncthreads();  // all kr snapshots done; k region → attn
#pragma unroll 1
    for (int u = 0; u < SK_; ++u) {
      int qt = s_mtop[g * SK_ + u];
      const float4* qp = (const float4*)&s_q[qt * 64 + g * HD_];
      float acc = 0.0f;
#pragma unroll
      for (int j = 0; j < 4; ++j) {
        float4 qv = qp[j];  // broadcast
        acc = fmaf(qv.x, kr[4 * j], acc);
        acc = fmaf(qv.y, kr[4 * j + 1], acc);
        acc = fmaf(qv.z, kr[4 * j + 2], acc);
        acc = fmaf(qv.w, kr[4 * j + 3], acc);
      }
      if (l < T_) ap[(g * SK_ + u) * T_ + l] = f2bf(__expf(acc * 0.25f));
    }
  }
  // denominators (same wave; lanes 0..19)
  if (l < SK_) {
    const uint* a32 = (const uint*)(smem + 13056) + (g * SK_ + l) * 24;
    float s0 = 0.0f, s1 = 0.0f;
#pragma unroll
    for (int tp = 0; tp < 24; ++tp) {
      uint w = a32[tp];
      s0 += bflo(w);
      s1 += bfhi(w);
    }
    s_rden[g * SK_ + l] = 1.0f / (s0 + s1);
  }

  // ---- P2d: upd = e @ V (V in LDS, conflict-free) ; vmean per-lane register
  const int u0 = l >> 4, jj = l & 15;
  float upd[5] = {0, 0, 0, 0, 0};
  float vm = 0.0f;
  {
    const uint* a32 = (const uint*)(smem + 13056) + g * SK_ * 24;
    const uint* v32 = s_v + g * HD_ + jj;
#pragma unroll 4
    for (int tp = 0; tp < 24; ++tp) {
      uint vw = v32[tp * 64];
      float vlo = bflo(vw), vhi = bfhi(vw);
      vm += vlo + vhi;
#pragma unroll
      for (int r = 0; r < 5; ++r) {
        uint aw = a32[(u0 + 4 * r) * 24 + tp];
        upd[r] = fmaf(bflo(aw), vlo, fmaf(bfhi(aw), vhi, upd[r]));
      }
    }
    vm *= (1.0f / (float)T_);
#pragma unroll
    for (int r = 0; r < 5; ++r) upd[r] *= s_rden[g * SK_ + u0 + 4 * r];
  }
  __syncthreads();  // all waves past attn/V reads; overlays → hs / (enc free)

  // ---- ctx → hs (bf16): vmean fill + top-k scatter + zero pad rows 48..51
  {
    ushort cvm = f2bf(vm);
#pragma unroll
    for (int r = 0; r < 12; ++r) {
      int i = l + 64 * r;  // 768 = 48x16
      int t = i >> 4;
      hs[t * 72 + g * HD_ + jj] = cvm;
    }
    hs[(48 + u0) * 72 + g * HD_ + jj] = 0;
#pragma unroll
    for (int r = 0; r < 5; ++r) {
      int row = s_mtop[g * SK_ + u0 + 4 * r];
      hs[row * 72 + g * HD_ + jj] = f2bf(upd[r]);
    }
  }
  __syncthreads();  // hs complete (cross-wave rows)

  // ================= MFMA tail: wave g owns output rows g*12..g*12+11 ======
  ushort* ft = (ushort*)(smem + 26112) + g * 1152;  // [16][72] per wave
  const f32x4 z = {0.f, 0.f, 0.f, 0.f};

  // residual er = x+tcpe (L2/L3-hot; loads hidden under Wo MFMA below)
  float er[16];
  {
    const float* xp = x + (size_t)bn * (T_ * D_);
    const float* tp2 = tcpe + (size_t)b * (T_ * D_);
#pragma unroll
    for (int reg = 0; reg < 4; ++reg) {
      int cr = kg * 4 + reg;
      int rowc = row0 + (cr < 12 ? cr : 11);  // clamp for pad rows
#pragma unroll
      for (int no = 0; no < 4; ++no)
        er[no * 4 + reg] =
            xp[rowc * D_ + no * 16 + c] + tp2[rowc * D_ + no * 16 + c];
    }
  }

  f32x4 co[4];
  {
    bf16x8 a0 = *(const bf16x8*)(const void*)(hs + (row0 + c) * 72 + kg * 8);
    bf16x8 a1 =
        *(const bf16x8*)(const void*)(hs + (row0 + c) * 72 + 32 + kg * 8);
#pragma unroll
    for (int no = 0; no < 4; ++no) {
      bf16x8 b0 = *(const bf16x8*)(const void*)(WoB + (no * 64 + l) * 8);
      bf16x8 b1f = *(const bf16x8*)(const void*)(WoB + ((4 + no) * 64 + l) * 8);
      f32x4 t0 = __builtin_amdgcn_mfma_f32_16x16x32_bf16(a0, b0, z, 0, 0, 0);
      co[no] = __builtin_amdgcn_mfma_f32_16x16x32_bf16(a1, b1f, t0, 0, 0, 0);
    }
  }
  __syncthreads();  // Wo A-reads done before h overwrites hs

  // + bo + residual, LN1 → h regs; h → hs (bf16)
  float h[16];
#pragma unroll
  for (int no = 0; no < 4; ++no) {
    int col = no * 16 + c;
    float bov = bo[col];
#pragma unroll
    for (int reg = 0; reg < 4; ++reg)
      h[no * 4 + reg] = co[no][reg] + bov + er[no * 4 + reg];
  }
#pragma unroll
  for (int reg = 0; reg < 4; ++reg) {
    float s = h[reg] + h[4 + reg] + h[8 + reg] + h[12 + reg];
    s += __shfl_xor(s, 1); s += __shfl_xor(s, 2);
    s += __shfl_xor(s, 4); s += __shfl_xor(s, 8);
    float mean = s * (1.0f / 64.0f);
    float d0 = h[reg] - mean, d1 = h[4 + reg] - mean;
    float d2 = h[8 + reg] - mean, d3 = h[12 + reg] - mean;
    float q = d0 * d0 + d1 * d1 + d2 * d2 + d3 * d3;
    q += __shfl_xor(q, 1); q += __shfl_xor(q, 2);
    q += __shfl_xor(q, 4); q += __shfl_xor(q, 8);
    float rstd = 1.0f / sqrtf(q * (1.0f / 64.0f) + EPS_);
#pragma unroll
    for (int no = 0; no < 4; ++no) {
      int col = no * 16 + c;
      h[no * 4 + reg] = (h[no * 4 + reg] - mean) * rstd * g1[col] + be1[col];
    }
  }
#pragma unroll
  for (int no = 0; no < 4; ++no)
#pragma unroll
    for (int reg = 0; reg < 4; ++reg) {
      int cr = kg * 4 + reg;
      if (cr < 12) hs[(row0 + cr) * 72 + no * 16 + c] = f2bf(h[no * 4 + reg]);
    }
  __syncthreads();  // h complete (cross-wave rows)

  // FFN: W1 → relu → W2 in four 64-col passes through wave-private ft
  f32x4 o[4] = {z, z, z, z};
  {
    bf16x8 ha0 = *(const bf16x8*)(const void*)(hs + (row0 + c) * 72 + kg * 8);
    bf16x8 ha1 =
        *(const bf16x8*)(const void*)(hs + (row0 + c) * 72 + 32 + kg * 8);
#pragma unroll 1
    for (int p = 0; p < 4; ++p) {
      f32x4 f1[4];
#pragma unroll
      for (int q = 0; q < 4; ++q) {
        int no = p * 4 + q;
        bf16x8 b0 = *(const bf16x8*)(const void*)(W1B + (no * 64 + l) * 8);
        bf16x8 b1f =
            *(const bf16x8*)(const void*)(W1B + ((16 + no) * 64 + l) * 8);
        f32x4 t0 = __builtin_amdgcn_mfma_f32_16x16x32_bf16(ha0, b0, z, 0, 0, 0);
        f1[q] = __builtin_amdgcn_mfma_f32_16x16x32_bf16(ha1, b1f, t0, 0, 0, 0);
      }
#pragma unroll
      for (int q = 0; q < 4; ++q) {
        float bb = b1[(p * 4 + q) * 16 + c];
#pragma unroll
        for (int reg = 0; reg < 4; ++reg) {
          float vv = fmaxf(f1[q][reg] + bb, 0.0f);
          ft[(kg * 4 + reg) * 72 + q * 16 + c] = f2bf(vv);
        }
      }
#pragma unroll
      for (int koi = 0; koi < 2; ++koi) {
        bf16x8 fa =
            *(const bf16x8*)(const void*)(ft + c * 72 + koi * 32 + kg * 8);
#pragma unroll
        for (int no = 0; no < 4; ++no) {
          bf16x8 bf_ = *(const bf16x8*)(const void*)(
              W2B + (((p * 2 + koi) * 4 + no) * 64 + l) * 8);
          o[no] =
              __builtin_amdgcn_mfma_f32_16x16x32_bf16(fa, bf_, o[no], 0, 0, 0);
        }
      }
    }
  }

  // + b2 + h, LN2 → wave-private bounce tile (V/enc region, dead) → out
  float* bt = (float*)smem + g * 816;  // [12][68]
  float v[16];
#pragma unroll
  for (int no = 0; no < 4; ++no) {
    float b2v = b2[no * 16 + c];
#pragma unroll
    for (int reg = 0; reg < 4; ++reg)
      v[no * 4 + reg] = o[no][reg] + b2v + h[no * 4 + reg];
  }
#pragma unroll
  for (int reg = 0; reg < 4; ++reg) {
    float s = v[reg] + v[4 + reg] + v[8 + reg] + v[12 + reg];
    s += __shfl_xor(s, 1); s += __shfl_xor(s, 2);
    s += __shfl_xor(s, 4); s += __shfl_xor(s, 8);
    float mean = s * (1.0f / 64.0f);
    float d0 = v[reg] - mean, d1 = v[4 + reg] - mean;
    float d2 = v[8 + reg] - mean, d3 = v[12 + reg] - mean;
    float q = d0 * d0 + d1 * d1 + d2 * d2 + d3 * d3;
    q += __shfl_xor(q, 1); q += __shfl_xor(q, 2);
    q += __shfl_xor(q, 4); q += __shfl_xor(q, 8);
    float rstd = 1.0f / sqrtf(q * (1.0f / 64.0f) + EPS_);
    int cr = kg * 4 + reg;
    if (cr < 12) {
#pragma unroll
      for (int no = 0; no < 4; ++no) {
        int col = no * 16 + c;
        bt[cr * 68 + col] = (v[no * 4 + reg] - mean) * rstd * g2[col] + be2[col];
      }
    }
  }
  // wave-private RAW through LDS (lgkmcnt-ordered), then full-row stores
  {
    float* op = out + ((size_t)bn * T_ + row0) * D_;
#pragma unroll
    for (int rr = 0; rr < 3; ++rr) {
      int i = l + 64 * rr;  // 192 float4 = 12 rows x 16
      int row = i >> 4;
      int c4 = (i & 15) << 2;
      *(float4*)&op[row * D_ + c4] = *(const float4*)&bt[row * 68 + c4];
    }
  }
}

extern "C" void kernel_launch(void* const* d_in, const int* in_sizes, int n_in,
                              void* d_out, int out_size, void* d_ws,
                              size_t ws_size, hipStream_t stream) {
  const float* x = (const float*)d_in[0];
  const int* tf = (const int*)d_in[1];
  const int* idxs = (const int*)d_in[2];
  const float* Wq = (const float*)d_in[3];
  const float* Wk = (const float*)d_in[4];
  const float* Wv = (const float*)d_in[5];
  const float* Wo = (const float*)d_in[6];
  const float* bo = (const float*)d_in[7];
  const float* W1 = (const float*)d_in[8];
  const float* b1 = (const float*)d_in[9];
  const float* W2 = (const float*)d_in[10];
  const float* b2 = (const float*)d_in[11];
  const float* g1 = (const float*)d_in[12];
  const float* be1 = (const float*)d_in[13];
  const float* g2 = (const float*)d_in[14];
  const float* be2 = (const float*)d_in[15];
  const float* em = (const float*)d_in[16];
  const float* eh = (const float*)d_in[17];
  const float* ew = (const float*)d_in[18];
  const float* emo = (const float*)d_in[19];
  const float* ey = (const float*)d_in[20];
  float* out = (float*)d_out;

  float* tcpe = (float*)d_ws;                     // 96 KiB
  ushort* WoB = (ushort*)((char*)d_ws + 98304);   // 8 KiB
  ushort* W1B = WoB + 4096;                       // 32 KiB
  ushort* W2B = W1B + 16384;                      // 32 KiB

  hipLaunchKernelGGL(prep_kernel, dim3(240), dim3(256), 0, stream, tf, em, eh,
                     ew, emo, ey, tcpe, Wo, W1, W2, WoB, W1B, W2B);
  hipLaunchKernelGGL(mega_kernel, dim3(B_ * N_), dim3(256), 0, stream, x, idxs,
                     Wq, Wk, Wv, WoB, W1B, W2B, bo, b1, b2, g1, be1, g2, be2,
                     tcpe, out);
}